// Round 7
// baseline (688.286 us; speedup 1.0000x reference)
//
#include <hip/hip_runtime.h>

typedef unsigned int u32;
typedef unsigned long long u64;

#define NN_ 6000
#define EE_ 192000
#define DD_ 512
#define KK_ 4096
#define OO_ 40
#define HSZ (1 << 19)
#define HMASK (HSZ - 1)
#define MT_A 376   // ceil(6000/16) m-tiles for node-sized packed arrays
#define NB_N 47    // 6016/128 blocks
#define WPACKE (32 * 16 * 512)   // elems per packed 512-row half

typedef __bf16 bf16x8 __attribute__((ext_vector_type(8)));
typedef float f32x4 __attribute__((ext_vector_type(4)));

__device__ __forceinline__ u32 okey(float f) {
    u32 u = __float_as_uint(f);
    return (u & 0x80000000u) ? ~u : (u | 0x80000000u);
}
__device__ __forceinline__ float dkey(u32 u) {
    u32 b = (u & 0x80000000u) ? (u ^ 0x80000000u) : ~u;
    return __uint_as_float(b);
}
__device__ __forceinline__ u64 packKey(float v, int col) {
    return ((u64)okey(v) << 32) | (u32)(~(u32)col);
}
__device__ __forceinline__ unsigned short f2bf_rne(float f) {
    u32 x = __float_as_uint(f);
    u32 r = x + 0x7fffu + ((x >> 16) & 1u);
    return (unsigned short)(r >> 16);
}
__device__ __forceinline__ void gld_lds16(void* l, const void* g) {
    __builtin_amdgcn_global_load_lds(
        (const __attribute__((address_space(1))) unsigned int*)g,
        (__attribute__((address_space(3))) unsigned int*)l, 16, 0, 0);
}
// compiler+hw ordering fence for same-wave LDS write->read (rule #18 analog)
#define LGKM0 do { asm volatile("s_waitcnt lgkmcnt(0)" ::: "memory"); __builtin_amdgcn_sched_barrier(0); } while (0)

// ---------------- graph prep ----------------
__global__ void k_deg(const int* __restrict__ src, const int* __restrict__ dst,
                      int* __restrict__ degout, int* __restrict__ degin) {
    int e = blockIdx.x * 256 + threadIdx.x;
    if (e >= EE_) return;
    atomicAdd(&degout[src[e]], 1);
    atomicAdd(&degin[dst[e]], 1);
}

__global__ void k_rsqrtdeg(const int* __restrict__ degout, const int* __restrict__ degin,
                           float* __restrict__ rout, float* __restrict__ rin) {
    int i = blockIdx.x * 256 + threadIdx.x;
    if (i >= NN_) return;
    int doV = degout[i]; if (doV < 1) doV = 1;
    int diV = degin[i];  if (diV < 1) diV = 1;
    rout[i] = rsqrtf((float)doV);
    rin[i]  = rsqrtf((float)diV);
}

// 6000-elem scan, 1 block x 1024 threads, 6 elems/thread (20 syncs vs old 120)
__global__ void k_scan(const int* __restrict__ cnt, int* __restrict__ offs, int n) {
    __shared__ int part[1024];
    int t = threadIdx.x;
    int base = t * 6;
    int v[6]; int s = 0;
    #pragma unroll
    for (int j = 0; j < 6; ++j) { int i = base + j; v[j] = (i < n) ? cnt[i] : 0; s += v[j]; }
    part[t] = s;
    __syncthreads();
    for (int off = 1; off < 1024; off <<= 1) {
        int x = (t >= off) ? part[t - off] : 0;
        __syncthreads();
        part[t] += x;
        __syncthreads();
    }
    int run = (t > 0) ? part[t - 1] : 0;
    if (t == 0) offs[0] = 0;
    #pragma unroll
    for (int j = 0; j < 6; ++j) {
        int i = base + j;
        run += v[j];
        if (i < n) offs[i + 1] = run;
    }
}

__global__ void k_fill(const int* __restrict__ src, const int* __restrict__ dst,
                       const int* __restrict__ offs, int* __restrict__ cursor,
                       int* __restrict__ esrc) {
    int e = blockIdx.x * 256 + threadIdx.x;
    if (e >= EE_) return;
    int d = dst[e];
    int pos = offs[d] + atomicAdd(&cursor[d], 1);
    esrc[pos] = src[e];
}

// split 8 floats into bf16 hi/lo packed words
__device__ __forceinline__ void split8(const float* vals, uint4& hw, uint4& lw) {
    u32 h[4], l[4];
    #pragma unroll
    for (int j = 0; j < 4; ++j) {
        unsigned short h0 = f2bf_rne(vals[2*j]),   h1 = f2bf_rne(vals[2*j+1]);
        float hf0 = __uint_as_float((u32)h0 << 16), hf1 = __uint_as_float((u32)h1 << 16);
        unsigned short l0 = f2bf_rne(vals[2*j] - hf0), l1 = f2bf_rne(vals[2*j+1] - hf1);
        h[j] = (u32)h0 | ((u32)h1 << 16);
        l[j] = (u32)l0 | ((u32)l1 << 16);
    }
    hw = make_uint4(h[0], h[1], h[2], h[3]);
    lw = make_uint4(l[0], l[1], l[2], l[3]);
}

// ---------------- persistent sliced aggregation (L2-resident gather) ----------------
template<int UNW>
__global__ __launch_bounds__(256) void k_aggs(
    const float* __restrict__ X, const int* __restrict__ esrc,
    const int* __restrict__ offs, const float* __restrict__ rout,
    const float* __restrict__ rin,
    unsigned short* __restrict__ dh, unsigned short* __restrict__ dl,
    float* __restrict__ gacc) {
    __shared__ float packbuf[4][128];
    __shared__ float mred[4];
    int b = blockIdx.x;                 // [0,1024)
    int xcd = b & 7;                    // heuristic XCD id (round-robin)
    int slice = xcd >> 1;               // 0..3, pinned per XCD pair
    int w = threadIdx.x >> 6, lane = threadIdx.x & 63;
    int wid = ((((b >> 3) << 1) | (xcd & 1)) << 2) + w;  // [0,1024) per slice
    const float* Xc = X + slice * 128 + lane * 2;        // this lane's col pair
    float mrAcc = 0.f;
    for (int node = wid; node < NN_; node += 1024) {
        int beg = offs[node], end = offs[node + 1];
        float a0 = 0.f, a1 = 0.f, u0 = 0.f, u1 = 0.f;
        for (int e = beg; e < end; ) {
            int cnt = end - e; if (cnt > 64) cnt = 64;
            int sreg = 0; float wreg = 0.f;
            if (lane < cnt) { sreg = esrc[e + lane]; wreg = rout[sreg]; }
            int j = 0;
            for (; j + 4 <= cnt; j += 4) {
                int s0 = __shfl(sreg, j),     s1 = __shfl(sreg, j + 1);
                int s2 = __shfl(sreg, j + 2), s3 = __shfl(sreg, j + 3);
                float w0 = __shfl(wreg, j),     w1 = __shfl(wreg, j + 1);
                float w2 = __shfl(wreg, j + 2), w3 = __shfl(wreg, j + 3);
                float2 v0 = *(const float2*)(Xc + (size_t)s0 * DD_);
                float2 v1 = *(const float2*)(Xc + (size_t)s1 * DD_);
                float2 v2 = *(const float2*)(Xc + (size_t)s2 * DD_);
                float2 v3 = *(const float2*)(Xc + (size_t)s3 * DD_);
                a0 = fmaf(w0, v0.x, a0); a1 = fmaf(w0, v0.y, a1);
                a0 = fmaf(w1, v1.x, a0); a1 = fmaf(w1, v1.y, a1);
                a0 = fmaf(w2, v2.x, a0); a1 = fmaf(w2, v2.y, a1);
                a0 = fmaf(w3, v3.x, a0); a1 = fmaf(w3, v3.y, a1);
                if (UNW) {
                    u0 += (v0.x + v1.x) + (v2.x + v3.x);
                    u1 += (v0.y + v1.y) + (v2.y + v3.y);
                }
            }
            for (; j < cnt; ++j) {
                int sj = __shfl(sreg, j); float wj = __shfl(wreg, j);
                float2 v = *(const float2*)(Xc + (size_t)sj * DD_);
                a0 = fmaf(wj, v.x, a0); a1 = fmaf(wj, v.y, a1);
                if (UNW) { u0 += v.x; u1 += v.y; }
            }
            e += cnt;
        }
        float ri = rin[node];
        packbuf[w][lane * 2] = a0 * ri;
        packbuf[w][lane * 2 + 1] = a1 * ri;
        LGKM0;
        if (lane < 16) {
            uint4 hw, lw;
            split8(&packbuf[w][(lane >> 2) * 32 + (lane & 3) * 8], hw, lw);
            int kb = slice * 4 + (lane >> 2);
            int lo = (lane & 3) * 16 + (node & 15);
            size_t base = (((size_t)(node >> 4) * 16 + kb) * 64 + lo) * 8;
            *(uint4*)(dh + base) = hw;
            *(uint4*)(dl + base) = lw;
        }
        if (UNW) {
            float2 q = *(const float2*)(Xc + (size_t)node * DD_);
            mrAcc = fmaf(q.x, u0, mrAcc);
            mrAcc = fmaf(q.y, u1, mrAcc);
        }
    }
    if (UNW) {
        for (int off = 32; off; off >>= 1) mrAcc += __shfl_xor(mrAcc, off);
        if (lane == 0) mred[w] = mrAcc;
        __syncthreads();
        if (threadIdx.x == 0)
            atomicAdd(&gacc[5], mred[0] + mred[1] + mred[2] + mred[3]);
    }
}

// ---------------- fused row-norm + MFMA-pack (wave-per-row, grid-stride) -------
// Replaces k_cbscale + k_pack: one pass over the source rows.
// NORM=1: sc = 1/sqrt(sum row^2 + 1e-12), optionally written to scaleOut[r].
// NORM=0: sc = scaleIn ? scaleIn[gidx[r] or r] : 1.
// lane l holds cols [8l, 8l+8) -> exactly one packed cell (kb=l>>2, sub=l&3).
template<int NORM>
__global__ __launch_bounds__(256) void k_rowpack(
    const float* __restrict__ src, const int* __restrict__ gidx,
    const float* __restrict__ scaleIn, float* __restrict__ scaleOut, int nrows,
    unsigned short* __restrict__ dh, unsigned short* __restrict__ dl) {
    int w = threadIdx.x >> 6, lane = threadIdx.x & 63;
    for (int r = blockIdx.x * 4 + w; r < nrows; r += gridDim.x * 4) {
        int rs = gidx ? gidx[r] : r;
        const float4* p = (const float4*)(src + (size_t)rs * DD_);
        float4 x = p[lane * 2], y = p[lane * 2 + 1];
        float sc;
        if (NORM) {
            float s = x.x * x.x + x.y * x.y + x.z * x.z + x.w * x.w
                    + y.x * y.x + y.y * y.y + y.z * y.z + y.w * y.w;
            for (int off = 32; off; off >>= 1) s += __shfl_xor(s, off);
            sc = 1.0f / sqrtf(s + 1e-12f);
            if (scaleOut && lane == 0) scaleOut[r] = sc;
        } else {
            sc = scaleIn ? scaleIn[rs] : 1.0f;
        }
        float vals[8] = {x.x*sc, x.y*sc, x.z*sc, x.w*sc, y.x*sc, y.y*sc, y.z*sc, y.w*sc};
        uint4 hw, lw;
        split8(vals, hw, lw);
        size_t base = (((size_t)(r >> 4) * 16 + (lane >> 2)) * 64 + (lane & 3) * 16 + (r & 15)) * 8;
        *(uint4*)(dh + base) = hw;
        *(uint4*)(dl + base) = lw;
    }
}

// transpose-pack a [512,512] weight: Bp rows = output cols
__global__ __launch_bounds__(256) void k_wpack(
    const float* __restrict__ W,
    unsigned short* __restrict__ dh, unsigned short* __restrict__ dl) {
    int u = threadIdx.x >> 6, lane = threadIdx.x & 63;
    int mt = blockIdx.x, kb = blockIdx.y * 4 + u;
    int n = mt * 16 + (lane & 15);
    int k = kb * 32 + (lane >> 4) * 8;
    float vals[8];
    #pragma unroll
    for (int j = 0; j < 8; ++j) vals[j] = W[(size_t)(k + j) * DD_ + n];
    uint4 hw, lw;
    split8(vals, hw, lw);
    size_t base = (((size_t)mt * 16 + kb) * 64 + lane) * 8;
    *(uint4*)(dh + base) = hw;
    *(uint4*)(dl + base) = lw;
}

// ---------------- MFMA GEMM, C = A . B^T via split-bf16 ----------
// THREE=1: 3-mfma hi/lo (hh+hl+lh). THREE=0: 2-mfma (hh+hl) — dist GEMM only.
// MODE 0: dist — store C fp32 to Cout (stride KK_)
// MODE 2: dense — store C+bias (opt relu) to Cout (stride DD_), rows < Mrows
// MODE 4: fused Wd — grid (8,47): bx<4 = dense (Wd1,bias,store QE);
//         bx>=4 = rec loss (Wd2 at B+2*WPACKE, bias2) -> gacc[3]. bx==4 blocks
//         additionally fold the commit loss sum((q-h)^2) from the A tile -> gacc[2].
template<int MODE, int THREE>
__global__ __launch_bounds__(256) void gemm_mfma(
    const unsigned short* __restrict__ Ah, const unsigned short* __restrict__ Al,
    const unsigned short* __restrict__ Bh, const unsigned short* __restrict__ Bl,
    float* __restrict__ Cout, const float* __restrict__ bias,
    const float* __restrict__ Ref, int relu, int Mrows,
    float* __restrict__ gacc, const float* __restrict__ bias2) {
    int bx = blockIdx.x, by = blockIdx.y;
    int side = (MODE == 4) ? (bx >> 2) : 0;
    int bxe  = (MODE == 4) ? (bx & 3) : bx;
    __shared__ char lds[32768];  // Ah|Al|Bh|Bl tiles, 8 KB each
    __shared__ float wred0[4], wred1[4];
    int tid = threadIdx.x;
    int wave = tid >> 6, lane = tid & 63;
    int gmtA = by * 8, gmtB = bxe * 8;
    const unsigned short* garr; int gmt0;
    if (wave == 0)      { garr = Ah; gmt0 = gmtA; }
    else if (wave == 1) { garr = Al; gmt0 = gmtA; }
    else if (wave == 2) { garr = Bh + (size_t)side * 2 * WPACKE; gmt0 = gmtB; }
    else                { garr = Bl + (size_t)side * 2 * WPACKE; gmt0 = gmtB; }
    char* ldst = lds + wave * 8192;
    f32x4 acc[4][4];
    #pragma unroll
    for (int i = 0; i < 4; ++i)
        #pragma unroll
        for (int j = 0; j < 4; ++j) acc[i][j] = (f32x4){0.f, 0.f, 0.f, 0.f};
    float commitAcc = 0.f;
    int wm = wave >> 1, wn = wave & 1;
    for (int kb = 0; kb < 16; ++kb) {
        if (THREE || wave != 1) {
            #pragma unroll
            for (int t = 0; t < 8; ++t) {
                const char* g = (const char*)garr + (((size_t)(gmt0 + t) * 16 + kb) * 1024) + lane * 16;
                gld_lds16(ldst + t * 1024 + lane * 16, g);
            }
        }
        __syncthreads();
        // commit-loss fold: reconstruct q from the A tile, compare vs h (=Ref)
        if (MODE == 4 && bx == 4) {
            int rg = tid >> 1, half = tid & 1;
            int m = by * 128 + rg;
            if (m < Mrows) {
                int tt = rg >> 4, r = rg & 15;
                const float* hp = Ref + (size_t)m * DD_ + kb * 32 + half * 16;
                float4 h0 = ((const float4*)hp)[0], h1 = ((const float4*)hp)[1];
                float4 h2 = ((const float4*)hp)[2], h3 = ((const float4*)hp)[3];
                float hv[16] = {h0.x,h0.y,h0.z,h0.w, h1.x,h1.y,h1.z,h1.w,
                                h2.x,h2.y,h2.z,h2.w, h3.x,h3.y,h3.z,h3.w};
                #pragma unroll
                for (int j2 = 0; j2 < 16; ++j2) {
                    int sub = half * 2 + (j2 >> 3), j = j2 & 7;
                    int off = tt * 1024 + (sub * 16 + r) * 16 + j * 2;
                    u32 hb = *(const unsigned short*)(lds + off);
                    u32 lb = *(const unsigned short*)(lds + 8192 + off);
                    float q = __uint_as_float(hb << 16) + __uint_as_float(lb << 16);
                    float d = q - hv[j2];
                    commitAcc = fmaf(d, d, commitAcc);
                }
            }
        }
        bf16x8 a_h[4], a_l[4], b_h[4], b_l[4];
        #pragma unroll
        for (int i = 0; i < 4; ++i) {
            int at = wm * 4 + i, bt = wn * 4 + i;
            a_h[i] = *(const bf16x8*)(lds + 0     + at * 1024 + lane * 16);
            if (THREE) a_l[i] = *(const bf16x8*)(lds + 8192 + at * 1024 + lane * 16);
            b_h[i] = *(const bf16x8*)(lds + 16384 + bt * 1024 + lane * 16);
            b_l[i] = *(const bf16x8*)(lds + 24576 + bt * 1024 + lane * 16);
        }
        #pragma unroll
        for (int i = 0; i < 4; ++i)
            #pragma unroll
            for (int j = 0; j < 4; ++j) {
                acc[i][j] = __builtin_amdgcn_mfma_f32_16x16x32_bf16(a_h[i], b_h[j], acc[i][j], 0, 0, 0);
                acc[i][j] = __builtin_amdgcn_mfma_f32_16x16x32_bf16(a_h[i], b_l[j], acc[i][j], 0, 0, 0);
                if (THREE)
                    acc[i][j] = __builtin_amdgcn_mfma_f32_16x16x32_bf16(a_l[i], b_h[j], acc[i][j], 0, 0, 0);
            }
        __syncthreads();
    }
    // C/D layout: col = lane&15, row = (lane>>4)*4 + reg
    int m_base = by * 128 + wm * 64;
    int n_base = bxe * 128 + wn * 64;
    int rq = lane >> 4, cc = lane & 15;
    if (MODE == 0) {
        #pragma unroll
        for (int i = 0; i < 4; ++i) {
            int m = m_base + i * 16 + rq * 4;
            #pragma unroll
            for (int j = 0; j < 4; ++j) {
                int n = n_base + j * 16 + cc;
                #pragma unroll
                for (int r = 0; r < 4; ++r) {
                    if (m + r < NN_) Cout[(size_t)(m + r) * KK_ + n] = acc[i][j][r];
                }
            }
        }
    } else if (MODE == 2 || (MODE == 4 && side == 0)) {
        #pragma unroll
        for (int i = 0; i < 4; ++i) {
            int m = m_base + i * 16 + rq * 4;
            #pragma unroll
            for (int j = 0; j < 4; ++j) {
                int n = n_base + j * 16 + cc;
                float bv = bias[n];
                #pragma unroll
                for (int r = 0; r < 4; ++r) {
                    if (m + r < Mrows) {
                        float v = acc[i][j][r] + bv;
                        if (relu) v = fmaxf(v, 0.f);
                        Cout[(size_t)(m + r) * DD_ + n] = v;
                    }
                }
            }
        }
    } else {  // MODE 4 rec-loss side
        const float* bs = bias2;
        float s = 0.f;
        #pragma unroll
        for (int i = 0; i < 4; ++i) {
            int m = m_base + i * 16 + rq * 4;
            #pragma unroll
            for (int j = 0; j < 4; ++j) {
                int n = n_base + j * 16 + cc;
                float bv = bs[n];
                #pragma unroll
                for (int r = 0; r < 4; ++r) {
                    if (m + r < Mrows) {
                        float d = Ref[(size_t)(m + r) * DD_ + n] - (acc[i][j][r] + bv);
                        s = fmaf(d, d, s);
                    }
                }
            }
        }
        for (int off = 32; off; off >>= 1) s += __shfl_xor(s, off);
        if (lane == 0) wred0[wave] = s;
        if (MODE == 4 && bx == 4) {
            float c = commitAcc;
            for (int off = 32; off; off >>= 1) c += __shfl_xor(c, off);
            if (lane == 0) wred1[wave] = c;
        }
        __syncthreads();
        if (tid == 0) {
            atomicAdd(&gacc[3], wred0[0] + wred0[1] + wred0[2] + wred0[3]);
            if (MODE == 4 && bx == 4)
                atomicAdd(&gacc[2], wred1[0] + wred1[1] + wred1[2] + wred1[3]);
        }
    }
}

// ---------------- dedicated rpass GEMM: 256x128 tiles over the triangle -------
// R6 post-mortem: 128x128 tiles stage 32 B/output-elem; 256x128 (2 A-tiles
// share one B-tile) stages 24 B/elem (-25% fetch), 576 blocks (~2/CU, one
// pass), standalone compile (no template regalloc perturbation, rule #19).
// Triangle: byp in [0,24) row-pairs, bx in [2byp,47); cum(b)=b*(48-b).
// XCD-chunked order: L=(blockIdx&7)*72+(blockIdx>>3) (bijective, 576=8*72) so
// consecutive triangle tiles (sharing the A-panel) land on one XCD's L2.
__global__ __launch_bounds__(256) void gemm_rpass(
    const unsigned short* __restrict__ Qh, const unsigned short* __restrict__ Ql,
    float* __restrict__ gacc, u32* __restrict__ minKey, u32* __restrict__ maxKey) {
    int Lp = blockIdx.x;
    int L = (Lp & 7) * 72 + (Lp >> 3);
    int b = (int)(24.f - sqrtf(576.f - (float)L));
    if (b < 0) b = 0; if (b > 23) b = 23;
    while (b * (48 - b) > L) --b;
    while ((b + 1) * (47 - b) <= L) ++b;
    int byp = b;
    int bx = 2 * byp + (L - byp * (48 - byp));
    __shared__ char lds[49152];   // Ah0|Al0|Ah1|Al1|Bh|Bl, 8 KB each
    __shared__ float wr0[4], wr1[4], wr2[4], wr3[4];
    int tid = threadIdx.x, wave = tid >> 6, lane = tid & 63;
    int rh = wave >> 1, wn = wave & 1;    // wave owns 128 rows x 64 cols
    int gmtA0 = byp * 16;                               // tile 2byp
    int gmtA1 = (2 * byp + 1 <= 46) ? (2 * byp + 1) * 8 : 46 * 8;  // clamp (masked)
    int gmtB  = bx * 8;
    f32x4 acc[8][4];
    #pragma unroll
    for (int i = 0; i < 8; ++i)
        #pragma unroll
        for (int j = 0; j < 4; ++j) acc[i][j] = (f32x4){0.f, 0.f, 0.f, 0.f};
    for (int kb = 0; kb < 16; ++kb) {
        #pragma unroll
        for (int k = 0; k < 12; ++k) {
            int g = wave * 12 + k;
            int arr = g >> 3, mt = g & 7;
            int gmt = (arr < 2) ? (gmtA0 + mt) : (arr < 4) ? (gmtA1 + mt) : (gmtB + mt);
            const unsigned short* sp = (arr & 1) ? Ql : Qh;
            gld_lds16(lds + arr * 8192 + mt * 1024 + lane * 16,
                      (const char*)sp + (((size_t)gmt * 16 + kb) * 1024) + lane * 16);
        }
        __syncthreads();
        bf16x8 b_h[4], b_l[4];
        #pragma unroll
        for (int j = 0; j < 4; ++j) {
            b_h[j] = *(const bf16x8*)(lds + 32768 + (wn * 4 + j) * 1024 + lane * 16);
            b_l[j] = *(const bf16x8*)(lds + 40960 + (wn * 4 + j) * 1024 + lane * 16);
        }
        #pragma unroll
        for (int ih = 0; ih < 2; ++ih) {
            bf16x8 a_h[4], a_l[4];
            #pragma unroll
            for (int z = 0; z < 4; ++z) {
                a_h[z] = *(const bf16x8*)(lds + rh * 16384 + (ih * 4 + z) * 1024 + lane * 16);
                a_l[z] = *(const bf16x8*)(lds + rh * 16384 + 8192 + (ih * 4 + z) * 1024 + lane * 16);
            }
            #pragma unroll
            for (int z = 0; z < 4; ++z)
                #pragma unroll
                for (int j = 0; j < 4; ++j) {
                    int i = ih * 4 + z;
                    acc[i][j] = __builtin_amdgcn_mfma_f32_16x16x32_bf16(a_h[z], b_h[j], acc[i][j], 0, 0, 0);
                    acc[i][j] = __builtin_amdgcn_mfma_f32_16x16x32_bf16(a_h[z], b_l[j], acc[i][j], 0, 0, 0);
                    acc[i][j] = __builtin_amdgcn_mfma_f32_16x16x32_bf16(a_l[z], b_h[j], acc[i][j], 0, 0, 0);
                }
        }
        __syncthreads();
    }
    int m_base = byp * 256 + rh * 128;
    int n_base = bx * 128 + wn * 64;
    int rq = lane >> 4, cc = lane & 15;
    float tsum = 0.f, tsq = 0.f, tmin = 3.4e38f, tmax = -3.4e38f;
    #pragma unroll
    for (int i = 0; i < 8; ++i) {
        #pragma unroll
        for (int j = 0; j < 4; ++j) {
            #pragma unroll
            for (int r = 0; r < 4; ++r) {
                int m = m_base + i * 16 + rq * 4 + r;
                int n = n_base + j * 16 + cc;
                if (m < NN_ && n < NN_ && n >= m) {
                    float v = acc[i][j][r];
                    float w = (n > m) ? 2.f : 1.f;
                    tsum += w * v;
                    tsq  += w * v * v;
                    tmin = fminf(tmin, v);
                    tmax = fmaxf(tmax, v);
                }
            }
        }
    }
    for (int off = 32; off; off >>= 1) {
        tsum += __shfl_xor(tsum, off);
        tsq  += __shfl_xor(tsq, off);
        tmin = fminf(tmin, __shfl_xor(tmin, off));
        tmax = fmaxf(tmax, __shfl_xor(tmax, off));
    }
    if (lane == 0) { wr0[wave] = tsum; wr1[wave] = tsq; wr2[wave] = tmin; wr3[wave] = tmax; }
    __syncthreads();
    if (tid == 0) {
        atomicAdd(&gacc[0], wr0[0] + wr0[1] + wr0[2] + wr0[3]);
        atomicAdd(&gacc[1], wr1[0] + wr1[1] + wr1[2] + wr1[3]);
        atomicMin(minKey, okey(fminf(fminf(wr2[0], wr2[1]), fminf(wr2[2], wr2[3]))));
        atomicMax(maxKey, okey(fmaxf(fmaxf(wr3[0], wr3[1]), fmaxf(wr3[2], wr3[3]))));
    }
}

// exact-fp32 argmax rescue — persistent, wave-per-row.
__global__ __launch_bounds__(256) void k_rescore(
    const float* __restrict__ dist, const float* __restrict__ h,
    const float* __restrict__ rnorm, const float* __restrict__ cb,
    const float* __restrict__ scale, int* __restrict__ ind) {
    int w = threadIdx.x >> 6, lane = threadIdx.x & 63;
    for (int row = blockIdx.x * 4 + w; row < NN_; row += gridDim.x * 4) {
        const float4* dr4 = (const float4*)(dist + (size_t)row * KK_);
        float4 vbuf[16];
        float lmax = -3.4e38f;
        #pragma unroll
        for (int it = 0; it < 16; ++it) {
            float4 v = dr4[lane + it * 64];
            vbuf[it] = v;
            lmax = fmaxf(lmax, fmaxf(fmaxf(v.x, v.y), fmaxf(v.z, v.w)));
        }
        for (int off = 32; off; off >>= 1) lmax = fmaxf(lmax, __shfl_xor(lmax, off));
        float thr = lmax - 1e-3f;
        float hr = rnorm[row];
        const float* hp = h + (size_t)row * DD_;
        u64 best = 0;
        #pragma unroll 1
        for (int it = 0; it < 16; ++it) {
            float4 v = vbuf[it];
            u32 m4 = (v.x >= thr ? 1u : 0u) | (v.y >= thr ? 2u : 0u)
                   | (v.z >= thr ? 4u : 0u) | (v.w >= thr ? 8u : 0u);
            u64 bal = __ballot(m4 != 0);
            while (bal) {
                int l = __ffsll((unsigned long long)bal) - 1;
                bal &= bal - 1;
                u32 mm = __shfl(m4, l);
                while (mm) {
                    int j = __ffs(mm) - 1;
                    mm &= mm - 1;
                    int col = (l + it * 64) * 4 + j;
                    const float* cp = cb + (size_t)col * DD_;
                    float dot = 0.f;
                    #pragma unroll
                    for (int jj = 0; jj < 8; ++jj)
                        dot = fmaf(hp[lane + jj * 64], cp[lane + jj * 64], dot);
                    for (int off = 32; off; off >>= 1) dot += __shfl_xor(dot, off);
                    u64 key = packKey(dot * hr * scale[col], col);
                    if (key > best) best = key;   // dot wave-uniform after butterfly
                }
            }
        }
        if (lane == 0) ind[row] = (int)(~(u32)(best & 0xFFFFFFFFull));
    }
}

// ---------------- fp32 GEMM (kept only for the 6000x40 output) ----------------
__global__ __launch_bounds__(256) void gemm_nn(
    const float* __restrict__ A, const float* __restrict__ B,
    const float* __restrict__ bias, float* __restrict__ C,
    int M, int Ncols, int Kdim) {
    __shared__ float As[16][68];
    __shared__ float Bs[16][68];
    int tid = threadIdx.x;
    int tx = tid & 15, ty = tid >> 4;
    int m0 = blockIdx.y * 64, n0 = blockIdx.x * 64;
    float cv[4][4] = {};
    int ar = tid >> 2;
    int ak = (tid & 3) << 2;
    int am = m0 + ar;
    const float* Arow = (am < M) ? (A + (size_t)am * Kdim) : nullptr;
    int bk = tid >> 4;
    int bn = (tid & 15) << 2;
    for (int k0 = 0; k0 < Kdim; k0 += 16) {
        float4 av = make_float4(0.f, 0.f, 0.f, 0.f);
        if (Arow) av = *(const float4*)(Arow + k0 + ak);
        As[ak + 0][ar] = av.x; As[ak + 1][ar] = av.y;
        As[ak + 2][ar] = av.z; As[ak + 3][ar] = av.w;
        float4 bv = make_float4(0.f, 0.f, 0.f, 0.f);
        if (n0 + bn < Ncols)
            bv = *(const float4*)(B + (size_t)(k0 + bk) * Ncols + n0 + bn);
        Bs[bk][bn + 0] = bv.x; Bs[bk][bn + 1] = bv.y;
        Bs[bk][bn + 2] = bv.z; Bs[bk][bn + 3] = bv.w;
        __syncthreads();
        #pragma unroll
        for (int kk = 0; kk < 16; ++kk) {
            float4 a4 = *(const float4*)&As[kk][ty << 2];
            float4 b4 = *(const float4*)&Bs[kk][tx << 2];
            float ax[4] = {a4.x, a4.y, a4.z, a4.w};
            float bx[4] = {b4.x, b4.y, b4.z, b4.w};
            #pragma unroll
            for (int i = 0; i < 4; ++i)
                #pragma unroll
                for (int j = 0; j < 4; ++j)
                    cv[i][j] = fmaf(ax[i], bx[j], cv[i][j]);
        }
        __syncthreads();
    }
    #pragma unroll
    for (int i = 0; i < 4; ++i) {
        int m = m0 + (ty << 2) + i;
        if (m >= M) continue;
        #pragma unroll
        for (int j = 0; j < 4; ++j) {
            int n = n0 + (tx << 2) + j;
            if (n >= Ncols) continue;
            C[(size_t)m * Ncols + n] = cv[i][j] + bias[n];
        }
    }
}

// ---------------- edge multiplicity hash (for sum m^2 only) ----------------
__global__ void k_hash(const int* __restrict__ src, const int* __restrict__ dst,
                       int* __restrict__ hkey, int* __restrict__ hcnt) {
    int e = blockIdx.x * 256 + threadIdx.x;
    if (e >= EE_) return;
    int key = dst[e] * NN_ + src[e];
    u32 h = ((u32)key * 2654435761u) & HMASK;
    while (true) {
        int old = atomicCAS(&hkey[h], -1, key);
        if (old == -1 || old == key) { atomicAdd(&hcnt[h], 1); break; }
        h = (h + 1) & HMASK;
    }
}

__global__ __launch_bounds__(256) void k_m2scan(const int* __restrict__ hcnt, float* __restrict__ gacc) {
    float s = 0.f;
    for (int i = blockIdx.x * 256 + threadIdx.x; i < HSZ; i += gridDim.x * 256) {
        float c = (float)hcnt[i];
        s = fmaf(c, c, s);
    }
    for (int off = 32; off; off >>= 1) s += __shfl_xor(s, off);
    __shared__ float w1[4];
    int lane = threadIdx.x & 63, wv = threadIdx.x >> 6;
    if (lane == 0) w1[wv] = s;
    __syncthreads();
    if (threadIdx.x == 0) atomicAdd(&gacc[4], w1[0] + w1[1] + w1[2] + w1[3]);
}

// ---------------- final loss assembly ----------------
__global__ void k_final(const float* __restrict__ gacc, const u32* __restrict__ minKey,
                        const u32* __restrict__ maxKey, float* __restrict__ lossOut) {
    if (threadIdx.x != 0 || blockIdx.x != 0) return;
    double Rsum = gacc[0], Rsq = gacc[1], commitS = gacc[2], recS = gacc[3];
    double m2 = gacc[4], mr = gacc[5], ms = (double)EE_;
    double mn = (double)dkey(*minKey);
    double mx = (double)dkey(*maxKey);
    double den = mx - mn;
    double NN2 = (double)NN_ * (double)NN_;
    double sum_aq2 = (Rsq - 2.0 * mn * Rsum + NN2 * mn * mn) / (den * den);
    double sum_maq = (mr - mn * ms) / den;
    double total = sum_aq2 + m2 - 2.0 * sum_maq;
    double edge = sqrt(total / NN2);
    double commit = 0.25 * commitS / ((double)NN_ * (double)DD_);
    double rec = recS / ((double)NN_ * (double)DD_);
    *lossOut = (float)(rec + edge + commit);
}

extern "C" void kernel_launch(void* const* d_in, const int* in_sizes, int n_in,
                              void* d_out, int out_size, void* d_ws, size_t ws_size,
                              hipStream_t stream) {
    const float* feats = (const float*)d_in[0];
    const float* W1 = (const float*)d_in[1];
    const float* b1 = (const float*)d_in[2];
    const float* W2 = (const float*)d_in[3];
    const float* b2v = (const float*)d_in[4];
    const float* Wd1 = (const float*)d_in[5];
    const float* bd1 = (const float*)d_in[6];
    const float* Wd2 = (const float*)d_in[7];
    const float* bd2 = (const float*)d_in[8];
    const float* Wl = (const float*)d_in[9];
    const float* bl = (const float*)d_in[10];
    const float* cb = (const float*)d_in[11];
    const int* src = (const int*)d_in[12];
    const int* dst = (const int*)d_in[13];

    float* outF = (float*)d_out;
    float* lossOut = outF + (size_t)NN_ * OO_;     // element 240000
    float* distOut = lossOut + 1;                  // element 240001

    char* w = (char*)d_ws;
    size_t off = 0;
    auto alloc = [&](size_t bytes) -> void* {
        void* p = w + off;
        off = (off + bytes + 255) & ~(size_t)255;
        return p;
    };
    // zone0: zero-init
    float* gacc = (float*)alloc(64);
    u32* maxKey = (u32*)alloc(4);
    int* degin = (int*)alloc((size_t)NN_ * 4);
    int* degout = (int*)alloc((size_t)NN_ * 4);
    int* cursor = (int*)alloc((size_t)NN_ * 4);
    int* hcnt = (int*)alloc((size_t)HSZ * 4);
    size_t z0end = off;
    // zone1: 0xFF-init
    int* hkey = (int*)alloc((size_t)HSZ * 4);
    u32* minKey = (u32*)alloc(4);
    size_t z1end = off;
    // uninit scratch
    int* offs = (int*)alloc((size_t)(NN_ + 1) * 4);
    int* esrc = (int*)alloc((size_t)EE_ * 4);
    float* rin = (float*)alloc((size_t)NN_ * 4);
    float* rout = (float*)alloc((size_t)NN_ * 4);
    int* ind = (int*)alloc((size_t)NN_ * 4);
    float* scale = (float*)alloc((size_t)KK_ * 4);
    float* rnorm = (float*)alloc((size_t)NN_ * 4);
    float* h = (float*)alloc((size_t)NN_ * DD_ * 4);       // h, later h2
    float* QE = (float*)alloc((size_t)NN_ * DD_ * 4);
    const size_t NPACK = (size_t)MT_A * 16 * DD_;          // node-sized packed half
    unsigned short* P1 = (unsigned short*)alloc(NPACK * 2 * 2);  // aggp -> qcp -> agg2p
    unsigned short* P2 = (unsigned short*)alloc(NPACK * 2 * 2);  // hnp -> QEp
    unsigned short* enp = (unsigned short*)alloc((size_t)KK_ * DD_ * 2 * 2);
    const size_t WPACK = (size_t)32 * 16 * DD_;            // 512-row packed half
    unsigned short* W1p = (unsigned short*)alloc(WPACK * 2 * 2);
    unsigned short* Wd1p = (unsigned short*)alloc(WPACK * 2 * 2);  // MUST stay
    unsigned short* Wd2p = (unsigned short*)alloc(WPACK * 2 * 2);  // contiguous (MODE4)
    unsigned short* W2p = (unsigned short*)alloc(WPACK * 2 * 2);

    unsigned short* aggp_h = P1,  *aggp_l = P1 + NPACK;
    unsigned short* qcp_h  = P1,  *qcp_l  = P1 + NPACK;
    unsigned short* ag2p_h = P1,  *ag2p_l = P1 + NPACK;
    unsigned short* hnp_h  = P2,  *hnp_l  = P2 + NPACK;
    unsigned short* QEp_h  = P2,  *QEp_l  = P2 + NPACK;
    unsigned short* enp_h  = enp, *enp_l  = enp + (size_t)KK_ * DD_;

    hipMemsetAsync(w, 0, z0end, stream);
    hipMemsetAsync(w + z0end, 0xFF, z1end - z0end, stream);

    const int TB = 256;
    k_deg<<<(EE_ + TB - 1) / TB, TB, 0, stream>>>(src, dst, degout, degin);
    k_rsqrtdeg<<<(NN_ + TB - 1) / TB, TB, 0, stream>>>(degout, degin, rout, rin);
    k_scan<<<1, 1024, 0, stream>>>(degin, offs, NN_);
    k_fill<<<(EE_ + TB - 1) / TB, TB, 0, stream>>>(src, dst, offs, cursor, esrc);
    k_wpack<<<dim3(32, 4), TB, 0, stream>>>(W1, W1p, W1p + WPACK);
    k_wpack<<<dim3(32, 4), TB, 0, stream>>>(Wd1, Wd1p, Wd1p + WPACK);
    k_wpack<<<dim3(32, 4), TB, 0, stream>>>(Wd2, Wd2p, Wd2p + WPACK);
    k_wpack<<<dim3(32, 4), TB, 0, stream>>>(W2, W2p, W2p + WPACK);
    k_aggs<0><<<1024, TB, 0, stream>>>(feats, esrc, offs, rout, rin, aggp_h, aggp_l, nullptr);
    gemm_mfma<2,1><<<dim3(4, NB_N), TB, 0, stream>>>(aggp_h, aggp_l, W1p, W1p + WPACK,
                                                     h, b1, nullptr, 1, NN_, nullptr, nullptr);
    k_rowpack<1><<<1024, TB, 0, stream>>>(h, nullptr, nullptr, rnorm, NN_, hnp_h, hnp_l);
    k_rowpack<1><<<1024, TB, 0, stream>>>(cb, nullptr, nullptr, scale, KK_, enp_h, enp_l);
    gemm_mfma<0,0><<<dim3(KK_ / 128, NB_N), TB, 0, stream>>>(hnp_h, hnp_l, enp_h, enp_l,
                                                             distOut, nullptr, nullptr, 0, NN_,
                                                             nullptr, nullptr);
    k_rescore<<<1024, TB, 0, stream>>>(distOut, h, rnorm, cb, scale, ind);
    k_rowpack<0><<<1024, TB, 0, stream>>>(cb, ind, scale, nullptr, NN_, qcp_h, qcp_l);
    // fused Wd1+Wd2 GEMM: stores QE (bx<4), rec loss (bx>=4), commit fold (bx==4)
    gemm_mfma<4,1><<<dim3(8, NB_N), TB, 0, stream>>>(qcp_h, qcp_l, Wd1p, Wd1p + WPACK,
                                                     QE, bd1, h, 0, NN_, gacc, bd2);
    k_rowpack<0><<<1024, TB, 0, stream>>>(QE, nullptr, nullptr, nullptr, NN_, QEp_h, QEp_l);
    gemm_rpass<<<576, TB, 0, stream>>>(QEp_h, QEp_l, gacc, minKey, maxKey);
    k_hash<<<(EE_ + TB - 1) / TB, TB, 0, stream>>>(src, dst, hkey, hcnt);
    k_m2scan<<<512, TB, 0, stream>>>(hcnt, gacc);
    k_aggs<1><<<1024, TB, 0, stream>>>(QE, esrc, offs, rout, rin, ag2p_h, ag2p_l, gacc);
    gemm_mfma<2,1><<<dim3(4, NB_N), TB, 0, stream>>>(ag2p_h, ag2p_l, W2p, W2p + WPACK,
                                                     h, b2v, nullptr, 1, NN_, nullptr, nullptr);
    gemm_nn<<<dim3(1, 94), TB, 0, stream>>>(h, Wl, bl, outF, NN_, OO_, DD_);
    k_final<<<1, 64, 0, stream>>>(gacc, minKey, maxKey, lossOut);
}

// Round 8
// 675.120 us; speedup vs baseline: 1.0195x; 1.0195x over previous
//
#include <hip/hip_runtime.h>

typedef unsigned int u32;
typedef unsigned long long u64;

#define NN_ 6000
#define EE_ 192000
#define DD_ 512
#define KK_ 4096
#define OO_ 40
#define HSZ (1 << 19)
#define HMASK (HSZ - 1)
#define MT_A 376   // ceil(6000/16) m-tiles for node-sized packed arrays
#define NB_N 47    // 6016/128 blocks
#define WPACKE (32 * 16 * 512)   // elems per packed 512-row half

typedef __bf16 bf16x8 __attribute__((ext_vector_type(8)));
typedef float f32x4 __attribute__((ext_vector_type(4)));

__device__ __forceinline__ u32 okey(float f) {
    u32 u = __float_as_uint(f);
    return (u & 0x80000000u) ? ~u : (u | 0x80000000u);
}
__device__ __forceinline__ float dkey(u32 u) {
    u32 b = (u & 0x80000000u) ? (u ^ 0x80000000u) : ~u;
    return __uint_as_float(b);
}
__device__ __forceinline__ u64 packKey(float v, int col) {
    return ((u64)okey(v) << 32) | (u32)(~(u32)col);
}
__device__ __forceinline__ unsigned short f2bf_rne(float f) {
    u32 x = __float_as_uint(f);
    u32 r = x + 0x7fffu + ((x >> 16) & 1u);
    return (unsigned short)(r >> 16);
}
__device__ __forceinline__ void gld_lds16(void* l, const void* g) {
    __builtin_amdgcn_global_load_lds(
        (const __attribute__((address_space(1))) unsigned int*)g,
        (__attribute__((address_space(3))) unsigned int*)l, 16, 0, 0);
}
// compiler+hw ordering fence for same-wave LDS write->read (rule #18 analog)
#define LGKM0 do { asm volatile("s_waitcnt lgkmcnt(0)" ::: "memory"); __builtin_amdgcn_sched_barrier(0); } while (0)

// ---------------- graph prep ----------------
__global__ void k_deg(const int* __restrict__ src, const int* __restrict__ dst,
                      int* __restrict__ degout, int* __restrict__ degin) {
    int e = blockIdx.x * 256 + threadIdx.x;
    if (e >= EE_) return;
    atomicAdd(&degout[src[e]], 1);
    atomicAdd(&degin[dst[e]], 1);
}

__global__ void k_rsqrtdeg(const int* __restrict__ degout, const int* __restrict__ degin,
                           float* __restrict__ rout, float* __restrict__ rin) {
    int i = blockIdx.x * 256 + threadIdx.x;
    if (i >= NN_) return;
    int doV = degout[i]; if (doV < 1) doV = 1;
    int diV = degin[i];  if (diV < 1) diV = 1;
    rout[i] = rsqrtf((float)doV);
    rin[i]  = rsqrtf((float)diV);
}

// 6000-elem scan, 1 block x 1024 threads, 6 elems/thread (20 syncs)
__global__ void k_scan(const int* __restrict__ cnt, int* __restrict__ offs, int n) {
    __shared__ int part[1024];
    int t = threadIdx.x;
    int base = t * 6;
    int v[6]; int s = 0;
    #pragma unroll
    for (int j = 0; j < 6; ++j) { int i = base + j; v[j] = (i < n) ? cnt[i] : 0; s += v[j]; }
    part[t] = s;
    __syncthreads();
    for (int off = 1; off < 1024; off <<= 1) {
        int x = (t >= off) ? part[t - off] : 0;
        __syncthreads();
        part[t] += x;
        __syncthreads();
    }
    int run = (t > 0) ? part[t - 1] : 0;
    if (t == 0) offs[0] = 0;
    #pragma unroll
    for (int j = 0; j < 6; ++j) {
        int i = base + j;
        run += v[j];
        if (i < n) offs[i + 1] = run;
    }
}

__global__ void k_fill(const int* __restrict__ src, const int* __restrict__ dst,
                       const int* __restrict__ offs, int* __restrict__ cursor,
                       int* __restrict__ esrc) {
    int e = blockIdx.x * 256 + threadIdx.x;
    if (e >= EE_) return;
    int d = dst[e];
    int pos = offs[d] + atomicAdd(&cursor[d], 1);
    esrc[pos] = src[e];
}

// split 8 floats into bf16 hi/lo packed words
__device__ __forceinline__ void split8(const float* vals, uint4& hw, uint4& lw) {
    u32 h[4], l[4];
    #pragma unroll
    for (int j = 0; j < 4; ++j) {
        unsigned short h0 = f2bf_rne(vals[2*j]),   h1 = f2bf_rne(vals[2*j+1]);
        float hf0 = __uint_as_float((u32)h0 << 16), hf1 = __uint_as_float((u32)h1 << 16);
        unsigned short l0 = f2bf_rne(vals[2*j] - hf0), l1 = f2bf_rne(vals[2*j+1] - hf1);
        h[j] = (u32)h0 | ((u32)h1 << 16);
        l[j] = (u32)l0 | ((u32)l1 << 16);
    }
    hw = make_uint4(h[0], h[1], h[2], h[3]);
    lw = make_uint4(l[0], l[1], l[2], l[3]);
}

// ---------------- persistent sliced aggregation (L2-resident gather) ----------------
template<int UNW>
__global__ __launch_bounds__(256) void k_aggs(
    const float* __restrict__ X, const int* __restrict__ esrc,
    const int* __restrict__ offs, const float* __restrict__ rout,
    const float* __restrict__ rin,
    unsigned short* __restrict__ dh, unsigned short* __restrict__ dl,
    float* __restrict__ gacc) {
    __shared__ float packbuf[4][128];
    __shared__ float mred[4];
    int b = blockIdx.x;                 // [0,1024)
    int xcd = b & 7;                    // heuristic XCD id (round-robin)
    int slice = xcd >> 1;               // 0..3, pinned per XCD pair
    int w = threadIdx.x >> 6, lane = threadIdx.x & 63;
    int wid = ((((b >> 3) << 1) | (xcd & 1)) << 2) + w;  // [0,1024) per slice
    const float* Xc = X + slice * 128 + lane * 2;        // this lane's col pair
    float mrAcc = 0.f;
    for (int node = wid; node < NN_; node += 1024) {
        int beg = offs[node], end = offs[node + 1];
        float a0 = 0.f, a1 = 0.f, u0 = 0.f, u1 = 0.f;
        for (int e = beg; e < end; ) {
            int cnt = end - e; if (cnt > 64) cnt = 64;
            int sreg = 0; float wreg = 0.f;
            if (lane < cnt) { sreg = esrc[e + lane]; wreg = rout[sreg]; }
            int j = 0;
            for (; j + 4 <= cnt; j += 4) {
                int s0 = __shfl(sreg, j),     s1 = __shfl(sreg, j + 1);
                int s2 = __shfl(sreg, j + 2), s3 = __shfl(sreg, j + 3);
                float w0 = __shfl(wreg, j),     w1 = __shfl(wreg, j + 1);
                float w2 = __shfl(wreg, j + 2), w3 = __shfl(wreg, j + 3);
                float2 v0 = *(const float2*)(Xc + (size_t)s0 * DD_);
                float2 v1 = *(const float2*)(Xc + (size_t)s1 * DD_);
                float2 v2 = *(const float2*)(Xc + (size_t)s2 * DD_);
                float2 v3 = *(const float2*)(Xc + (size_t)s3 * DD_);
                a0 = fmaf(w0, v0.x, a0); a1 = fmaf(w0, v0.y, a1);
                a0 = fmaf(w1, v1.x, a0); a1 = fmaf(w1, v1.y, a1);
                a0 = fmaf(w2, v2.x, a0); a1 = fmaf(w2, v2.y, a1);
                a0 = fmaf(w3, v3.x, a0); a1 = fmaf(w3, v3.y, a1);
                if (UNW) {
                    u0 += (v0.x + v1.x) + (v2.x + v3.x);
                    u1 += (v0.y + v1.y) + (v2.y + v3.y);
                }
            }
            for (; j < cnt; ++j) {
                int sj = __shfl(sreg, j); float wj = __shfl(wreg, j);
                float2 v = *(const float2*)(Xc + (size_t)sj * DD_);
                a0 = fmaf(wj, v.x, a0); a1 = fmaf(wj, v.y, a1);
                if (UNW) { u0 += v.x; u1 += v.y; }
            }
            e += cnt;
        }
        float ri = rin[node];
        packbuf[w][lane * 2] = a0 * ri;
        packbuf[w][lane * 2 + 1] = a1 * ri;
        LGKM0;
        if (lane < 16) {
            uint4 hw, lw;
            split8(&packbuf[w][(lane >> 2) * 32 + (lane & 3) * 8], hw, lw);
            int kb = slice * 4 + (lane >> 2);
            int lo = (lane & 3) * 16 + (node & 15);
            size_t base = (((size_t)(node >> 4) * 16 + kb) * 64 + lo) * 8;
            *(uint4*)(dh + base) = hw;
            *(uint4*)(dl + base) = lw;
        }
        if (UNW) {
            float2 q = *(const float2*)(Xc + (size_t)node * DD_);
            mrAcc = fmaf(q.x, u0, mrAcc);
            mrAcc = fmaf(q.y, u1, mrAcc);
        }
    }
    if (UNW) {
        for (int off = 32; off; off >>= 1) mrAcc += __shfl_xor(mrAcc, off);
        if (lane == 0) mred[w] = mrAcc;
        __syncthreads();
        if (threadIdx.x == 0)
            atomicAdd(&gacc[5], mred[0] + mred[1] + mred[2] + mred[3]);
    }
}

// ---------------- fused row-norm + MFMA-pack (wave-per-row, grid-stride) -------
template<int NORM>
__global__ __launch_bounds__(256) void k_rowpack(
    const float* __restrict__ src, const int* __restrict__ gidx,
    const float* __restrict__ scaleIn, float* __restrict__ scaleOut, int nrows,
    unsigned short* __restrict__ dh, unsigned short* __restrict__ dl) {
    int w = threadIdx.x >> 6, lane = threadIdx.x & 63;
    for (int r = blockIdx.x * 4 + w; r < nrows; r += gridDim.x * 4) {
        int rs = gidx ? gidx[r] : r;
        const float4* p = (const float4*)(src + (size_t)rs * DD_);
        float4 x = p[lane * 2], y = p[lane * 2 + 1];
        float sc;
        if (NORM) {
            float s = x.x * x.x + x.y * x.y + x.z * x.z + x.w * x.w
                    + y.x * y.x + y.y * y.y + y.z * y.z + y.w * y.w;
            for (int off = 32; off; off >>= 1) s += __shfl_xor(s, off);
            sc = 1.0f / sqrtf(s + 1e-12f);
            if (scaleOut && lane == 0) scaleOut[r] = sc;
        } else {
            sc = scaleIn ? scaleIn[rs] : 1.0f;
        }
        float vals[8] = {x.x*sc, x.y*sc, x.z*sc, x.w*sc, y.x*sc, y.y*sc, y.z*sc, y.w*sc};
        uint4 hw, lw;
        split8(vals, hw, lw);
        size_t base = (((size_t)(r >> 4) * 16 + (lane >> 2)) * 64 + (lane & 3) * 16 + (r & 15)) * 8;
        *(uint4*)(dh + base) = hw;
        *(uint4*)(dl + base) = lw;
    }
}

// transpose-pack a [512,512] weight: Bp rows = output cols
__global__ __launch_bounds__(256) void k_wpack(
    const float* __restrict__ W,
    unsigned short* __restrict__ dh, unsigned short* __restrict__ dl) {
    int u = threadIdx.x >> 6, lane = threadIdx.x & 63;
    int mt = blockIdx.x, kb = blockIdx.y * 4 + u;
    int n = mt * 16 + (lane & 15);
    int k = kb * 32 + (lane >> 4) * 8;
    float vals[8];
    #pragma unroll
    for (int j = 0; j < 8; ++j) vals[j] = W[(size_t)(k + j) * DD_ + n];
    uint4 hw, lw;
    split8(vals, hw, lw);
    size_t base = (((size_t)mt * 16 + kb) * 64 + lane) * 8;
    *(uint4*)(dh + base) = hw;
    *(uint4*)(dl + base) = lw;
}

// ---------------- MFMA GEMM, C = A . B^T via split-bf16 ----------
// THREE=1: 3-mfma hi/lo (hh+hl+lh). THREE=0: 2-mfma (hh+hl) — dist GEMM only.
// MODE 0: dist — store C fp32 to Cout (stride KK_)
// MODE 2: dense — store C+bias (opt relu) to Cout (stride DD_), rows < Mrows
// MODE 4: fused Wd — grid (8,47): bx<4 = dense (Wd1,bias,store QE);
//         bx>=4 = rec loss (Wd2 at B+2*WPACKE, bias2) -> gacc[3]. bx==4 blocks
//         additionally fold the commit loss sum((q-h)^2) from the A tile -> gacc[2].
template<int MODE, int THREE>
__global__ __launch_bounds__(256) void gemm_mfma(
    const unsigned short* __restrict__ Ah, const unsigned short* __restrict__ Al,
    const unsigned short* __restrict__ Bh, const unsigned short* __restrict__ Bl,
    float* __restrict__ Cout, const float* __restrict__ bias,
    const float* __restrict__ Ref, int relu, int Mrows,
    float* __restrict__ gacc, const float* __restrict__ bias2) {
    int bx = blockIdx.x, by = blockIdx.y;
    int side = (MODE == 4) ? (bx >> 2) : 0;
    int bxe  = (MODE == 4) ? (bx & 3) : bx;
    __shared__ char lds[32768];  // Ah|Al|Bh|Bl tiles, 8 KB each
    __shared__ float wred0[4], wred1[4];
    int tid = threadIdx.x;
    int wave = tid >> 6, lane = tid & 63;
    int gmtA = by * 8, gmtB = bxe * 8;
    const unsigned short* garr; int gmt0;
    if (wave == 0)      { garr = Ah; gmt0 = gmtA; }
    else if (wave == 1) { garr = Al; gmt0 = gmtA; }
    else if (wave == 2) { garr = Bh + (size_t)side * 2 * WPACKE; gmt0 = gmtB; }
    else                { garr = Bl + (size_t)side * 2 * WPACKE; gmt0 = gmtB; }
    char* ldst = lds + wave * 8192;
    f32x4 acc[4][4];
    #pragma unroll
    for (int i = 0; i < 4; ++i)
        #pragma unroll
        for (int j = 0; j < 4; ++j) acc[i][j] = (f32x4){0.f, 0.f, 0.f, 0.f};
    float commitAcc = 0.f;
    int wm = wave >> 1, wn = wave & 1;
    for (int kb = 0; kb < 16; ++kb) {
        if (THREE || wave != 1) {
            #pragma unroll
            for (int t = 0; t < 8; ++t) {
                const char* g = (const char*)garr + (((size_t)(gmt0 + t) * 16 + kb) * 1024) + lane * 16;
                gld_lds16(ldst + t * 1024 + lane * 16, g);
            }
        }
        __syncthreads();
        // commit-loss fold: reconstruct q from the A tile, compare vs h (=Ref)
        if (MODE == 4 && bx == 4) {
            int rg = tid >> 1, half = tid & 1;
            int m = by * 128 + rg;
            if (m < Mrows) {
                int tt = rg >> 4, r = rg & 15;
                const float* hp = Ref + (size_t)m * DD_ + kb * 32 + half * 16;
                float4 h0 = ((const float4*)hp)[0], h1 = ((const float4*)hp)[1];
                float4 h2 = ((const float4*)hp)[2], h3 = ((const float4*)hp)[3];
                float hv[16] = {h0.x,h0.y,h0.z,h0.w, h1.x,h1.y,h1.z,h1.w,
                                h2.x,h2.y,h2.z,h2.w, h3.x,h3.y,h3.z,h3.w};
                #pragma unroll
                for (int j2 = 0; j2 < 16; ++j2) {
                    int sub = half * 2 + (j2 >> 3), j = j2 & 7;
                    int off = tt * 1024 + (sub * 16 + r) * 16 + j * 2;
                    u32 hb = *(const unsigned short*)(lds + off);
                    u32 lb = *(const unsigned short*)(lds + 8192 + off);
                    float q = __uint_as_float(hb << 16) + __uint_as_float(lb << 16);
                    float d = q - hv[j2];
                    commitAcc = fmaf(d, d, commitAcc);
                }
            }
        }
        bf16x8 a_h[4], a_l[4], b_h[4], b_l[4];
        #pragma unroll
        for (int i = 0; i < 4; ++i) {
            int at = wm * 4 + i, bt = wn * 4 + i;
            a_h[i] = *(const bf16x8*)(lds + 0     + at * 1024 + lane * 16);
            if (THREE) a_l[i] = *(const bf16x8*)(lds + 8192 + at * 1024 + lane * 16);
            b_h[i] = *(const bf16x8*)(lds + 16384 + bt * 1024 + lane * 16);
            b_l[i] = *(const bf16x8*)(lds + 24576 + bt * 1024 + lane * 16);
        }
        #pragma unroll
        for (int i = 0; i < 4; ++i)
            #pragma unroll
            for (int j = 0; j < 4; ++j) {
                acc[i][j] = __builtin_amdgcn_mfma_f32_16x16x32_bf16(a_h[i], b_h[j], acc[i][j], 0, 0, 0);
                acc[i][j] = __builtin_amdgcn_mfma_f32_16x16x32_bf16(a_h[i], b_l[j], acc[i][j], 0, 0, 0);
                if (THREE)
                    acc[i][j] = __builtin_amdgcn_mfma_f32_16x16x32_bf16(a_l[i], b_h[j], acc[i][j], 0, 0, 0);
            }
        __syncthreads();
    }
    // C/D layout: col = lane&15, row = (lane>>4)*4 + reg
    int m_base = by * 128 + wm * 64;
    int n_base = bxe * 128 + wn * 64;
    int rq = lane >> 4, cc = lane & 15;
    if (MODE == 0) {
        #pragma unroll
        for (int i = 0; i < 4; ++i) {
            int m = m_base + i * 16 + rq * 4;
            #pragma unroll
            for (int j = 0; j < 4; ++j) {
                int n = n_base + j * 16 + cc;
                #pragma unroll
                for (int r = 0; r < 4; ++r) {
                    if (m + r < NN_) Cout[(size_t)(m + r) * KK_ + n] = acc[i][j][r];
                }
            }
        }
    } else if (MODE == 2 || (MODE == 4 && side == 0)) {
        #pragma unroll
        for (int i = 0; i < 4; ++i) {
            int m = m_base + i * 16 + rq * 4;
            #pragma unroll
            for (int j = 0; j < 4; ++j) {
                int n = n_base + j * 16 + cc;
                float bv = bias[n];
                #pragma unroll
                for (int r = 0; r < 4; ++r) {
                    if (m + r < Mrows) {
                        float v = acc[i][j][r] + bv;
                        if (relu) v = fmaxf(v, 0.f);
                        Cout[(size_t)(m + r) * DD_ + n] = v;
                    }
                }
            }
        }
    } else {  // MODE 4 rec-loss side
        const float* bs = bias2;
        float s = 0.f;
        #pragma unroll
        for (int i = 0; i < 4; ++i) {
            int m = m_base + i * 16 + rq * 4;
            #pragma unroll
            for (int j = 0; j < 4; ++j) {
                int n = n_base + j * 16 + cc;
                float bv = bs[n];
                #pragma unroll
                for (int r = 0; r < 4; ++r) {
                    if (m + r < Mrows) {
                        float d = Ref[(size_t)(m + r) * DD_ + n] - (acc[i][j][r] + bv);
                        s = fmaf(d, d, s);
                    }
                }
            }
        }
        for (int off = 32; off; off >>= 1) s += __shfl_xor(s, off);
        if (lane == 0) wred0[wave] = s;
        if (MODE == 4 && bx == 4) {
            float c = commitAcc;
            for (int off = 32; off; off >>= 1) c += __shfl_xor(c, off);
            if (lane == 0) wred1[wave] = c;
        }
        __syncthreads();
        if (tid == 0) {
            atomicAdd(&gacc[3], wred0[0] + wred0[1] + wred0[2] + wred0[3]);
            if (MODE == 4 && bx == 4)
                atomicAdd(&gacc[2], wred1[0] + wred1[1] + wred1[2] + wred1[3]);
        }
    }
}

// ---------------- dedicated rpass GEMM: 128x128 triangular, XCD-chunked -------
// R7 post-mortem: 256x128 cut FETCH 94->65MB but occupancy 8% (188 VGPR,
// 49KB LDS, 1 blk/CU) killed latency hiding -> 117us. Revert to the proven
// 128^2 shape (acc[4][4], 32KB LDS, ~3-4 blk/CU; 78.7us in r5) but keep:
//  (a) DEDICATED kernel — no template co-compilation (rule #19 regalloc
//      perturbation cost r6 ~16us), (b) XCD-chunked triangle order
//      L=(b&7)*141+(b>>3) (bijective, 1128=8*141): consecutive L share the
//      B-panel -> same-XCD L2 reuse.
__global__ __launch_bounds__(256) void gemm_rpass(
    const unsigned short* __restrict__ Qh, const unsigned short* __restrict__ Ql,
    float* __restrict__ gacc, u32* __restrict__ minKey, u32* __restrict__ maxKey) {
    int Lp = blockIdx.x;
    int L = (Lp & 7) * 141 + (Lp >> 3);
    int bx = (int)((sqrtf(8.f * (float)L + 1.f) - 1.f) * 0.5f);
    while ((bx + 1) * (bx + 2) / 2 <= L) ++bx;
    while (bx * (bx + 1) / 2 > L) --bx;
    int by = L - bx * (bx + 1) / 2;     // bx >= by
    __shared__ char lds[32768];  // Ah|Al|Bh|Bl tiles, 8 KB each
    __shared__ float wr0[4], wr1[4], wr2[4], wr3[4];
    int tid = threadIdx.x;
    int wave = tid >> 6, lane = tid & 63;
    int gmtA = by * 8, gmtB = bx * 8;
    const unsigned short* garr; int gmt0;
    if (wave == 0)      { garr = Qh; gmt0 = gmtA; }
    else if (wave == 1) { garr = Ql; gmt0 = gmtA; }
    else if (wave == 2) { garr = Qh; gmt0 = gmtB; }
    else                { garr = Ql; gmt0 = gmtB; }
    char* ldst = lds + wave * 8192;
    f32x4 acc[4][4];
    #pragma unroll
    for (int i = 0; i < 4; ++i)
        #pragma unroll
        for (int j = 0; j < 4; ++j) acc[i][j] = (f32x4){0.f, 0.f, 0.f, 0.f};
    int wm = wave >> 1, wn = wave & 1;
    for (int kb = 0; kb < 16; ++kb) {
        #pragma unroll
        for (int t = 0; t < 8; ++t) {
            const char* g = (const char*)garr + (((size_t)(gmt0 + t) * 16 + kb) * 1024) + lane * 16;
            gld_lds16(ldst + t * 1024 + lane * 16, g);
        }
        __syncthreads();
        bf16x8 a_h[4], a_l[4], b_h[4], b_l[4];
        #pragma unroll
        for (int i = 0; i < 4; ++i) {
            int at = wm * 4 + i, bt = wn * 4 + i;
            a_h[i] = *(const bf16x8*)(lds + 0     + at * 1024 + lane * 16);
            a_l[i] = *(const bf16x8*)(lds + 8192  + at * 1024 + lane * 16);
            b_h[i] = *(const bf16x8*)(lds + 16384 + bt * 1024 + lane * 16);
            b_l[i] = *(const bf16x8*)(lds + 24576 + bt * 1024 + lane * 16);
        }
        #pragma unroll
        for (int i = 0; i < 4; ++i)
            #pragma unroll
            for (int j = 0; j < 4; ++j) {
                acc[i][j] = __builtin_amdgcn_mfma_f32_16x16x32_bf16(a_h[i], b_h[j], acc[i][j], 0, 0, 0);
                acc[i][j] = __builtin_amdgcn_mfma_f32_16x16x32_bf16(a_h[i], b_l[j], acc[i][j], 0, 0, 0);
                acc[i][j] = __builtin_amdgcn_mfma_f32_16x16x32_bf16(a_l[i], b_h[j], acc[i][j], 0, 0, 0);
            }
        __syncthreads();
    }
    int m_base = by * 128 + wm * 64;
    int n_base = bx * 128 + wn * 64;
    int rq = lane >> 4, cc = lane & 15;
    float tsum = 0.f, tsq = 0.f, tmin = 3.4e38f, tmax = -3.4e38f;
    #pragma unroll
    for (int i = 0; i < 4; ++i) {
        #pragma unroll
        for (int j = 0; j < 4; ++j) {
            #pragma unroll
            for (int r = 0; r < 4; ++r) {
                int m = m_base + i * 16 + rq * 4 + r;
                int n = n_base + j * 16 + cc;
                if (m < NN_ && n < NN_ && n >= m) {
                    float v = acc[i][j][r];
                    float w = (n > m) ? 2.f : 1.f;
                    tsum += w * v;
                    tsq  += w * v * v;
                    tmin = fminf(tmin, v);
                    tmax = fmaxf(tmax, v);
                }
            }
        }
    }
    for (int off = 32; off; off >>= 1) {
        tsum += __shfl_xor(tsum, off);
        tsq  += __shfl_xor(tsq, off);
        tmin = fminf(tmin, __shfl_xor(tmin, off));
        tmax = fmaxf(tmax, __shfl_xor(tmax, off));
    }
    if (lane == 0) { wr0[wave] = tsum; wr1[wave] = tsq; wr2[wave] = tmin; wr3[wave] = tmax; }
    __syncthreads();
    if (tid == 0) {
        atomicAdd(&gacc[0], wr0[0] + wr0[1] + wr0[2] + wr0[3]);
        atomicAdd(&gacc[1], wr1[0] + wr1[1] + wr1[2] + wr1[3]);
        atomicMin(minKey, okey(fminf(fminf(wr2[0], wr2[1]), fminf(wr2[2], wr2[3]))));
        atomicMax(maxKey, okey(fmaxf(fmaxf(wr3[0], wr3[1]), fmaxf(wr3[2], wr3[3]))));
    }
}

// exact-fp32 argmax rescue — persistent, wave-per-row.
__global__ __launch_bounds__(256) void k_rescore(
    const float* __restrict__ dist, const float* __restrict__ h,
    const float* __restrict__ rnorm, const float* __restrict__ cb,
    const float* __restrict__ scale, int* __restrict__ ind) {
    int w = threadIdx.x >> 6, lane = threadIdx.x & 63;
    for (int row = blockIdx.x * 4 + w; row < NN_; row += gridDim.x * 4) {
        const float4* dr4 = (const float4*)(dist + (size_t)row * KK_);
        float4 vbuf[16];
        float lmax = -3.4e38f;
        #pragma unroll
        for (int it = 0; it < 16; ++it) {
            float4 v = dr4[lane + it * 64];
            vbuf[it] = v;
            lmax = fmaxf(lmax, fmaxf(fmaxf(v.x, v.y), fmaxf(v.z, v.w)));
        }
        for (int off = 32; off; off >>= 1) lmax = fmaxf(lmax, __shfl_xor(lmax, off));
        float thr = lmax - 1e-3f;
        float hr = rnorm[row];
        const float* hp = h + (size_t)row * DD_;
        u64 best = 0;
        #pragma unroll 1
        for (int it = 0; it < 16; ++it) {
            float4 v = vbuf[it];
            u32 m4 = (v.x >= thr ? 1u : 0u) | (v.y >= thr ? 2u : 0u)
                   | (v.z >= thr ? 4u : 0u) | (v.w >= thr ? 8u : 0u);
            u64 bal = __ballot(m4 != 0);
            while (bal) {
                int l = __ffsll((unsigned long long)bal) - 1;
                bal &= bal - 1;
                u32 mm = __shfl(m4, l);
                while (mm) {
                    int j = __ffs(mm) - 1;
                    mm &= mm - 1;
                    int col = (l + it * 64) * 4 + j;
                    const float* cp = cb + (size_t)col * DD_;
                    float dot = 0.f;
                    #pragma unroll
                    for (int jj = 0; jj < 8; ++jj)
                        dot = fmaf(hp[lane + jj * 64], cp[lane + jj * 64], dot);
                    for (int off = 32; off; off >>= 1) dot += __shfl_xor(dot, off);
                    u64 key = packKey(dot * hr * scale[col], col);
                    if (key > best) best = key;   // dot wave-uniform after butterfly
                }
            }
        }
        if (lane == 0) ind[row] = (int)(~(u32)(best & 0xFFFFFFFFull));
    }
}

// ---------------- fp32 GEMM (kept only for the 6000x40 output) ----------------
__global__ __launch_bounds__(256) void gemm_nn(
    const float* __restrict__ A, const float* __restrict__ B,
    const float* __restrict__ bias, float* __restrict__ C,
    int M, int Ncols, int Kdim) {
    __shared__ float As[16][68];
    __shared__ float Bs[16][68];
    int tid = threadIdx.x;
    int tx = tid & 15, ty = tid >> 4;
    int m0 = blockIdx.y * 64, n0 = blockIdx.x * 64;
    float cv[4][4] = {};
    int ar = tid >> 2;
    int ak = (tid & 3) << 2;
    int am = m0 + ar;
    const float* Arow = (am < M) ? (A + (size_t)am * Kdim) : nullptr;
    int bk = tid >> 4;
    int bn = (tid & 15) << 2;
    for (int k0 = 0; k0 < Kdim; k0 += 16) {
        float4 av = make_float4(0.f, 0.f, 0.f, 0.f);
        if (Arow) av = *(const float4*)(Arow + k0 + ak);
        As[ak + 0][ar] = av.x; As[ak + 1][ar] = av.y;
        As[ak + 2][ar] = av.z; As[ak + 3][ar] = av.w;
        float4 bv = make_float4(0.f, 0.f, 0.f, 0.f);
        if (n0 + bn < Ncols)
            bv = *(const float4*)(B + (size_t)(k0 + bk) * Ncols + n0 + bn);
        Bs[bk][bn + 0] = bv.x; Bs[bk][bn + 1] = bv.y;
        Bs[bk][bn + 2] = bv.z; Bs[bk][bn + 3] = bv.w;
        __syncthreads();
        #pragma unroll
        for (int kk = 0; kk < 16; ++kk) {
            float4 a4 = *(const float4*)&As[kk][ty << 2];
            float4 b4 = *(const float4*)&Bs[kk][tx << 2];
            float ax[4] = {a4.x, a4.y, a4.z, a4.w};
            float bx[4] = {b4.x, b4.y, b4.z, b4.w};
            #pragma unroll
            for (int i = 0; i < 4; ++i)
                #pragma unroll
                for (int j = 0; j < 4; ++j)
                    cv[i][j] = fmaf(ax[i], bx[j], cv[i][j]);
        }
        __syncthreads();
    }
    #pragma unroll
    for (int i = 0; i < 4; ++i) {
        int m = m0 + (ty << 2) + i;
        if (m >= M) continue;
        #pragma unroll
        for (int j = 0; j < 4; ++j) {
            int n = n0 + (tx << 2) + j;
            if (n >= Ncols) continue;
            C[(size_t)m * Ncols + n] = cv[i][j] + bias[n];
        }
    }
}

// ---------------- edge multiplicity hash (for sum m^2 only) ----------------
__global__ void k_hash(const int* __restrict__ src, const int* __restrict__ dst,
                       int* __restrict__ hkey, int* __restrict__ hcnt) {
    int e = blockIdx.x * 256 + threadIdx.x;
    if (e >= EE_) return;
    int key = dst[e] * NN_ + src[e];
    u32 h = ((u32)key * 2654435761u) & HMASK;
    while (true) {
        int old = atomicCAS(&hkey[h], -1, key);
        if (old == -1 || old == key) { atomicAdd(&hcnt[h], 1); break; }
        h = (h + 1) & HMASK;
    }
}

__global__ __launch_bounds__(256) void k_m2scan(const int* __restrict__ hcnt, float* __restrict__ gacc) {
    float s = 0.f;
    for (int i = blockIdx.x * 256 + threadIdx.x; i < HSZ; i += gridDim.x * 256) {
        float c = (float)hcnt[i];
        s = fmaf(c, c, s);
    }
    for (int off = 32; off; off >>= 1) s += __shfl_xor(s, off);
    __shared__ float w1[4];
    int lane = threadIdx.x & 63, wv = threadIdx.x >> 6;
    if (lane == 0) w1[wv] = s;
    __syncthreads();
    if (threadIdx.x == 0) atomicAdd(&gacc[4], w1[0] + w1[1] + w1[2] + w1[3]);
}

// ---------------- final loss assembly ----------------
__global__ void k_final(const float* __restrict__ gacc, const u32* __restrict__ minKey,
                        const u32* __restrict__ maxKey, float* __restrict__ lossOut) {
    if (threadIdx.x != 0 || blockIdx.x != 0) return;
    double Rsum = gacc[0], Rsq = gacc[1], commitS = gacc[2], recS = gacc[3];
    double m2 = gacc[4], mr = gacc[5], ms = (double)EE_;
    double mn = (double)dkey(*minKey);
    double mx = (double)dkey(*maxKey);
    double den = mx - mn;
    double NN2 = (double)NN_ * (double)NN_;
    double sum_aq2 = (Rsq - 2.0 * mn * Rsum + NN2 * mn * mn) / (den * den);
    double sum_maq = (mr - mn * ms) / den;
    double total = sum_aq2 + m2 - 2.0 * sum_maq;
    double edge = sqrt(total / NN2);
    double commit = 0.25 * commitS / ((double)NN_ * (double)DD_);
    double rec = recS / ((double)NN_ * (double)DD_);
    *lossOut = (float)(rec + edge + commit);
}

extern "C" void kernel_launch(void* const* d_in, const int* in_sizes, int n_in,
                              void* d_out, int out_size, void* d_ws, size_t ws_size,
                              hipStream_t stream) {
    const float* feats = (const float*)d_in[0];
    const float* W1 = (const float*)d_in[1];
    const float* b1 = (const float*)d_in[2];
    const float* W2 = (const float*)d_in[3];
    const float* b2v = (const float*)d_in[4];
    const float* Wd1 = (const float*)d_in[5];
    const float* bd1 = (const float*)d_in[6];
    const float* Wd2 = (const float*)d_in[7];
    const float* bd2 = (const float*)d_in[8];
    const float* Wl = (const float*)d_in[9];
    const float* bl = (const float*)d_in[10];
    const float* cb = (const float*)d_in[11];
    const int* src = (const int*)d_in[12];
    const int* dst = (const int*)d_in[13];

    float* outF = (float*)d_out;
    float* lossOut = outF + (size_t)NN_ * OO_;     // element 240000
    float* distOut = lossOut + 1;                  // element 240001

    char* w = (char*)d_ws;
    size_t off = 0;
    auto alloc = [&](size_t bytes) -> void* {
        void* p = w + off;
        off = (off + bytes + 255) & ~(size_t)255;
        return p;
    };
    // zone0: zero-init
    float* gacc = (float*)alloc(64);
    u32* maxKey = (u32*)alloc(4);
    int* degin = (int*)alloc((size_t)NN_ * 4);
    int* degout = (int*)alloc((size_t)NN_ * 4);
    int* cursor = (int*)alloc((size_t)NN_ * 4);
    int* hcnt = (int*)alloc((size_t)HSZ * 4);
    size_t z0end = off;
    // zone1: 0xFF-init
    int* hkey = (int*)alloc((size_t)HSZ * 4);
    u32* minKey = (u32*)alloc(4);
    size_t z1end = off;
    // uninit scratch
    int* offs = (int*)alloc((size_t)(NN_ + 1) * 4);
    int* esrc = (int*)alloc((size_t)EE_ * 4);
    float* rin = (float*)alloc((size_t)NN_ * 4);
    float* rout = (float*)alloc((size_t)NN_ * 4);
    int* ind = (int*)alloc((size_t)NN_ * 4);
    float* scale = (float*)alloc((size_t)KK_ * 4);
    float* rnorm = (float*)alloc((size_t)NN_ * 4);
    float* h = (float*)alloc((size_t)NN_ * DD_ * 4);       // h, later h2
    float* QE = (float*)alloc((size_t)NN_ * DD_ * 4);
    const size_t NPACK = (size_t)MT_A * 16 * DD_;          // node-sized packed half
    unsigned short* P1 = (unsigned short*)alloc(NPACK * 2 * 2);  // aggp -> qcp -> agg2p
    unsigned short* P2 = (unsigned short*)alloc(NPACK * 2 * 2);  // hnp -> QEp
    unsigned short* enp = (unsigned short*)alloc((size_t)KK_ * DD_ * 2 * 2);
    const size_t WPACK = (size_t)32 * 16 * DD_;            // 512-row packed half
    unsigned short* W1p = (unsigned short*)alloc(WPACK * 2 * 2);
    unsigned short* Wd1p = (unsigned short*)alloc(WPACK * 2 * 2);  // MUST stay
    unsigned short* Wd2p = (unsigned short*)alloc(WPACK * 2 * 2);  // contiguous (MODE4)
    unsigned short* W2p = (unsigned short*)alloc(WPACK * 2 * 2);

    unsigned short* aggp_h = P1,  *aggp_l = P1 + NPACK;
    unsigned short* qcp_h  = P1,  *qcp_l  = P1 + NPACK;
    unsigned short* ag2p_h = P1,  *ag2p_l = P1 + NPACK;
    unsigned short* hnp_h  = P2,  *hnp_l  = P2 + NPACK;
    unsigned short* QEp_h  = P2,  *QEp_l  = P2 + NPACK;
    unsigned short* enp_h  = enp, *enp_l  = enp + (size_t)KK_ * DD_;

    hipMemsetAsync(w, 0, z0end, stream);
    hipMemsetAsync(w + z0end, 0xFF, z1end - z0end, stream);

    const int TB = 256;
    k_deg<<<(EE_ + TB - 1) / TB, TB, 0, stream>>>(src, dst, degout, degin);
    k_rsqrtdeg<<<(NN_ + TB - 1) / TB, TB, 0, stream>>>(degout, degin, rout, rin);
    k_scan<<<1, 1024, 0, stream>>>(degin, offs, NN_);
    k_fill<<<(EE_ + TB - 1) / TB, TB, 0, stream>>>(src, dst, offs, cursor, esrc);
    k_wpack<<<dim3(32, 4), TB, 0, stream>>>(W1, W1p, W1p + WPACK);
    k_wpack<<<dim3(32, 4), TB, 0, stream>>>(Wd1, Wd1p, Wd1p + WPACK);
    k_wpack<<<dim3(32, 4), TB, 0, stream>>>(Wd2, Wd2p, Wd2p + WPACK);
    k_wpack<<<dim3(32, 4), TB, 0, stream>>>(W2, W2p, W2p + WPACK);
    k_aggs<0><<<1024, TB, 0, stream>>>(feats, esrc, offs, rout, rin, aggp_h, aggp_l, nullptr);
    gemm_mfma<2,1><<<dim3(4, NB_N), TB, 0, stream>>>(aggp_h, aggp_l, W1p, W1p + WPACK,
                                                     h, b1, nullptr, 1, NN_, nullptr, nullptr);
    k_rowpack<1><<<1024, TB, 0, stream>>>(h, nullptr, nullptr, rnorm, NN_, hnp_h, hnp_l);
    k_rowpack<1><<<1024, TB, 0, stream>>>(cb, nullptr, nullptr, scale, KK_, enp_h, enp_l);
    gemm_mfma<0,0><<<dim3(KK_ / 128, NB_N), TB, 0, stream>>>(hnp_h, hnp_l, enp_h, enp_l,
                                                             distOut, nullptr, nullptr, 0, NN_,
                                                             nullptr, nullptr);
    k_rescore<<<1024, TB, 0, stream>>>(distOut, h, rnorm, cb, scale, ind);
    k_rowpack<0><<<1024, TB, 0, stream>>>(cb, ind, scale, nullptr, NN_, qcp_h, qcp_l);
    // fused Wd1+Wd2 GEMM: stores QE (bx<4), rec loss (bx>=4), commit fold (bx==4)
    gemm_mfma<4,1><<<dim3(8, NB_N), TB, 0, stream>>>(qcp_h, qcp_l, Wd1p, Wd1p + WPACK,
                                                     QE, bd1, h, 0, NN_, gacc, bd2);
    k_rowpack<0><<<1024, TB, 0, stream>>>(QE, nullptr, nullptr, nullptr, NN_, QEp_h, QEp_l);
    gemm_rpass<<<1128, TB, 0, stream>>>(QEp_h, QEp_l, gacc, minKey, maxKey);
    k_hash<<<(EE_ + TB - 1) / TB, TB, 0, stream>>>(src, dst, hkey, hcnt);
    k_m2scan<<<512, TB, 0, stream>>>(hcnt, gacc);
    k_aggs<1><<<1024, TB, 0, stream>>>(QE, esrc, offs, rout, rin, ag2p_h, ag2p_l, gacc);
    gemm_mfma<2,1><<<dim3(4, NB_N), TB, 0, stream>>>(ag2p_h, ag2p_l, W2p, W2p + WPACK,
                                                     h, b2v, nullptr, 1, NN_, nullptr, nullptr);
    gemm_nn<<<dim3(1, 94), TB, 0, stream>>>(h, Wl, bl, outF, NN_, OO_, DD_);
    k_final<<<1, 64, 0, stream>>>(gacc, minKey, maxKey, lossOut);
}

// Round 9
// 666.508 us; speedup vs baseline: 1.0327x; 1.0129x over previous
//
#include <hip/hip_runtime.h>

typedef unsigned int u32;
typedef unsigned long long u64;

#define NN_ 6000
#define EE_ 192000
#define DD_ 512
#define KK_ 4096
#define OO_ 40
#define HSZ (1 << 19)
#define HMASK (HSZ - 1)
#define MT_A 376   // ceil(6000/16) m-tiles for node-sized packed arrays
#define NB_N 47    // 6016/128 blocks
#define WPACKE (32 * 16 * 512)   // elems per packed 512-row half

typedef __bf16 bf16x8 __attribute__((ext_vector_type(8)));
typedef float f32x4 __attribute__((ext_vector_type(4)));

__device__ __forceinline__ u32 okey(float f) {
    u32 u = __float_as_uint(f);
    return (u & 0x80000000u) ? ~u : (u | 0x80000000u);
}
__device__ __forceinline__ float dkey(u32 u) {
    u32 b = (u & 0x80000000u) ? (u ^ 0x80000000u) : ~u;
    return __uint_as_float(b);
}
__device__ __forceinline__ u64 packKey(float v, int col) {
    return ((u64)okey(v) << 32) | (u32)(~(u32)col);
}
__device__ __forceinline__ unsigned short f2bf_rne(float f) {
    u32 x = __float_as_uint(f);
    u32 r = x + 0x7fffu + ((x >> 16) & 1u);
    return (unsigned short)(r >> 16);
}
__device__ __forceinline__ void gld_lds16(void* l, const void* g) {
    __builtin_amdgcn_global_load_lds(
        (const __attribute__((address_space(1))) unsigned int*)g,
        (__attribute__((address_space(3))) unsigned int*)l, 16, 0, 0);
}
// compiler+hw ordering fence for same-wave LDS write->read (rule #18 analog)
#define LGKM0 do { asm volatile("s_waitcnt lgkmcnt(0)" ::: "memory"); __builtin_amdgcn_sched_barrier(0); } while (0)

// ---------------- graph prep ----------------
__global__ void k_deg(const int* __restrict__ src, const int* __restrict__ dst,
                      int* __restrict__ degout, int* __restrict__ degin) {
    int e = blockIdx.x * 256 + threadIdx.x;
    if (e >= EE_) return;
    atomicAdd(&degout[src[e]], 1);
    atomicAdd(&degin[dst[e]], 1);
}

__global__ void k_rsqrtdeg(const int* __restrict__ degout, const int* __restrict__ degin,
                           float* __restrict__ rout, float* __restrict__ rin) {
    int i = blockIdx.x * 256 + threadIdx.x;
    if (i >= NN_) return;
    int doV = degout[i]; if (doV < 1) doV = 1;
    int diV = degin[i];  if (diV < 1) diV = 1;
    rout[i] = rsqrtf((float)doV);
    rin[i]  = rsqrtf((float)diV);
}

// 6000-elem scan, 1 block x 1024 threads, 6 elems/thread (20 syncs)
__global__ void k_scan(const int* __restrict__ cnt, int* __restrict__ offs, int n) {
    __shared__ int part[1024];
    int t = threadIdx.x;
    int base = t * 6;
    int v[6]; int s = 0;
    #pragma unroll
    for (int j = 0; j < 6; ++j) { int i = base + j; v[j] = (i < n) ? cnt[i] : 0; s += v[j]; }
    part[t] = s;
    __syncthreads();
    for (int off = 1; off < 1024; off <<= 1) {
        int x = (t >= off) ? part[t - off] : 0;
        __syncthreads();
        part[t] += x;
        __syncthreads();
    }
    int run = (t > 0) ? part[t - 1] : 0;
    if (t == 0) offs[0] = 0;
    #pragma unroll
    for (int j = 0; j < 6; ++j) {
        int i = base + j;
        run += v[j];
        if (i < n) offs[i + 1] = run;
    }
}

__global__ void k_fill(const int* __restrict__ src, const int* __restrict__ dst,
                       const int* __restrict__ offs, int* __restrict__ cursor,
                       int* __restrict__ esrc) {
    int e = blockIdx.x * 256 + threadIdx.x;
    if (e >= EE_) return;
    int d = dst[e];
    int pos = offs[d] + atomicAdd(&cursor[d], 1);
    esrc[pos] = src[e];
}

// split 8 floats into bf16 hi/lo packed words
__device__ __forceinline__ void split8(const float* vals, uint4& hw, uint4& lw) {
    u32 h[4], l[4];
    #pragma unroll
    for (int j = 0; j < 4; ++j) {
        unsigned short h0 = f2bf_rne(vals[2*j]),   h1 = f2bf_rne(vals[2*j+1]);
        float hf0 = __uint_as_float((u32)h0 << 16), hf1 = __uint_as_float((u32)h1 << 16);
        unsigned short l0 = f2bf_rne(vals[2*j] - hf0), l1 = f2bf_rne(vals[2*j+1] - hf1);
        h[j] = (u32)h0 | ((u32)h1 << 16);
        l[j] = (u32)l0 | ((u32)l1 << 16);
    }
    hw = make_uint4(h[0], h[1], h[2], h[3]);
    lw = make_uint4(l[0], l[1], l[2], l[3]);
}

// ---------------- persistent sliced aggregation (L2-resident gather) ----------------
template<int UNW>
__global__ __launch_bounds__(256) void k_aggs(
    const float* __restrict__ X, const int* __restrict__ esrc,
    const int* __restrict__ offs, const float* __restrict__ rout,
    const float* __restrict__ rin,
    unsigned short* __restrict__ dh, unsigned short* __restrict__ dl,
    float* __restrict__ gacc) {
    __shared__ float packbuf[4][128];
    __shared__ float mred[4];
    int b = blockIdx.x;                 // [0,1024)
    int xcd = b & 7;                    // heuristic XCD id (round-robin)
    int slice = xcd >> 1;               // 0..3, pinned per XCD pair
    int w = threadIdx.x >> 6, lane = threadIdx.x & 63;
    int wid = ((((b >> 3) << 1) | (xcd & 1)) << 2) + w;  // [0,1024) per slice
    const float* Xc = X + slice * 128 + lane * 2;        // this lane's col pair
    float mrAcc = 0.f;
    for (int node = wid; node < NN_; node += 1024) {
        int beg = offs[node], end = offs[node + 1];
        float a0 = 0.f, a1 = 0.f, u0 = 0.f, u1 = 0.f;
        for (int e = beg; e < end; ) {
            int cnt = end - e; if (cnt > 64) cnt = 64;
            int sreg = 0; float wreg = 0.f;
            if (lane < cnt) { sreg = esrc[e + lane]; wreg = rout[sreg]; }
            int j = 0;
            for (; j + 4 <= cnt; j += 4) {
                int s0 = __shfl(sreg, j),     s1 = __shfl(sreg, j + 1);
                int s2 = __shfl(sreg, j + 2), s3 = __shfl(sreg, j + 3);
                float w0 = __shfl(wreg, j),     w1 = __shfl(wreg, j + 1);
                float w2 = __shfl(wreg, j + 2), w3 = __shfl(wreg, j + 3);
                float2 v0 = *(const float2*)(Xc + (size_t)s0 * DD_);
                float2 v1 = *(const float2*)(Xc + (size_t)s1 * DD_);
                float2 v2 = *(const float2*)(Xc + (size_t)s2 * DD_);
                float2 v3 = *(const float2*)(Xc + (size_t)s3 * DD_);
                a0 = fmaf(w0, v0.x, a0); a1 = fmaf(w0, v0.y, a1);
                a0 = fmaf(w1, v1.x, a0); a1 = fmaf(w1, v1.y, a1);
                a0 = fmaf(w2, v2.x, a0); a1 = fmaf(w2, v2.y, a1);
                a0 = fmaf(w3, v3.x, a0); a1 = fmaf(w3, v3.y, a1);
                if (UNW) {
                    u0 += (v0.x + v1.x) + (v2.x + v3.x);
                    u1 += (v0.y + v1.y) + (v2.y + v3.y);
                }
            }
            for (; j < cnt; ++j) {
                int sj = __shfl(sreg, j); float wj = __shfl(wreg, j);
                float2 v = *(const float2*)(Xc + (size_t)sj * DD_);
                a0 = fmaf(wj, v.x, a0); a1 = fmaf(wj, v.y, a1);
                if (UNW) { u0 += v.x; u1 += v.y; }
            }
            e += cnt;
        }
        float ri = rin[node];
        packbuf[w][lane * 2] = a0 * ri;
        packbuf[w][lane * 2 + 1] = a1 * ri;
        LGKM0;
        if (lane < 16) {
            uint4 hw, lw;
            split8(&packbuf[w][(lane >> 2) * 32 + (lane & 3) * 8], hw, lw);
            int kb = slice * 4 + (lane >> 2);
            int lo = (lane & 3) * 16 + (node & 15);
            size_t base = (((size_t)(node >> 4) * 16 + kb) * 64 + lo) * 8;
            *(uint4*)(dh + base) = hw;
            *(uint4*)(dl + base) = lw;
        }
        if (UNW) {
            float2 q = *(const float2*)(Xc + (size_t)node * DD_);
            mrAcc = fmaf(q.x, u0, mrAcc);
            mrAcc = fmaf(q.y, u1, mrAcc);
        }
    }
    if (UNW) {
        for (int off = 32; off; off >>= 1) mrAcc += __shfl_xor(mrAcc, off);
        if (lane == 0) mred[w] = mrAcc;
        __syncthreads();
        if (threadIdx.x == 0)
            atomicAdd(&gacc[5], mred[0] + mred[1] + mred[2] + mred[3]);
    }
}

// ---------------- fused row-norm + MFMA-pack (wave-per-row, grid-stride) -------
template<int NORM>
__global__ __launch_bounds__(256) void k_rowpack(
    const float* __restrict__ src, const int* __restrict__ gidx,
    const float* __restrict__ scaleIn, float* __restrict__ scaleOut, int nrows,
    unsigned short* __restrict__ dh, unsigned short* __restrict__ dl) {
    int w = threadIdx.x >> 6, lane = threadIdx.x & 63;
    for (int r = blockIdx.x * 4 + w; r < nrows; r += gridDim.x * 4) {
        int rs = gidx ? gidx[r] : r;
        const float4* p = (const float4*)(src + (size_t)rs * DD_);
        float4 x = p[lane * 2], y = p[lane * 2 + 1];
        float sc;
        if (NORM) {
            float s = x.x * x.x + x.y * x.y + x.z * x.z + x.w * x.w
                    + y.x * y.x + y.y * y.y + y.z * y.z + y.w * y.w;
            for (int off = 32; off; off >>= 1) s += __shfl_xor(s, off);
            sc = 1.0f / sqrtf(s + 1e-12f);
            if (scaleOut && lane == 0) scaleOut[r] = sc;
        } else {
            sc = scaleIn ? scaleIn[rs] : 1.0f;
        }
        float vals[8] = {x.x*sc, x.y*sc, x.z*sc, x.w*sc, y.x*sc, y.y*sc, y.z*sc, y.w*sc};
        uint4 hw, lw;
        split8(vals, hw, lw);
        size_t base = (((size_t)(r >> 4) * 16 + (lane >> 2)) * 64 + (lane & 3) * 16 + (r & 15)) * 8;
        *(uint4*)(dh + base) = hw;
        *(uint4*)(dl + base) = lw;
    }
}

// transpose-pack a [512,512] weight: Bp rows = output cols
__global__ __launch_bounds__(256) void k_wpack(
    const float* __restrict__ W,
    unsigned short* __restrict__ dh, unsigned short* __restrict__ dl) {
    int u = threadIdx.x >> 6, lane = threadIdx.x & 63;
    int mt = blockIdx.x, kb = blockIdx.y * 4 + u;
    int n = mt * 16 + (lane & 15);
    int k = kb * 32 + (lane >> 4) * 8;
    float vals[8];
    #pragma unroll
    for (int j = 0; j < 8; ++j) vals[j] = W[(size_t)(k + j) * DD_ + n];
    uint4 hw, lw;
    split8(vals, hw, lw);
    size_t base = (((size_t)mt * 16 + kb) * 64 + lane) * 8;
    *(uint4*)(dh + base) = hw;
    *(uint4*)(dl + base) = lw;
}

// ---------------- MFMA GEMM, C = A . B^T via split-bf16 ----------
// THREE=1: 3-mfma hi/lo (hh+hl+lh). THREE=0: 2-mfma (hh+hl) — dist GEMM only.
// MODE 0: dist — store C fp32 to Cout (stride KK_)
// MODE 2: dense — store C+bias (opt relu) to Cout (stride DD_), rows < Mrows
// MODE 4: fused Wd — grid (8,47): bx<4 = dense (Wd1,bias,store QE);
//         bx>=4 = rec loss (Wd2 at B+2*WPACKE, bias2) -> gacc[3]. bx==4 blocks
//         additionally fold the commit loss sum((q-h)^2) from the A tile -> gacc[2].
// R8 lesson: epilogue scratch MUST alias the 32KB lds buffer — a separate
// __shared__ array pushes LDS_Block_Size to 33280 -> 4 blocks/CU instead of 5.
template<int MODE, int THREE>
__global__ __launch_bounds__(256) void gemm_mfma(
    const unsigned short* __restrict__ Ah, const unsigned short* __restrict__ Al,
    const unsigned short* __restrict__ Bh, const unsigned short* __restrict__ Bl,
    float* __restrict__ Cout, const float* __restrict__ bias,
    const float* __restrict__ Ref, int relu, int Mrows,
    float* __restrict__ gacc, const float* __restrict__ bias2) {
    int bx = blockIdx.x, by = blockIdx.y;
    int side = (MODE == 4) ? (bx >> 2) : 0;
    int bxe  = (MODE == 4) ? (bx & 3) : bx;
    __shared__ char lds[32768];  // Ah|Al|Bh|Bl tiles, 8 KB each; epilogue scratch aliased
    float* wred0 = (float*)lds;          // valid after final barrier
    float* wred1 = (float*)lds + 4;
    int tid = threadIdx.x;
    int wave = tid >> 6, lane = tid & 63;
    int gmtA = by * 8, gmtB = bxe * 8;
    const unsigned short* garr; int gmt0;
    if (wave == 0)      { garr = Ah; gmt0 = gmtA; }
    else if (wave == 1) { garr = Al; gmt0 = gmtA; }
    else if (wave == 2) { garr = Bh + (size_t)side * 2 * WPACKE; gmt0 = gmtB; }
    else                { garr = Bl + (size_t)side * 2 * WPACKE; gmt0 = gmtB; }
    char* ldst = lds + wave * 8192;
    f32x4 acc[4][4];
    #pragma unroll
    for (int i = 0; i < 4; ++i)
        #pragma unroll
        for (int j = 0; j < 4; ++j) acc[i][j] = (f32x4){0.f, 0.f, 0.f, 0.f};
    float commitAcc = 0.f;
    int wm = wave >> 1, wn = wave & 1;
    for (int kb = 0; kb < 16; ++kb) {
        if (THREE || wave != 1) {
            #pragma unroll
            for (int t = 0; t < 8; ++t) {
                const char* g = (const char*)garr + (((size_t)(gmt0 + t) * 16 + kb) * 1024) + lane * 16;
                gld_lds16(ldst + t * 1024 + lane * 16, g);
            }
        }
        __syncthreads();
        // commit-loss fold: reconstruct q from the A tile, compare vs h (=Ref)
        if (MODE == 4 && bx == 4) {
            int rg = tid >> 1, half = tid & 1;
            int m = by * 128 + rg;
            if (m < Mrows) {
                int tt = rg >> 4, r = rg & 15;
                const float* hp = Ref + (size_t)m * DD_ + kb * 32 + half * 16;
                float4 h0 = ((const float4*)hp)[0], h1 = ((const float4*)hp)[1];
                float4 h2 = ((const float4*)hp)[2], h3 = ((const float4*)hp)[3];
                float hv[16] = {h0.x,h0.y,h0.z,h0.w, h1.x,h1.y,h1.z,h1.w,
                                h2.x,h2.y,h2.z,h2.w, h3.x,h3.y,h3.z,h3.w};
                #pragma unroll
                for (int j2 = 0; j2 < 16; ++j2) {
                    int sub = half * 2 + (j2 >> 3), j = j2 & 7;
                    int off = tt * 1024 + (sub * 16 + r) * 16 + j * 2;
                    u32 hb = *(const unsigned short*)(lds + off);
                    u32 lb = *(const unsigned short*)(lds + 8192 + off);
                    float q = __uint_as_float(hb << 16) + __uint_as_float(lb << 16);
                    float d = q - hv[j2];
                    commitAcc = fmaf(d, d, commitAcc);
                }
            }
        }
        bf16x8 a_h[4], a_l[4], b_h[4], b_l[4];
        #pragma unroll
        for (int i = 0; i < 4; ++i) {
            int at = wm * 4 + i, bt = wn * 4 + i;
            a_h[i] = *(const bf16x8*)(lds + 0     + at * 1024 + lane * 16);
            if (THREE) a_l[i] = *(const bf16x8*)(lds + 8192 + at * 1024 + lane * 16);
            b_h[i] = *(const bf16x8*)(lds + 16384 + bt * 1024 + lane * 16);
            b_l[i] = *(const bf16x8*)(lds + 24576 + bt * 1024 + lane * 16);
        }
        #pragma unroll
        for (int i = 0; i < 4; ++i)
            #pragma unroll
            for (int j = 0; j < 4; ++j) {
                acc[i][j] = __builtin_amdgcn_mfma_f32_16x16x32_bf16(a_h[i], b_h[j], acc[i][j], 0, 0, 0);
                acc[i][j] = __builtin_amdgcn_mfma_f32_16x16x32_bf16(a_h[i], b_l[j], acc[i][j], 0, 0, 0);
                if (THREE)
                    acc[i][j] = __builtin_amdgcn_mfma_f32_16x16x32_bf16(a_l[i], b_h[j], acc[i][j], 0, 0, 0);
            }
        __syncthreads();   // also makes lds safe for epilogue-scratch reuse
    }
    // C/D layout: col = lane&15, row = (lane>>4)*4 + reg
    int m_base = by * 128 + wm * 64;
    int n_base = bxe * 128 + wn * 64;
    int rq = lane >> 4, cc = lane & 15;
    if (MODE == 0) {
        #pragma unroll
        for (int i = 0; i < 4; ++i) {
            int m = m_base + i * 16 + rq * 4;
            #pragma unroll
            for (int j = 0; j < 4; ++j) {
                int n = n_base + j * 16 + cc;
                #pragma unroll
                for (int r = 0; r < 4; ++r) {
                    if (m + r < NN_) Cout[(size_t)(m + r) * KK_ + n] = acc[i][j][r];
                }
            }
        }
    } else if (MODE == 2 || (MODE == 4 && side == 0)) {
        #pragma unroll
        for (int i = 0; i < 4; ++i) {
            int m = m_base + i * 16 + rq * 4;
            #pragma unroll
            for (int j = 0; j < 4; ++j) {
                int n = n_base + j * 16 + cc;
                float bv = bias[n];
                #pragma unroll
                for (int r = 0; r < 4; ++r) {
                    if (m + r < Mrows) {
                        float v = acc[i][j][r] + bv;
                        if (relu) v = fmaxf(v, 0.f);
                        Cout[(size_t)(m + r) * DD_ + n] = v;
                    }
                }
            }
        }
    } else {  // MODE 4 rec-loss side
        const float* bs = bias2;
        float s = 0.f;
        #pragma unroll
        for (int i = 0; i < 4; ++i) {
            int m = m_base + i * 16 + rq * 4;
            #pragma unroll
            for (int j = 0; j < 4; ++j) {
                int n = n_base + j * 16 + cc;
                float bv = bs[n];
                #pragma unroll
                for (int r = 0; r < 4; ++r) {
                    if (m + r < Mrows) {
                        float d = Ref[(size_t)(m + r) * DD_ + n] - (acc[i][j][r] + bv);
                        s = fmaf(d, d, s);
                    }
                }
            }
        }
        for (int off = 32; off; off >>= 1) s += __shfl_xor(s, off);
        if (lane == 0) wred0[wave] = s;
        if (MODE == 4 && bx == 4) {
            float c = commitAcc;
            for (int off = 32; off; off >>= 1) c += __shfl_xor(c, off);
            if (lane == 0) wred1[wave] = c;
        }
        __syncthreads();
        if (tid == 0) {
            atomicAdd(&gacc[3], wred0[0] + wred0[1] + wred0[2] + wred0[3]);
            if (MODE == 4 && bx == 4)
                atomicAdd(&gacc[2], wred1[0] + wred1[1] + wred1[2] + wred1[3]);
        }
    }
}

// ---------------- dedicated rpass GEMM: 128x128 triangular, XCD-chunked -------
// 128^2 shape (acc[4][4], exactly 32KB LDS -> 5 blk/CU), dedicated compile,
// XCD-chunked triangle order L=(b&7)*141+(b>>3). Epilogue scratch aliases lds
// (R8 lesson: separate __shared__ arrays cost one block/CU).
__global__ __launch_bounds__(256) void gemm_rpass(
    const unsigned short* __restrict__ Qh, const unsigned short* __restrict__ Ql,
    float* __restrict__ gacc, u32* __restrict__ minKey, u32* __restrict__ maxKey) {
    int Lp = blockIdx.x;
    int L = (Lp & 7) * 141 + (Lp >> 3);
    int bx = (int)((sqrtf(8.f * (float)L + 1.f) - 1.f) * 0.5f);
    while ((bx + 1) * (bx + 2) / 2 <= L) ++bx;
    while (bx * (bx + 1) / 2 > L) --bx;
    int by = L - bx * (bx + 1) / 2;     // bx >= by
    __shared__ char lds[32768];  // Ah|Al|Bh|Bl tiles, 8 KB each; epilogue scratch aliased
    float* wr0 = (float*)lds;
    float* wr1 = (float*)lds + 4;
    float* wr2 = (float*)lds + 8;
    float* wr3 = (float*)lds + 12;
    int tid = threadIdx.x;
    int wave = tid >> 6, lane = tid & 63;
    int gmtA = by * 8, gmtB = bx * 8;
    const unsigned short* garr; int gmt0;
    if (wave == 0)      { garr = Qh; gmt0 = gmtA; }
    else if (wave == 1) { garr = Ql; gmt0 = gmtA; }
    else if (wave == 2) { garr = Qh; gmt0 = gmtB; }
    else                { garr = Ql; gmt0 = gmtB; }
    char* ldst = lds + wave * 8192;
    f32x4 acc[4][4];
    #pragma unroll
    for (int i = 0; i < 4; ++i)
        #pragma unroll
        for (int j = 0; j < 4; ++j) acc[i][j] = (f32x4){0.f, 0.f, 0.f, 0.f};
    int wm = wave >> 1, wn = wave & 1;
    for (int kb = 0; kb < 16; ++kb) {
        #pragma unroll
        for (int t = 0; t < 8; ++t) {
            const char* g = (const char*)garr + (((size_t)(gmt0 + t) * 16 + kb) * 1024) + lane * 16;
            gld_lds16(ldst + t * 1024 + lane * 16, g);
        }
        __syncthreads();
        bf16x8 a_h[4], a_l[4], b_h[4], b_l[4];
        #pragma unroll
        for (int i = 0; i < 4; ++i) {
            int at = wm * 4 + i, bt = wn * 4 + i;
            a_h[i] = *(const bf16x8*)(lds + 0     + at * 1024 + lane * 16);
            a_l[i] = *(const bf16x8*)(lds + 8192  + at * 1024 + lane * 16);
            b_h[i] = *(const bf16x8*)(lds + 16384 + bt * 1024 + lane * 16);
            b_l[i] = *(const bf16x8*)(lds + 24576 + bt * 1024 + lane * 16);
        }
        #pragma unroll
        for (int i = 0; i < 4; ++i)
            #pragma unroll
            for (int j = 0; j < 4; ++j) {
                acc[i][j] = __builtin_amdgcn_mfma_f32_16x16x32_bf16(a_h[i], b_h[j], acc[i][j], 0, 0, 0);
                acc[i][j] = __builtin_amdgcn_mfma_f32_16x16x32_bf16(a_h[i], b_l[j], acc[i][j], 0, 0, 0);
                acc[i][j] = __builtin_amdgcn_mfma_f32_16x16x32_bf16(a_l[i], b_h[j], acc[i][j], 0, 0, 0);
            }
        __syncthreads();   // also makes lds safe for epilogue-scratch reuse
    }
    int m_base = by * 128 + wm * 64;
    int n_base = bx * 128 + wn * 64;
    int rq = lane >> 4, cc = lane & 15;
    float tsum = 0.f, tsq = 0.f, tmin = 3.4e38f, tmax = -3.4e38f;
    #pragma unroll
    for (int i = 0; i < 4; ++i) {
        #pragma unroll
        for (int j = 0; j < 4; ++j) {
            #pragma unroll
            for (int r = 0; r < 4; ++r) {
                int m = m_base + i * 16 + rq * 4 + r;
                int n = n_base + j * 16 + cc;
                if (m < NN_ && n < NN_ && n >= m) {
                    float v = acc[i][j][r];
                    float w = (n > m) ? 2.f : 1.f;
                    tsum += w * v;
                    tsq  += w * v * v;
                    tmin = fminf(tmin, v);
                    tmax = fmaxf(tmax, v);
                }
            }
        }
    }
    for (int off = 32; off; off >>= 1) {
        tsum += __shfl_xor(tsum, off);
        tsq  += __shfl_xor(tsq, off);
        tmin = fminf(tmin, __shfl_xor(tmin, off));
        tmax = fmaxf(tmax, __shfl_xor(tmax, off));
    }
    if (lane == 0) { wr0[wave] = tsum; wr1[wave] = tsq; wr2[wave] = tmin; wr3[wave] = tmax; }
    __syncthreads();
    if (tid == 0) {
        atomicAdd(&gacc[0], wr0[0] + wr0[1] + wr0[2] + wr0[3]);
        atomicAdd(&gacc[1], wr1[0] + wr1[1] + wr1[2] + wr1[3]);
        atomicMin(minKey, okey(fminf(fminf(wr2[0], wr2[1]), fminf(wr2[2], wr2[3]))));
        atomicMax(maxKey, okey(fmaxf(fmaxf(wr3[0], wr3[1]), fmaxf(wr3[2], wr3[3]))));
    }
}

// exact-fp32 argmax rescue — persistent, wave-per-row.
__global__ __launch_bounds__(256) void k_rescore(
    const float* __restrict__ dist, const float* __restrict__ h,
    const float* __restrict__ rnorm, const float* __restrict__ cb,
    const float* __restrict__ scale, int* __restrict__ ind) {
    int w = threadIdx.x >> 6, lane = threadIdx.x & 63;
    for (int row = blockIdx.x * 4 + w; row < NN_; row += gridDim.x * 4) {
        const float4* dr4 = (const float4*)(dist + (size_t)row * KK_);
        float4 vbuf[16];
        float lmax = -3.4e38f;
        #pragma unroll
        for (int it = 0; it < 16; ++it) {
            float4 v = dr4[lane + it * 64];
            vbuf[it] = v;
            lmax = fmaxf(lmax, fmaxf(fmaxf(v.x, v.y), fmaxf(v.z, v.w)));
        }
        for (int off = 32; off; off >>= 1) lmax = fmaxf(lmax, __shfl_xor(lmax, off));
        float thr = lmax - 1e-3f;
        float hr = rnorm[row];
        const float* hp = h + (size_t)row * DD_;
        u64 best = 0;
        #pragma unroll 1
        for (int it = 0; it < 16; ++it) {
            float4 v = vbuf[it];
            u32 m4 = (v.x >= thr ? 1u : 0u) | (v.y >= thr ? 2u : 0u)
                   | (v.z >= thr ? 4u : 0u) | (v.w >= thr ? 8u : 0u);
            u64 bal = __ballot(m4 != 0);
            while (bal) {
                int l = __ffsll((unsigned long long)bal) - 1;
                bal &= bal - 1;
                u32 mm = __shfl(m4, l);
                while (mm) {
                    int j = __ffs(mm) - 1;
                    mm &= mm - 1;
                    int col = (l + it * 64) * 4 + j;
                    const float* cp = cb + (size_t)col * DD_;
                    float dot = 0.f;
                    #pragma unroll
                    for (int jj = 0; jj < 8; ++jj)
                        dot = fmaf(hp[lane + jj * 64], cp[lane + jj * 64], dot);
                    for (int off = 32; off; off >>= 1) dot += __shfl_xor(dot, off);
                    u64 key = packKey(dot * hr * scale[col], col);
                    if (key > best) best = key;   // dot wave-uniform after butterfly
                }
            }
        }
        if (lane == 0) ind[row] = (int)(~(u32)(best & 0xFFFFFFFFull));
    }
}

// ---------------- fp32 GEMM (kept only for the 6000x40 output) ----------------
__global__ __launch_bounds__(256) void gemm_nn(
    const float* __restrict__ A, const float* __restrict__ B,
    const float* __restrict__ bias, float* __restrict__ C,
    int M, int Ncols, int Kdim) {
    __shared__ float As[16][68];
    __shared__ float Bs[16][68];
    int tid = threadIdx.x;
    int tx = tid & 15, ty = tid >> 4;
    int m0 = blockIdx.y * 64, n0 = blockIdx.x * 64;
    float cv[4][4] = {};
    int ar = tid >> 2;
    int ak = (tid & 3) << 2;
    int am = m0 + ar;
    const float* Arow = (am < M) ? (A + (size_t)am * Kdim) : nullptr;
    int bk = tid >> 4;
    int bn = (tid & 15) << 2;
    for (int k0 = 0; k0 < Kdim; k0 += 16) {
        float4 av = make_float4(0.f, 0.f, 0.f, 0.f);
        if (Arow) av = *(const float4*)(Arow + k0 + ak);
        As[ak + 0][ar] = av.x; As[ak + 1][ar] = av.y;
        As[ak + 2][ar] = av.z; As[ak + 3][ar] = av.w;
        float4 bv = make_float4(0.f, 0.f, 0.f, 0.f);
        if (n0 + bn < Ncols)
            bv = *(const float4*)(B + (size_t)(k0 + bk) * Ncols + n0 + bn);
        Bs[bk][bn + 0] = bv.x; Bs[bk][bn + 1] = bv.y;
        Bs[bk][bn + 2] = bv.z; Bs[bk][bn + 3] = bv.w;
        __syncthreads();
        #pragma unroll
        for (int kk = 0; kk < 16; ++kk) {
            float4 a4 = *(const float4*)&As[kk][ty << 2];
            float4 b4 = *(const float4*)&Bs[kk][tx << 2];
            float ax[4] = {a4.x, a4.y, a4.z, a4.w};
            float bx[4] = {b4.x, b4.y, b4.z, b4.w};
            #pragma unroll
            for (int i = 0; i < 4; ++i)
                #pragma unroll
                for (int j = 0; j < 4; ++j)
                    cv[i][j] = fmaf(ax[i], bx[j], cv[i][j]);
        }
        __syncthreads();
    }
    #pragma unroll
    for (int i = 0; i < 4; ++i) {
        int m = m0 + (ty << 2) + i;
        if (m >= M) continue;
        #pragma unroll
        for (int j = 0; j < 4; ++j) {
            int n = n0 + (tx << 2) + j;
            if (n >= Ncols) continue;
            C[(size_t)m * Ncols + n] = cv[i][j] + bias[n];
        }
    }
}

// ---------------- edge multiplicity hash (for sum m^2 only) ----------------
__global__ void k_hash(const int* __restrict__ src, const int* __restrict__ dst,
                       int* __restrict__ hkey, int* __restrict__ hcnt) {
    int e = blockIdx.x * 256 + threadIdx.x;
    if (e >= EE_) return;
    int key = dst[e] * NN_ + src[e];
    u32 h = ((u32)key * 2654435761u) & HMASK;
    while (true) {
        int old = atomicCAS(&hkey[h], -1, key);
        if (old == -1 || old == key) { atomicAdd(&hcnt[h], 1); break; }
        h = (h + 1) & HMASK;
    }
}

__global__ __launch_bounds__(256) void k_m2scan(const int* __restrict__ hcnt, float* __restrict__ gacc) {
    float s = 0.f;
    for (int i = blockIdx.x * 256 + threadIdx.x; i < HSZ; i += gridDim.x * 256) {
        float c = (float)hcnt[i];
        s = fmaf(c, c, s);
    }
    for (int off = 32; off; off >>= 1) s += __shfl_xor(s, off);
    __shared__ float w1[4];
    int lane = threadIdx.x & 63, wv = threadIdx.x >> 6;
    if (lane == 0) w1[wv] = s;
    __syncthreads();
    if (threadIdx.x == 0) atomicAdd(&gacc[4], w1[0] + w1[1] + w1[2] + w1[3]);
}

// ---------------- final loss assembly ----------------
__global__ void k_final(const float* __restrict__ gacc, const u32* __restrict__ minKey,
                        const u32* __restrict__ maxKey, float* __restrict__ lossOut) {
    if (threadIdx.x != 0 || blockIdx.x != 0) return;
    double Rsum = gacc[0], Rsq = gacc[1], commitS = gacc[2], recS = gacc[3];
    double m2 = gacc[4], mr = gacc[5], ms = (double)EE_;
    double mn = (double)dkey(*minKey);
    double mx = (double)dkey(*maxKey);
    double den = mx - mn;
    double NN2 = (double)NN_ * (double)NN_;
    double sum_aq2 = (Rsq - 2.0 * mn * Rsum + NN2 * mn * mn) / (den * den);
    double sum_maq = (mr - mn * ms) / den;
    double total = sum_aq2 + m2 - 2.0 * sum_maq;
    double edge = sqrt(total / NN2);
    double commit = 0.25 * commitS / ((double)NN_ * (double)DD_);
    double rec = recS / ((double)NN_ * (double)DD_);
    *lossOut = (float)(rec + edge + commit);
}

extern "C" void kernel_launch(void* const* d_in, const int* in_sizes, int n_in,
                              void* d_out, int out_size, void* d_ws, size_t ws_size,
                              hipStream_t stream) {
    const float* feats = (const float*)d_in[0];
    const float* W1 = (const float*)d_in[1];
    const float* b1 = (const float*)d_in[2];
    const float* W2 = (const float*)d_in[3];
    const float* b2v = (const float*)d_in[4];
    const float* Wd1 = (const float*)d_in[5];
    const float* bd1 = (const float*)d_in[6];
    const float* Wd2 = (const float*)d_in[7];
    const float* bd2 = (const float*)d_in[8];
    const float* Wl = (const float*)d_in[9];
    const float* bl = (const float*)d_in[10];
    const float* cb = (const float*)d_in[11];
    const int* src = (const int*)d_in[12];
    const int* dst = (const int*)d_in[13];

    float* outF = (float*)d_out;
    float* lossOut = outF + (size_t)NN_ * OO_;     // element 240000
    float* distOut = lossOut + 1;                  // element 240001

    char* w = (char*)d_ws;
    size_t off = 0;
    auto alloc = [&](size_t bytes) -> void* {
        void* p = w + off;
        off = (off + bytes + 255) & ~(size_t)255;
        return p;
    };
    // zone0: zero-init
    float* gacc = (float*)alloc(64);
    u32* maxKey = (u32*)alloc(4);
    int* degin = (int*)alloc((size_t)NN_ * 4);
    int* degout = (int*)alloc((size_t)NN_ * 4);
    int* cursor = (int*)alloc((size_t)NN_ * 4);
    int* hcnt = (int*)alloc((size_t)HSZ * 4);
    size_t z0end = off;
    // zone1: 0xFF-init
    int* hkey = (int*)alloc((size_t)HSZ * 4);
    u32* minKey = (u32*)alloc(4);
    size_t z1end = off;
    // uninit scratch
    int* offs = (int*)alloc((size_t)(NN_ + 1) * 4);
    int* esrc = (int*)alloc((size_t)EE_ * 4);
    float* rin = (float*)alloc((size_t)NN_ * 4);
    float* rout = (float*)alloc((size_t)NN_ * 4);
    int* ind = (int*)alloc((size_t)NN_ * 4);
    float* scale = (float*)alloc((size_t)KK_ * 4);
    float* rnorm = (float*)alloc((size_t)NN_ * 4);
    float* h = (float*)alloc((size_t)NN_ * DD_ * 4);       // h, later h2
    float* QE = (float*)alloc((size_t)NN_ * DD_ * 4);
    const size_t NPACK = (size_t)MT_A * 16 * DD_;          // node-sized packed half
    unsigned short* P1 = (unsigned short*)alloc(NPACK * 2 * 2);  // aggp -> qcp -> agg2p
    unsigned short* P2 = (unsigned short*)alloc(NPACK * 2 * 2);  // hnp -> QEp
    unsigned short* enp = (unsigned short*)alloc((size_t)KK_ * DD_ * 2 * 2);
    const size_t WPACK = (size_t)32 * 16 * DD_;            // 512-row packed half
    unsigned short* W1p = (unsigned short*)alloc(WPACK * 2 * 2);
    unsigned short* Wd1p = (unsigned short*)alloc(WPACK * 2 * 2);  // MUST stay
    unsigned short* Wd2p = (unsigned short*)alloc(WPACK * 2 * 2);  // contiguous (MODE4)
    unsigned short* W2p = (unsigned short*)alloc(WPACK * 2 * 2);

    unsigned short* aggp_h = P1,  *aggp_l = P1 + NPACK;
    unsigned short* qcp_h  = P1,  *qcp_l  = P1 + NPACK;
    unsigned short* ag2p_h = P1,  *ag2p_l = P1 + NPACK;
    unsigned short* hnp_h  = P2,  *hnp_l  = P2 + NPACK;
    unsigned short* QEp_h  = P2,  *QEp_l  = P2 + NPACK;
    unsigned short* enp_h  = enp, *enp_l  = enp + (size_t)KK_ * DD_;

    hipMemsetAsync(w, 0, z0end, stream);
    hipMemsetAsync(w + z0end, 0xFF, z1end - z0end, stream);

    const int TB = 256;
    k_deg<<<(EE_ + TB - 1) / TB, TB, 0, stream>>>(src, dst, degout, degin);
    k_rsqrtdeg<<<(NN_ + TB - 1) / TB, TB, 0, stream>>>(degout, degin, rout, rin);
    k_scan<<<1, 1024, 0, stream>>>(degin, offs, NN_);
    k_fill<<<(EE_ + TB - 1) / TB, TB, 0, stream>>>(src, dst, offs, cursor, esrc);
    k_wpack<<<dim3(32, 4), TB, 0, stream>>>(W1, W1p, W1p + WPACK);
    k_wpack<<<dim3(32, 4), TB, 0, stream>>>(Wd1, Wd1p, Wd1p + WPACK);
    k_wpack<<<dim3(32, 4), TB, 0, stream>>>(Wd2, Wd2p, Wd2p + WPACK);
    k_wpack<<<dim3(32, 4), TB, 0, stream>>>(W2, W2p, W2p + WPACK);
    k_aggs<0><<<1024, TB, 0, stream>>>(feats, esrc, offs, rout, rin, aggp_h, aggp_l, nullptr);
    gemm_mfma<2,1><<<dim3(4, NB_N), TB, 0, stream>>>(aggp_h, aggp_l, W1p, W1p + WPACK,
                                                     h, b1, nullptr, 1, NN_, nullptr, nullptr);
    k_rowpack<1><<<1024, TB, 0, stream>>>(h, nullptr, nullptr, rnorm, NN_, hnp_h, hnp_l);
    k_rowpack<1><<<1024, TB, 0, stream>>>(cb, nullptr, nullptr, scale, KK_, enp_h, enp_l);
    gemm_mfma<0,0><<<dim3(KK_ / 128, NB_N), TB, 0, stream>>>(hnp_h, hnp_l, enp_h, enp_l,
                                                             distOut, nullptr, nullptr, 0, NN_,
                                                             nullptr, nullptr);
    k_rescore<<<1024, TB, 0, stream>>>(distOut, h, rnorm, cb, scale, ind);
    k_rowpack<0><<<1024, TB, 0, stream>>>(cb, ind, scale, nullptr, NN_, qcp_h, qcp_l);
    // fused Wd1+Wd2 GEMM: stores QE (bx<4), rec loss (bx>=4), commit fold (bx==4)
    gemm_mfma<4,1><<<dim3(8, NB_N), TB, 0, stream>>>(qcp_h, qcp_l, Wd1p, Wd1p + WPACK,
                                                     QE, bd1, h, 0, NN_, gacc, bd2);
    k_rowpack<0><<<1024, TB, 0, stream>>>(QE, nullptr, nullptr, nullptr, NN_, QEp_h, QEp_l);
    gemm_rpass<<<1128, TB, 0, stream>>>(QEp_h, QEp_l, gacc, minKey, maxKey);
    k_hash<<<(EE_ + TB - 1) / TB, TB, 0, stream>>>(src, dst, hkey, hcnt);
    k_m2scan<<<512, TB, 0, stream>>>(hcnt, gacc);
    k_aggs<1><<<1024, TB, 0, stream>>>(QE, esrc, offs, rout, rin, ag2p_h, ag2p_l, gacc);
    gemm_mfma<2,1><<<dim3(4, NB_N), TB, 0, stream>>>(ag2p_h, ag2p_l, W2p, W2p + WPACK,
                                                     h, b2v, nullptr, 1, NN_, nullptr, nullptr);
    gemm_nn<<<dim3(1, 94), TB, 0, stream>>>(h, Wl, bl, outF, NN_, OO_, DD_);
    k_final<<<1, 64, 0, stream>>>(gacc, minKey, maxKey, lossOut);
}

// Round 10
// 664.462 us; speedup vs baseline: 1.0359x; 1.0031x over previous
//
#include <hip/hip_runtime.h>

typedef unsigned int u32;
typedef unsigned long long u64;

#define NN_ 6000
#define EE_ 192000
#define DD_ 512
#define KK_ 4096
#define OO_ 40
#define HSZ (1 << 19)
#define HMASK (HSZ - 1)
#define MT_A 376   // ceil(6000/16) m-tiles for node-sized packed arrays
#define NB_N 47    // 6016/128 blocks
#define WPACKE (32 * 16 * 512)   // elems per packed 512-row half

typedef __bf16 bf16x8 __attribute__((ext_vector_type(8)));
typedef float f32x4 __attribute__((ext_vector_type(4)));

__device__ __forceinline__ u32 okey(float f) {
    u32 u = __float_as_uint(f);
    return (u & 0x80000000u) ? ~u : (u | 0x80000000u);
}
__device__ __forceinline__ float dkey(u32 u) {
    u32 b = (u & 0x80000000u) ? (u ^ 0x80000000u) : ~u;
    return __uint_as_float(b);
}
__device__ __forceinline__ u64 packKey(float v, int col) {
    return ((u64)okey(v) << 32) | (u32)(~(u32)col);
}
__device__ __forceinline__ unsigned short f2bf_rne(float f) {
    u32 x = __float_as_uint(f);
    u32 r = x + 0x7fffu + ((x >> 16) & 1u);
    return (unsigned short)(r >> 16);
}
__device__ __forceinline__ void gld_lds16(void* l, const void* g) {
    __builtin_amdgcn_global_load_lds(
        (const __attribute__((address_space(1))) unsigned int*)g,
        (__attribute__((address_space(3))) unsigned int*)l, 16, 0, 0);
}
// compiler+hw ordering fence for same-wave LDS write->read (rule #18 analog)
#define LGKM0 do { asm volatile("s_waitcnt lgkmcnt(0)" ::: "memory"); __builtin_amdgcn_sched_barrier(0); } while (0)

// ---------------- graph prep ----------------
__global__ void k_deg(const int* __restrict__ src, const int* __restrict__ dst,
                      int* __restrict__ degout, int* __restrict__ degin) {
    int e = blockIdx.x * 256 + threadIdx.x;
    if (e >= EE_) return;
    atomicAdd(&degout[src[e]], 1);
    atomicAdd(&degin[dst[e]], 1);
}

__global__ void k_rsqrtdeg(const int* __restrict__ degout, const int* __restrict__ degin,
                           float* __restrict__ rout, float* __restrict__ rin) {
    int i = blockIdx.x * 256 + threadIdx.x;
    if (i >= NN_) return;
    int doV = degout[i]; if (doV < 1) doV = 1;
    int diV = degin[i];  if (diV < 1) diV = 1;
    rout[i] = rsqrtf((float)doV);
    rin[i]  = rsqrtf((float)diV);
}

// 6000-elem scan, 1 block x 1024 threads, 6 elems/thread (20 syncs)
__global__ void k_scan(const int* __restrict__ cnt, int* __restrict__ offs, int n) {
    __shared__ int part[1024];
    int t = threadIdx.x;
    int base = t * 6;
    int v[6]; int s = 0;
    #pragma unroll
    for (int j = 0; j < 6; ++j) { int i = base + j; v[j] = (i < n) ? cnt[i] : 0; s += v[j]; }
    part[t] = s;
    __syncthreads();
    for (int off = 1; off < 1024; off <<= 1) {
        int x = (t >= off) ? part[t - off] : 0;
        __syncthreads();
        part[t] += x;
        __syncthreads();
    }
    int run = (t > 0) ? part[t - 1] : 0;
    if (t == 0) offs[0] = 0;
    #pragma unroll
    for (int j = 0; j < 6; ++j) {
        int i = base + j;
        run += v[j];
        if (i < n) offs[i + 1] = run;
    }
}

__global__ void k_fill(const int* __restrict__ src, const int* __restrict__ dst,
                       const int* __restrict__ offs, int* __restrict__ cursor,
                       int* __restrict__ esrc) {
    int e = blockIdx.x * 256 + threadIdx.x;
    if (e >= EE_) return;
    int d = dst[e];
    int pos = offs[d] + atomicAdd(&cursor[d], 1);
    esrc[pos] = src[e];
}

// split 8 floats into bf16 hi/lo packed words
__device__ __forceinline__ void split8(const float* vals, uint4& hw, uint4& lw) {
    u32 h[4], l[4];
    #pragma unroll
    for (int j = 0; j < 4; ++j) {
        unsigned short h0 = f2bf_rne(vals[2*j]),   h1 = f2bf_rne(vals[2*j+1]);
        float hf0 = __uint_as_float((u32)h0 << 16), hf1 = __uint_as_float((u32)h1 << 16);
        unsigned short l0 = f2bf_rne(vals[2*j] - hf0), l1 = f2bf_rne(vals[2*j+1] - hf1);
        h[j] = (u32)h0 | ((u32)h1 << 16);
        l[j] = (u32)l0 | ((u32)l1 << 16);
    }
    hw = make_uint4(h[0], h[1], h[2], h[3]);
    lw = make_uint4(l[0], l[1], l[2], l[3]);
}

// ---------------- persistent sliced aggregation (L2-resident gather) ----------------
template<int UNW>
__global__ __launch_bounds__(256) void k_aggs(
    const float* __restrict__ X, const int* __restrict__ esrc,
    const int* __restrict__ offs, const float* __restrict__ rout,
    const float* __restrict__ rin,
    unsigned short* __restrict__ dh, unsigned short* __restrict__ dl,
    float* __restrict__ gacc) {
    __shared__ float packbuf[4][128];
    __shared__ float mred[4];
    int b = blockIdx.x;                 // [0,1024)
    int xcd = b & 7;                    // heuristic XCD id (round-robin)
    int slice = xcd >> 1;               // 0..3, pinned per XCD pair
    int w = threadIdx.x >> 6, lane = threadIdx.x & 63;
    int wid = ((((b >> 3) << 1) | (xcd & 1)) << 2) + w;  // [0,1024) per slice
    const float* Xc = X + slice * 128 + lane * 2;        // this lane's col pair
    float mrAcc = 0.f;
    for (int node = wid; node < NN_; node += 1024) {
        int beg = offs[node], end = offs[node + 1];
        float a0 = 0.f, a1 = 0.f, u0 = 0.f, u1 = 0.f;
        for (int e = beg; e < end; ) {
            int cnt = end - e; if (cnt > 64) cnt = 64;
            int sreg = 0; float wreg = 0.f;
            if (lane < cnt) { sreg = esrc[e + lane]; wreg = rout[sreg]; }
            int j = 0;
            for (; j + 4 <= cnt; j += 4) {
                int s0 = __shfl(sreg, j),     s1 = __shfl(sreg, j + 1);
                int s2 = __shfl(sreg, j + 2), s3 = __shfl(sreg, j + 3);
                float w0 = __shfl(wreg, j),     w1 = __shfl(wreg, j + 1);
                float w2 = __shfl(wreg, j + 2), w3 = __shfl(wreg, j + 3);
                float2 v0 = *(const float2*)(Xc + (size_t)s0 * DD_);
                float2 v1 = *(const float2*)(Xc + (size_t)s1 * DD_);
                float2 v2 = *(const float2*)(Xc + (size_t)s2 * DD_);
                float2 v3 = *(const float2*)(Xc + (size_t)s3 * DD_);
                a0 = fmaf(w0, v0.x, a0); a1 = fmaf(w0, v0.y, a1);
                a0 = fmaf(w1, v1.x, a0); a1 = fmaf(w1, v1.y, a1);
                a0 = fmaf(w2, v2.x, a0); a1 = fmaf(w2, v2.y, a1);
                a0 = fmaf(w3, v3.x, a0); a1 = fmaf(w3, v3.y, a1);
                if (UNW) {
                    u0 += (v0.x + v1.x) + (v2.x + v3.x);
                    u1 += (v0.y + v1.y) + (v2.y + v3.y);
                }
            }
            for (; j < cnt; ++j) {
                int sj = __shfl(sreg, j); float wj = __shfl(wreg, j);
                float2 v = *(const float2*)(Xc + (size_t)sj * DD_);
                a0 = fmaf(wj, v.x, a0); a1 = fmaf(wj, v.y, a1);
                if (UNW) { u0 += v.x; u1 += v.y; }
            }
            e += cnt;
        }
        float ri = rin[node];
        packbuf[w][lane * 2] = a0 * ri;
        packbuf[w][lane * 2 + 1] = a1 * ri;
        LGKM0;
        if (lane < 16) {
            uint4 hw, lw;
            split8(&packbuf[w][(lane >> 2) * 32 + (lane & 3) * 8], hw, lw);
            int kb = slice * 4 + (lane >> 2);
            int lo = (lane & 3) * 16 + (node & 15);
            size_t base = (((size_t)(node >> 4) * 16 + kb) * 64 + lo) * 8;
            *(uint4*)(dh + base) = hw;
            *(uint4*)(dl + base) = lw;
        }
        if (UNW) {
            float2 q = *(const float2*)(Xc + (size_t)node * DD_);
            mrAcc = fmaf(q.x, u0, mrAcc);
            mrAcc = fmaf(q.y, u1, mrAcc);
        }
    }
    if (UNW) {
        for (int off = 32; off; off >>= 1) mrAcc += __shfl_xor(mrAcc, off);
        if (lane == 0) mred[w] = mrAcc;
        __syncthreads();
        if (threadIdx.x == 0)
            atomicAdd(&gacc[5], mred[0] + mred[1] + mred[2] + mred[3]);
    }
}

// ---------------- fused row-norm + MFMA-pack (wave-per-row, grid-stride) -------
template<int NORM>
__global__ __launch_bounds__(256) void k_rowpack(
    const float* __restrict__ src, const int* __restrict__ gidx,
    const float* __restrict__ scaleIn, float* __restrict__ scaleOut, int nrows,
    unsigned short* __restrict__ dh, unsigned short* __restrict__ dl) {
    int w = threadIdx.x >> 6, lane = threadIdx.x & 63;
    for (int r = blockIdx.x * 4 + w; r < nrows; r += gridDim.x * 4) {
        int rs = gidx ? gidx[r] : r;
        const float4* p = (const float4*)(src + (size_t)rs * DD_);
        float4 x = p[lane * 2], y = p[lane * 2 + 1];
        float sc;
        if (NORM) {
            float s = x.x * x.x + x.y * x.y + x.z * x.z + x.w * x.w
                    + y.x * y.x + y.y * y.y + y.z * y.z + y.w * y.w;
            for (int off = 32; off; off >>= 1) s += __shfl_xor(s, off);
            sc = 1.0f / sqrtf(s + 1e-12f);
            if (scaleOut && lane == 0) scaleOut[r] = sc;
        } else {
            sc = scaleIn ? scaleIn[rs] : 1.0f;
        }
        float vals[8] = {x.x*sc, x.y*sc, x.z*sc, x.w*sc, y.x*sc, y.y*sc, y.z*sc, y.w*sc};
        uint4 hw, lw;
        split8(vals, hw, lw);
        size_t base = (((size_t)(r >> 4) * 16 + (lane >> 2)) * 64 + (lane & 3) * 16 + (r & 15)) * 8;
        *(uint4*)(dh + base) = hw;
        *(uint4*)(dl + base) = lw;
    }
}

// transpose-pack a [512,512] weight: Bp rows = output cols
__global__ __launch_bounds__(256) void k_wpack(
    const float* __restrict__ W,
    unsigned short* __restrict__ dh, unsigned short* __restrict__ dl) {
    int u = threadIdx.x >> 6, lane = threadIdx.x & 63;
    int mt = blockIdx.x, kb = blockIdx.y * 4 + u;
    int n = mt * 16 + (lane & 15);
    int k = kb * 32 + (lane >> 4) * 8;
    float vals[8];
    #pragma unroll
    for (int j = 0; j < 8; ++j) vals[j] = W[(size_t)(k + j) * DD_ + n];
    uint4 hw, lw;
    split8(vals, hw, lw);
    size_t base = (((size_t)mt * 16 + kb) * 64 + lane) * 8;
    *(uint4*)(dh + base) = hw;
    *(uint4*)(dl + base) = lw;
}

// ---------------- MFMA GEMM, C = A . B^T via split-bf16 ----------
// THREE=1: 3-mfma hi/lo (hh+hl+lh). THREE=0: 2-mfma (hh+hl) — dist GEMM only.
// MODE 0: dist — store C fp32 to Cout (stride KK_)
// MODE 2: dense — store C+bias (opt relu) to Cout (stride DD_), rows < Mrows
// MODE 4: fused Wd — grid (8,47): bx<4 = dense (Wd1,bias,store QE);
//         bx>=4 = rec loss (Wd2 at B+2*WPACKE, bias2) -> gacc[3]. bx==4 blocks
//         additionally fold the commit loss sum((q-h)^2) from the A tile -> gacc[2].
// R8 lesson: epilogue scratch aliases the 32KB lds buffer (separate __shared__
// arrays push LDS_Block_Size to 33280 -> one fewer block/CU).
template<int MODE, int THREE>
__global__ __launch_bounds__(256) void gemm_mfma(
    const unsigned short* __restrict__ Ah, const unsigned short* __restrict__ Al,
    const unsigned short* __restrict__ Bh, const unsigned short* __restrict__ Bl,
    float* __restrict__ Cout, const float* __restrict__ bias,
    const float* __restrict__ Ref, int relu, int Mrows,
    float* __restrict__ gacc, const float* __restrict__ bias2) {
    int bx = blockIdx.x, by = blockIdx.y;
    int side = (MODE == 4) ? (bx >> 2) : 0;
    int bxe  = (MODE == 4) ? (bx & 3) : bx;
    __shared__ char lds[32768];  // Ah|Al|Bh|Bl tiles, 8 KB each; epilogue scratch aliased
    float* wred0 = (float*)lds;          // valid after final barrier
    float* wred1 = (float*)lds + 4;
    int tid = threadIdx.x;
    int wave = tid >> 6, lane = tid & 63;
    int gmtA = by * 8, gmtB = bxe * 8;
    const unsigned short* garr; int gmt0;
    if (wave == 0)      { garr = Ah; gmt0 = gmtA; }
    else if (wave == 1) { garr = Al; gmt0 = gmtA; }
    else if (wave == 2) { garr = Bh + (size_t)side * 2 * WPACKE; gmt0 = gmtB; }
    else                { garr = Bl + (size_t)side * 2 * WPACKE; gmt0 = gmtB; }
    char* ldst = lds + wave * 8192;
    f32x4 acc[4][4];
    #pragma unroll
    for (int i = 0; i < 4; ++i)
        #pragma unroll
        for (int j = 0; j < 4; ++j) acc[i][j] = (f32x4){0.f, 0.f, 0.f, 0.f};
    float commitAcc = 0.f;
    int wm = wave >> 1, wn = wave & 1;
    for (int kb = 0; kb < 16; ++kb) {
        if (THREE || wave != 1) {
            #pragma unroll
            for (int t = 0; t < 8; ++t) {
                const char* g = (const char*)garr + (((size_t)(gmt0 + t) * 16 + kb) * 1024) + lane * 16;
                gld_lds16(ldst + t * 1024 + lane * 16, g);
            }
        }
        __syncthreads();
        // commit-loss fold: reconstruct q from the A tile, compare vs h (=Ref)
        if (MODE == 4 && bx == 4) {
            int rg = tid >> 1, half = tid & 1;
            int m = by * 128 + rg;
            if (m < Mrows) {
                int tt = rg >> 4, r = rg & 15;
                const float* hp = Ref + (size_t)m * DD_ + kb * 32 + half * 16;
                float4 h0 = ((const float4*)hp)[0], h1 = ((const float4*)hp)[1];
                float4 h2 = ((const float4*)hp)[2], h3 = ((const float4*)hp)[3];
                float hv[16] = {h0.x,h0.y,h0.z,h0.w, h1.x,h1.y,h1.z,h1.w,
                                h2.x,h2.y,h2.z,h2.w, h3.x,h3.y,h3.z,h3.w};
                #pragma unroll
                for (int j2 = 0; j2 < 16; ++j2) {
                    int sub = half * 2 + (j2 >> 3), j = j2 & 7;
                    int off = tt * 1024 + (sub * 16 + r) * 16 + j * 2;
                    u32 hb = *(const unsigned short*)(lds + off);
                    u32 lb = *(const unsigned short*)(lds + 8192 + off);
                    float q = __uint_as_float(hb << 16) + __uint_as_float(lb << 16);
                    float d = q - hv[j2];
                    commitAcc = fmaf(d, d, commitAcc);
                }
            }
        }
        bf16x8 a_h[4], a_l[4], b_h[4], b_l[4];
        #pragma unroll
        for (int i = 0; i < 4; ++i) {
            int at = wm * 4 + i, bt = wn * 4 + i;
            a_h[i] = *(const bf16x8*)(lds + 0     + at * 1024 + lane * 16);
            if (THREE) a_l[i] = *(const bf16x8*)(lds + 8192 + at * 1024 + lane * 16);
            b_h[i] = *(const bf16x8*)(lds + 16384 + bt * 1024 + lane * 16);
            b_l[i] = *(const bf16x8*)(lds + 24576 + bt * 1024 + lane * 16);
        }
        #pragma unroll
        for (int i = 0; i < 4; ++i)
            #pragma unroll
            for (int j = 0; j < 4; ++j) {
                acc[i][j] = __builtin_amdgcn_mfma_f32_16x16x32_bf16(a_h[i], b_h[j], acc[i][j], 0, 0, 0);
                acc[i][j] = __builtin_amdgcn_mfma_f32_16x16x32_bf16(a_h[i], b_l[j], acc[i][j], 0, 0, 0);
                if (THREE)
                    acc[i][j] = __builtin_amdgcn_mfma_f32_16x16x32_bf16(a_l[i], b_h[j], acc[i][j], 0, 0, 0);
            }
        __syncthreads();   // also makes lds safe for epilogue-scratch reuse
    }
    // C/D layout: col = lane&15, row = (lane>>4)*4 + reg
    int m_base = by * 128 + wm * 64;
    int n_base = bxe * 128 + wn * 64;
    int rq = lane >> 4, cc = lane & 15;
    if (MODE == 0) {
        #pragma unroll
        for (int i = 0; i < 4; ++i) {
            int m = m_base + i * 16 + rq * 4;
            #pragma unroll
            for (int j = 0; j < 4; ++j) {
                int n = n_base + j * 16 + cc;
                #pragma unroll
                for (int r = 0; r < 4; ++r) {
                    if (m + r < NN_) Cout[(size_t)(m + r) * KK_ + n] = acc[i][j][r];
                }
            }
        }
    } else if (MODE == 2 || (MODE == 4 && side == 0)) {
        #pragma unroll
        for (int i = 0; i < 4; ++i) {
            int m = m_base + i * 16 + rq * 4;
            #pragma unroll
            for (int j = 0; j < 4; ++j) {
                int n = n_base + j * 16 + cc;
                float bv = bias[n];
                #pragma unroll
                for (int r = 0; r < 4; ++r) {
                    if (m + r < Mrows) {
                        float v = acc[i][j][r] + bv;
                        if (relu) v = fmaxf(v, 0.f);
                        Cout[(size_t)(m + r) * DD_ + n] = v;
                    }
                }
            }
        }
    } else {  // MODE 4 rec-loss side
        const float* bs = bias2;
        float s = 0.f;
        #pragma unroll
        for (int i = 0; i < 4; ++i) {
            int m = m_base + i * 16 + rq * 4;
            #pragma unroll
            for (int j = 0; j < 4; ++j) {
                int n = n_base + j * 16 + cc;
                float bv = bs[n];
                #pragma unroll
                for (int r = 0; r < 4; ++r) {
                    if (m + r < Mrows) {
                        float d = Ref[(size_t)(m + r) * DD_ + n] - (acc[i][j][r] + bv);
                        s = fmaf(d, d, s);
                    }
                }
            }
        }
        for (int off = 32; off; off >>= 1) s += __shfl_xor(s, off);
        if (lane == 0) wred0[wave] = s;
        if (MODE == 4 && bx == 4) {
            float c = commitAcc;
            for (int off = 32; off; off >>= 1) c += __shfl_xor(c, off);
            if (lane == 0) wred1[wave] = c;
        }
        __syncthreads();
        if (tid == 0) {
            atomicAdd(&gacc[3], wred0[0] + wred0[1] + wred0[2] + wred0[3]);
            if (MODE == 4 && bx == 4)
                atomicAdd(&gacc[2], wred1[0] + wred1[1] + wred1[2] + wred1[3]);
        }
    }
}

// ---------------- dedicated rpass GEMM: 128x128 triangular -------
// R9 post-mortem: XCD-chunked triangle order cut FETCH (84->76.6MB) but cost
// 18% time — achieved BW 1100->847 GB/s: concentrating panel-sharing blocks
// on one XCD serializes the miss stream through one L2 while identity order
// fetches redundant copies IN PARALLEL across 8 L2s. This kernel is
// fetch-parallelism-bound, not bytes-bound. Identity mapping (r5's 78.7us
// config) + dedicated compile + aliased epilogue scratch.
__global__ __launch_bounds__(256) void gemm_rpass(
    const unsigned short* __restrict__ Qh, const unsigned short* __restrict__ Ql,
    float* __restrict__ gacc, u32* __restrict__ minKey, u32* __restrict__ maxKey) {
    int L = blockIdx.x;
    int bx = (int)((sqrtf(8.f * (float)L + 1.f) - 1.f) * 0.5f);
    while ((bx + 1) * (bx + 2) / 2 <= L) ++bx;
    while (bx * (bx + 1) / 2 > L) --bx;
    int by = L - bx * (bx + 1) / 2;     // bx >= by
    __shared__ char lds[32768];  // Ah|Al|Bh|Bl tiles, 8 KB each; epilogue scratch aliased
    float* wr0 = (float*)lds;
    float* wr1 = (float*)lds + 4;
    float* wr2 = (float*)lds + 8;
    float* wr3 = (float*)lds + 12;
    int tid = threadIdx.x;
    int wave = tid >> 6, lane = tid & 63;
    int gmtA = by * 8, gmtB = bx * 8;
    const unsigned short* garr; int gmt0;
    if (wave == 0)      { garr = Qh; gmt0 = gmtA; }
    else if (wave == 1) { garr = Ql; gmt0 = gmtA; }
    else if (wave == 2) { garr = Qh; gmt0 = gmtB; }
    else                { garr = Ql; gmt0 = gmtB; }
    char* ldst = lds + wave * 8192;
    f32x4 acc[4][4];
    #pragma unroll
    for (int i = 0; i < 4; ++i)
        #pragma unroll
        for (int j = 0; j < 4; ++j) acc[i][j] = (f32x4){0.f, 0.f, 0.f, 0.f};
    int wm = wave >> 1, wn = wave & 1;
    for (int kb = 0; kb < 16; ++kb) {
        #pragma unroll
        for (int t = 0; t < 8; ++t) {
            const char* g = (const char*)garr + (((size_t)(gmt0 + t) * 16 + kb) * 1024) + lane * 16;
            gld_lds16(ldst + t * 1024 + lane * 16, g);
        }
        __syncthreads();
        bf16x8 a_h[4], a_l[4], b_h[4], b_l[4];
        #pragma unroll
        for (int i = 0; i < 4; ++i) {
            int at = wm * 4 + i, bt = wn * 4 + i;
            a_h[i] = *(const bf16x8*)(lds + 0     + at * 1024 + lane * 16);
            a_l[i] = *(const bf16x8*)(lds + 8192  + at * 1024 + lane * 16);
            b_h[i] = *(const bf16x8*)(lds + 16384 + bt * 1024 + lane * 16);
            b_l[i] = *(const bf16x8*)(lds + 24576 + bt * 1024 + lane * 16);
        }
        #pragma unroll
        for (int i = 0; i < 4; ++i)
            #pragma unroll
            for (int j = 0; j < 4; ++j) {
                acc[i][j] = __builtin_amdgcn_mfma_f32_16x16x32_bf16(a_h[i], b_h[j], acc[i][j], 0, 0, 0);
                acc[i][j] = __builtin_amdgcn_mfma_f32_16x16x32_bf16(a_h[i], b_l[j], acc[i][j], 0, 0, 0);
                acc[i][j] = __builtin_amdgcn_mfma_f32_16x16x32_bf16(a_l[i], b_h[j], acc[i][j], 0, 0, 0);
            }
        __syncthreads();   // also makes lds safe for epilogue-scratch reuse
    }
    int m_base = by * 128 + wm * 64;
    int n_base = bx * 128 + wn * 64;
    int rq = lane >> 4, cc = lane & 15;
    float tsum = 0.f, tsq = 0.f, tmin = 3.4e38f, tmax = -3.4e38f;
    #pragma unroll
    for (int i = 0; i < 4; ++i) {
        #pragma unroll
        for (int j = 0; j < 4; ++j) {
            #pragma unroll
            for (int r = 0; r < 4; ++r) {
                int m = m_base + i * 16 + rq * 4 + r;
                int n = n_base + j * 16 + cc;
                if (m < NN_ && n < NN_ && n >= m) {
                    float v = acc[i][j][r];
                    float w = (n > m) ? 2.f : 1.f;
                    tsum += w * v;
                    tsq  += w * v * v;
                    tmin = fminf(tmin, v);
                    tmax = fmaxf(tmax, v);
                }
            }
        }
    }
    for (int off = 32; off; off >>= 1) {
        tsum += __shfl_xor(tsum, off);
        tsq  += __shfl_xor(tsq, off);
        tmin = fminf(tmin, __shfl_xor(tmin, off));
        tmax = fmaxf(tmax, __shfl_xor(tmax, off));
    }
    if (lane == 0) { wr0[wave] = tsum; wr1[wave] = tsq; wr2[wave] = tmin; wr3[wave] = tmax; }
    __syncthreads();
    if (tid == 0) {
        atomicAdd(&gacc[0], wr0[0] + wr0[1] + wr0[2] + wr0[3]);
        atomicAdd(&gacc[1], wr1[0] + wr1[1] + wr1[2] + wr1[3]);
        atomicMin(minKey, okey(fminf(fminf(wr2[0], wr2[1]), fminf(wr2[2], wr2[3]))));
        atomicMax(maxKey, okey(fmaxf(fmaxf(wr3[0], wr3[1]), fmaxf(wr3[2], wr3[3]))));
    }
}

// exact-fp32 argmax rescue — persistent, wave-per-row.
__global__ __launch_bounds__(256) void k_rescore(
    const float* __restrict__ dist, const float* __restrict__ h,
    const float* __restrict__ rnorm, const float* __restrict__ cb,
    const float* __restrict__ scale, int* __restrict__ ind) {
    int w = threadIdx.x >> 6, lane = threadIdx.x & 63;
    for (int row = blockIdx.x * 4 + w; row < NN_; row += gridDim.x * 4) {
        const float4* dr4 = (const float4*)(dist + (size_t)row * KK_);
        float4 vbuf[16];
        float lmax = -3.4e38f;
        #pragma unroll
        for (int it = 0; it < 16; ++it) {
            float4 v = dr4[lane + it * 64];
            vbuf[it] = v;
            lmax = fmaxf(lmax, fmaxf(fmaxf(v.x, v.y), fmaxf(v.z, v.w)));
        }
        for (int off = 32; off; off >>= 1) lmax = fmaxf(lmax, __shfl_xor(lmax, off));
        float thr = lmax - 1e-3f;
        float hr = rnorm[row];
        const float* hp = h + (size_t)row * DD_;
        u64 best = 0;
        #pragma unroll 1
        for (int it = 0; it < 16; ++it) {
            float4 v = vbuf[it];
            u32 m4 = (v.x >= thr ? 1u : 0u) | (v.y >= thr ? 2u : 0u)
                   | (v.z >= thr ? 4u : 0u) | (v.w >= thr ? 8u : 0u);
            u64 bal = __ballot(m4 != 0);
            while (bal) {
                int l = __ffsll((unsigned long long)bal) - 1;
                bal &= bal - 1;
                u32 mm = __shfl(m4, l);
                while (mm) {
                    int j = __ffs(mm) - 1;
                    mm &= mm - 1;
                    int col = (l + it * 64) * 4 + j;
                    const float* cp = cb + (size_t)col * DD_;
                    float dot = 0.f;
                    #pragma unroll
                    for (int jj = 0; jj < 8; ++jj)
                        dot = fmaf(hp[lane + jj * 64], cp[lane + jj * 64], dot);
                    for (int off = 32; off; off >>= 1) dot += __shfl_xor(dot, off);
                    u64 key = packKey(dot * hr * scale[col], col);
                    if (key > best) best = key;   // dot wave-uniform after butterfly
                }
            }
        }
        if (lane == 0) ind[row] = (int)(~(u32)(best & 0xFFFFFFFFull));
    }
}

// ---------------- fp32 GEMM (kept only for the 6000x40 output) ----------------
__global__ __launch_bounds__(256) void gemm_nn(
    const float* __restrict__ A, const float* __restrict__ B,
    const float* __restrict__ bias, float* __restrict__ C,
    int M, int Ncols, int Kdim) {
    __shared__ float As[16][68];
    __shared__ float Bs[16][68];
    int tid = threadIdx.x;
    int tx = tid & 15, ty = tid >> 4;
    int m0 = blockIdx.y * 64, n0 = blockIdx.x * 64;
    float cv[4][4] = {};
    int ar = tid >> 2;
    int ak = (tid & 3) << 2;
    int am = m0 + ar;
    const float* Arow = (am < M) ? (A + (size_t)am * Kdim) : nullptr;
    int bk = tid >> 4;
    int bn = (tid & 15) << 2;
    for (int k0 = 0; k0 < Kdim; k0 += 16) {
        float4 av = make_float4(0.f, 0.f, 0.f, 0.f);
        if (Arow) av = *(const float4*)(Arow + k0 + ak);
        As[ak + 0][ar] = av.x; As[ak + 1][ar] = av.y;
        As[ak + 2][ar] = av.z; As[ak + 3][ar] = av.w;
        float4 bv = make_float4(0.f, 0.f, 0.f, 0.f);
        if (n0 + bn < Ncols)
            bv = *(const float4*)(B + (size_t)(k0 + bk) * Ncols + n0 + bn);
        Bs[bk][bn + 0] = bv.x; Bs[bk][bn + 1] = bv.y;
        Bs[bk][bn + 2] = bv.z; Bs[bk][bn + 3] = bv.w;
        __syncthreads();
        #pragma unroll
        for (int kk = 0; kk < 16; ++kk) {
            float4 a4 = *(const float4*)&As[kk][ty << 2];
            float4 b4 = *(const float4*)&Bs[kk][tx << 2];
            float ax[4] = {a4.x, a4.y, a4.z, a4.w};
            float bx[4] = {b4.x, b4.y, b4.z, b4.w};
            #pragma unroll
            for (int i = 0; i < 4; ++i)
                #pragma unroll
                for (int j = 0; j < 4; ++j)
                    cv[i][j] = fmaf(ax[i], bx[j], cv[i][j]);
        }
        __syncthreads();
    }
    #pragma unroll
    for (int i = 0; i < 4; ++i) {
        int m = m0 + (ty << 2) + i;
        if (m >= M) continue;
        #pragma unroll
        for (int j = 0; j < 4; ++j) {
            int n = n0 + (tx << 2) + j;
            if (n >= Ncols) continue;
            C[(size_t)m * Ncols + n] = cv[i][j] + bias[n];
        }
    }
}

// ---------------- edge multiplicity hash (for sum m^2 only) ----------------
__global__ void k_hash(const int* __restrict__ src, const int* __restrict__ dst,
                       int* __restrict__ hkey, int* __restrict__ hcnt) {
    int e = blockIdx.x * 256 + threadIdx.x;
    if (e >= EE_) return;
    int key = dst[e] * NN_ + src[e];
    u32 h = ((u32)key * 2654435761u) & HMASK;
    while (true) {
        int old = atomicCAS(&hkey[h], -1, key);
        if (old == -1 || old == key) { atomicAdd(&hcnt[h], 1); break; }
        h = (h + 1) & HMASK;
    }
}

__global__ __launch_bounds__(256) void k_m2scan(const int* __restrict__ hcnt, float* __restrict__ gacc) {
    float s = 0.f;
    for (int i = blockIdx.x * 256 + threadIdx.x; i < HSZ; i += gridDim.x * 256) {
        float c = (float)hcnt[i];
        s = fmaf(c, c, s);
    }
    for (int off = 32; off; off >>= 1) s += __shfl_xor(s, off);
    __shared__ float w1[4];
    int lane = threadIdx.x & 63, wv = threadIdx.x >> 6;
    if (lane == 0) w1[wv] = s;
    __syncthreads();
    if (threadIdx.x == 0) atomicAdd(&gacc[4], w1[0] + w1[1] + w1[2] + w1[3]);
}

// ---------------- final loss assembly ----------------
__global__ void k_final(const float* __restrict__ gacc, const u32* __restrict__ minKey,
                        const u32* __restrict__ maxKey, float* __restrict__ lossOut) {
    if (threadIdx.x != 0 || blockIdx.x != 0) return;
    double Rsum = gacc[0], Rsq = gacc[1], commitS = gacc[2], recS = gacc[3];
    double m2 = gacc[4], mr = gacc[5], ms = (double)EE_;
    double mn = (double)dkey(*minKey);
    double mx = (double)dkey(*maxKey);
    double den = mx - mn;
    double NN2 = (double)NN_ * (double)NN_;
    double sum_aq2 = (Rsq - 2.0 * mn * Rsum + NN2 * mn * mn) / (den * den);
    double sum_maq = (mr - mn * ms) / den;
    double total = sum_aq2 + m2 - 2.0 * sum_maq;
    double edge = sqrt(total / NN2);
    double commit = 0.25 * commitS / ((double)NN_ * (double)DD_);
    double rec = recS / ((double)NN_ * (double)DD_);
    *lossOut = (float)(rec + edge + commit);
}

extern "C" void kernel_launch(void* const* d_in, const int* in_sizes, int n_in,
                              void* d_out, int out_size, void* d_ws, size_t ws_size,
                              hipStream_t stream) {
    const float* feats = (const float*)d_in[0];
    const float* W1 = (const float*)d_in[1];
    const float* b1 = (const float*)d_in[2];
    const float* W2 = (const float*)d_in[3];
    const float* b2v = (const float*)d_in[4];
    const float* Wd1 = (const float*)d_in[5];
    const float* bd1 = (const float*)d_in[6];
    const float* Wd2 = (const float*)d_in[7];
    const float* bd2 = (const float*)d_in[8];
    const float* Wl = (const float*)d_in[9];
    const float* bl = (const float*)d_in[10];
    const float* cb = (const float*)d_in[11];
    const int* src = (const int*)d_in[12];
    const int* dst = (const int*)d_in[13];

    float* outF = (float*)d_out;
    float* lossOut = outF + (size_t)NN_ * OO_;     // element 240000
    float* distOut = lossOut + 1;                  // element 240001

    char* w = (char*)d_ws;
    size_t off = 0;
    auto alloc = [&](size_t bytes) -> void* {
        void* p = w + off;
        off = (off + bytes + 255) & ~(size_t)255;
        return p;
    };
    // zone0: zero-init
    float* gacc = (float*)alloc(64);
    u32* maxKey = (u32*)alloc(4);
    int* degin = (int*)alloc((size_t)NN_ * 4);
    int* degout = (int*)alloc((size_t)NN_ * 4);
    int* cursor = (int*)alloc((size_t)NN_ * 4);
    int* hcnt = (int*)alloc((size_t)HSZ * 4);
    size_t z0end = off;
    // zone1: 0xFF-init
    int* hkey = (int*)alloc((size_t)HSZ * 4);
    u32* minKey = (u32*)alloc(4);
    size_t z1end = off;
    // uninit scratch
    int* offs = (int*)alloc((size_t)(NN_ + 1) * 4);
    int* esrc = (int*)alloc((size_t)EE_ * 4);
    float* rin = (float*)alloc((size_t)NN_ * 4);
    float* rout = (float*)alloc((size_t)NN_ * 4);
    int* ind = (int*)alloc((size_t)NN_ * 4);
    float* scale = (float*)alloc((size_t)KK_ * 4);
    float* rnorm = (float*)alloc((size_t)NN_ * 4);
    float* h = (float*)alloc((size_t)NN_ * DD_ * 4);       // h, later h2
    float* QE = (float*)alloc((size_t)NN_ * DD_ * 4);
    const size_t NPACK = (size_t)MT_A * 16 * DD_;          // node-sized packed half
    unsigned short* P1 = (unsigned short*)alloc(NPACK * 2 * 2);  // aggp -> qcp -> agg2p
    unsigned short* P2 = (unsigned short*)alloc(NPACK * 2 * 2);  // hnp -> QEp
    unsigned short* enp = (unsigned short*)alloc((size_t)KK_ * DD_ * 2 * 2);
    const size_t WPACK = (size_t)32 * 16 * DD_;            // 512-row packed half
    unsigned short* W1p = (unsigned short*)alloc(WPACK * 2 * 2);
    unsigned short* Wd1p = (unsigned short*)alloc(WPACK * 2 * 2);  // MUST stay
    unsigned short* Wd2p = (unsigned short*)alloc(WPACK * 2 * 2);  // contiguous (MODE4)
    unsigned short* W2p = (unsigned short*)alloc(WPACK * 2 * 2);

    unsigned short* aggp_h = P1,  *aggp_l = P1 + NPACK;
    unsigned short* qcp_h  = P1,  *qcp_l  = P1 + NPACK;
    unsigned short* ag2p_h = P1,  *ag2p_l = P1 + NPACK;
    unsigned short* hnp_h  = P2,  *hnp_l  = P2 + NPACK;
    unsigned short* QEp_h  = P2,  *QEp_l  = P2 + NPACK;
    unsigned short* enp_h  = enp, *enp_l  = enp + (size_t)KK_ * DD_;

    hipMemsetAsync(w, 0, z0end, stream);
    hipMemsetAsync(w + z0end, 0xFF, z1end - z0end, stream);

    const int TB = 256;
    k_deg<<<(EE_ + TB - 1) / TB, TB, 0, stream>>>(src, dst, degout, degin);
    k_rsqrtdeg<<<(NN_ + TB - 1) / TB, TB, 0, stream>>>(degout, degin, rout, rin);
    k_scan<<<1, 1024, 0, stream>>>(degin, offs, NN_);
    k_fill<<<(EE_ + TB - 1) / TB, TB, 0, stream>>>(src, dst, offs, cursor, esrc);
    k_wpack<<<dim3(32, 4), TB, 0, stream>>>(W1, W1p, W1p + WPACK);
    k_wpack<<<dim3(32, 4), TB, 0, stream>>>(Wd1, Wd1p, Wd1p + WPACK);
    k_wpack<<<dim3(32, 4), TB, 0, stream>>>(Wd2, Wd2p, Wd2p + WPACK);
    k_wpack<<<dim3(32, 4), TB, 0, stream>>>(W2, W2p, W2p + WPACK);
    k_aggs<0><<<1024, TB, 0, stream>>>(feats, esrc, offs, rout, rin, aggp_h, aggp_l, nullptr);
    gemm_mfma<2,1><<<dim3(4, NB_N), TB, 0, stream>>>(aggp_h, aggp_l, W1p, W1p + WPACK,
                                                     h, b1, nullptr, 1, NN_, nullptr, nullptr);
    k_rowpack<1><<<1024, TB, 0, stream>>>(h, nullptr, nullptr, rnorm, NN_, hnp_h, hnp_l);
    k_rowpack<1><<<1024, TB, 0, stream>>>(cb, nullptr, nullptr, scale, KK_, enp_h, enp_l);
    gemm_mfma<0,0><<<dim3(KK_ / 128, NB_N), TB, 0, stream>>>(hnp_h, hnp_l, enp_h, enp_l,
                                                             distOut, nullptr, nullptr, 0, NN_,
                                                             nullptr, nullptr);
    k_rescore<<<1024, TB, 0, stream>>>(distOut, h, rnorm, cb, scale, ind);
    k_rowpack<0><<<1024, TB, 0, stream>>>(cb, ind, scale, nullptr, NN_, qcp_h, qcp_l);
    // fused Wd1+Wd2 GEMM: stores QE (bx<4), rec loss (bx>=4), commit fold (bx==4)
    gemm_mfma<4,1><<<dim3(8, NB_N), TB, 0, stream>>>(qcp_h, qcp_l, Wd1p, Wd1p + WPACK,
                                                     QE, bd1, h, 0, NN_, gacc, bd2);
    k_rowpack<0><<<1024, TB, 0, stream>>>(QE, nullptr, nullptr, nullptr, NN_, QEp_h, QEp_l);
    gemm_rpass<<<1128, TB, 0, stream>>>(QEp_h, QEp_l, gacc, minKey, maxKey);
    k_hash<<<(EE_ + TB - 1) / TB, TB, 0, stream>>>(src, dst, hkey, hcnt);
    k_m2scan<<<512, TB, 0, stream>>>(hcnt, gacc);
    k_aggs<1><<<1024, TB, 0, stream>>>(QE, esrc, offs, rout, rin, ag2p_h, ag2p_l, gacc);
    gemm_mfma<2,1><<<dim3(4, NB_N), TB, 0, stream>>>(ag2p_h, ag2p_l, W2p, W2p + WPACK,
                                                     h, b2v, nullptr, 1, NN_, nullptr, nullptr);
    gemm_nn<<<dim3(1, 94), TB, 0, stream>>>(h, Wl, bl, outF, NN_, OO_, DD_);
    k_final<<<1, 64, 0, stream>>>(gacc, minKey, maxKey, lossOut);
}

// Round 11
// 649.215 us; speedup vs baseline: 1.0602x; 1.0235x over previous
//
#include <hip/hip_runtime.h>

typedef unsigned int u32;
typedef unsigned long long u64;

#define NN_ 6000
#define EE_ 192000
#define DD_ 512
#define KK_ 4096
#define OO_ 40
#define HSZ (1 << 19)
#define HMASK (HSZ - 1)
#define MT_A 376   // ceil(6000/16) m-tiles for node-sized packed arrays
#define NB_N 47    // 6016/128 blocks
#define WPACKE (32 * 16 * 512)   // elems per packed 512-row half

typedef __bf16 bf16x8 __attribute__((ext_vector_type(8)));
typedef float f32x4 __attribute__((ext_vector_type(4)));

__device__ __forceinline__ u32 okey(float f) {
    u32 u = __float_as_uint(f);
    return (u & 0x80000000u) ? ~u : (u | 0x80000000u);
}
__device__ __forceinline__ float dkey(u32 u) {
    u32 b = (u & 0x80000000u) ? (u ^ 0x80000000u) : ~u;
    return __uint_as_float(b);
}
__device__ __forceinline__ u64 packKey(float v, int col) {
    return ((u64)okey(v) << 32) | (u32)(~(u32)col);
}
__device__ __forceinline__ unsigned short f2bf_rne(float f) {
    u32 x = __float_as_uint(f);
    u32 r = x + 0x7fffu + ((x >> 16) & 1u);
    return (unsigned short)(r >> 16);
}
__device__ __forceinline__ void gld_lds16(void* l, const void* g) {
    __builtin_amdgcn_global_load_lds(
        (const __attribute__((address_space(1))) unsigned int*)g,
        (__attribute__((address_space(3))) unsigned int*)l, 16, 0, 0);
}
// compiler+hw ordering fence for same-wave LDS write->read (rule #18 analog)
#define LGKM0 do { asm volatile("s_waitcnt lgkmcnt(0)" ::: "memory"); __builtin_amdgcn_sched_barrier(0); } while (0)

// ---------------- graph prep ----------------
__global__ void k_deg(const int* __restrict__ src, const int* __restrict__ dst,
                      int* __restrict__ degout, int* __restrict__ degin) {
    int e = blockIdx.x * 256 + threadIdx.x;
    if (e >= EE_) return;
    atomicAdd(&degout[src[e]], 1);
    atomicAdd(&degin[dst[e]], 1);
}

__global__ void k_rsqrtdeg(const int* __restrict__ degout, const int* __restrict__ degin,
                           float* __restrict__ rout, float* __restrict__ rin) {
    int i = blockIdx.x * 256 + threadIdx.x;
    if (i >= NN_) return;
    int doV = degout[i]; if (doV < 1) doV = 1;
    int diV = degin[i];  if (diV < 1) diV = 1;
    rout[i] = rsqrtf((float)doV);
    rin[i]  = rsqrtf((float)diV);
}

// 6000-elem scan, 1 block x 1024 threads, 6 elems/thread (20 syncs)
__global__ void k_scan(const int* __restrict__ cnt, int* __restrict__ offs, int n) {
    __shared__ int part[1024];
    int t = threadIdx.x;
    int base = t * 6;
    int v[6]; int s = 0;
    #pragma unroll
    for (int j = 0; j < 6; ++j) { int i = base + j; v[j] = (i < n) ? cnt[i] : 0; s += v[j]; }
    part[t] = s;
    __syncthreads();
    for (int off = 1; off < 1024; off <<= 1) {
        int x = (t >= off) ? part[t - off] : 0;
        __syncthreads();
        part[t] += x;
        __syncthreads();
    }
    int run = (t > 0) ? part[t - 1] : 0;
    if (t == 0) offs[0] = 0;
    #pragma unroll
    for (int j = 0; j < 6; ++j) {
        int i = base + j;
        run += v[j];
        if (i < n) offs[i + 1] = run;
    }
}

__global__ void k_fill(const int* __restrict__ src, const int* __restrict__ dst,
                       const int* __restrict__ offs, int* __restrict__ cursor,
                       int* __restrict__ esrc) {
    int e = blockIdx.x * 256 + threadIdx.x;
    if (e >= EE_) return;
    int d = dst[e];
    int pos = offs[d] + atomicAdd(&cursor[d], 1);
    esrc[pos] = src[e];
}

// split 8 floats into bf16 hi/lo packed words
__device__ __forceinline__ void split8(const float* vals, uint4& hw, uint4& lw) {
    u32 h[4], l[4];
    #pragma unroll
    for (int j = 0; j < 4; ++j) {
        unsigned short h0 = f2bf_rne(vals[2*j]),   h1 = f2bf_rne(vals[2*j+1]);
        float hf0 = __uint_as_float((u32)h0 << 16), hf1 = __uint_as_float((u32)h1 << 16);
        unsigned short l0 = f2bf_rne(vals[2*j] - hf0), l1 = f2bf_rne(vals[2*j+1] - hf1);
        h[j] = (u32)h0 | ((u32)h1 << 16);
        l[j] = (u32)l0 | ((u32)l1 << 16);
    }
    hw = make_uint4(h[0], h[1], h[2], h[3]);
    lw = make_uint4(l[0], l[1], l[2], l[3]);
}

// ---------------- persistent sliced aggregation (L2-resident gather) ----------------
template<int UNW>
__global__ __launch_bounds__(256) void k_aggs(
    const float* __restrict__ X, const int* __restrict__ esrc,
    const int* __restrict__ offs, const float* __restrict__ rout,
    const float* __restrict__ rin,
    unsigned short* __restrict__ dh, unsigned short* __restrict__ dl,
    float* __restrict__ gacc) {
    __shared__ float packbuf[4][128];
    __shared__ float mred[4];
    int b = blockIdx.x;                 // [0,1024)
    int xcd = b & 7;                    // heuristic XCD id (round-robin)
    int slice = xcd >> 1;               // 0..3, pinned per XCD pair
    int w = threadIdx.x >> 6, lane = threadIdx.x & 63;
    int wid = ((((b >> 3) << 1) | (xcd & 1)) << 2) + w;  // [0,1024) per slice
    const float* Xc = X + slice * 128 + lane * 2;        // this lane's col pair
    float mrAcc = 0.f;
    for (int node = wid; node < NN_; node += 1024) {
        int beg = offs[node], end = offs[node + 1];
        float a0 = 0.f, a1 = 0.f, u0 = 0.f, u1 = 0.f;
        for (int e = beg; e < end; ) {
            int cnt = end - e; if (cnt > 64) cnt = 64;
            int sreg = 0; float wreg = 0.f;
            if (lane < cnt) { sreg = esrc[e + lane]; wreg = rout[sreg]; }
            int j = 0;
            for (; j + 4 <= cnt; j += 4) {
                int s0 = __shfl(sreg, j),     s1 = __shfl(sreg, j + 1);
                int s2 = __shfl(sreg, j + 2), s3 = __shfl(sreg, j + 3);
                float w0 = __shfl(wreg, j),     w1 = __shfl(wreg, j + 1);
                float w2 = __shfl(wreg, j + 2), w3 = __shfl(wreg, j + 3);
                float2 v0 = *(const float2*)(Xc + (size_t)s0 * DD_);
                float2 v1 = *(const float2*)(Xc + (size_t)s1 * DD_);
                float2 v2 = *(const float2*)(Xc + (size_t)s2 * DD_);
                float2 v3 = *(const float2*)(Xc + (size_t)s3 * DD_);
                a0 = fmaf(w0, v0.x, a0); a1 = fmaf(w0, v0.y, a1);
                a0 = fmaf(w1, v1.x, a0); a1 = fmaf(w1, v1.y, a1);
                a0 = fmaf(w2, v2.x, a0); a1 = fmaf(w2, v2.y, a1);
                a0 = fmaf(w3, v3.x, a0); a1 = fmaf(w3, v3.y, a1);
                if (UNW) {
                    u0 += (v0.x + v1.x) + (v2.x + v3.x);
                    u1 += (v0.y + v1.y) + (v2.y + v3.y);
                }
            }
            for (; j < cnt; ++j) {
                int sj = __shfl(sreg, j); float wj = __shfl(wreg, j);
                float2 v = *(const float2*)(Xc + (size_t)sj * DD_);
                a0 = fmaf(wj, v.x, a0); a1 = fmaf(wj, v.y, a1);
                if (UNW) { u0 += v.x; u1 += v.y; }
            }
            e += cnt;
        }
        float ri = rin[node];
        packbuf[w][lane * 2] = a0 * ri;
        packbuf[w][lane * 2 + 1] = a1 * ri;
        LGKM0;
        if (lane < 16) {
            uint4 hw, lw;
            split8(&packbuf[w][(lane >> 2) * 32 + (lane & 3) * 8], hw, lw);
            int kb = slice * 4 + (lane >> 2);
            int lo = (lane & 3) * 16 + (node & 15);
            size_t base = (((size_t)(node >> 4) * 16 + kb) * 64 + lo) * 8;
            *(uint4*)(dh + base) = hw;
            *(uint4*)(dl + base) = lw;
        }
        if (UNW) {
            float2 q = *(const float2*)(Xc + (size_t)node * DD_);
            mrAcc = fmaf(q.x, u0, mrAcc);
            mrAcc = fmaf(q.y, u1, mrAcc);
        }
    }
    if (UNW) {
        for (int off = 32; off; off >>= 1) mrAcc += __shfl_xor(mrAcc, off);
        if (lane == 0) mred[w] = mrAcc;
        __syncthreads();
        if (threadIdx.x == 0)
            atomicAdd(&gacc[5], mred[0] + mred[1] + mred[2] + mred[3]);
    }
}

// ---------------- fused row-norm + MFMA-pack (wave-per-row, grid-stride) -------
template<int NORM>
__global__ __launch_bounds__(256) void k_rowpack(
    const float* __restrict__ src, const int* __restrict__ gidx,
    const float* __restrict__ scaleIn, float* __restrict__ scaleOut, int nrows,
    unsigned short* __restrict__ dh, unsigned short* __restrict__ dl) {
    int w = threadIdx.x >> 6, lane = threadIdx.x & 63;
    for (int r = blockIdx.x * 4 + w; r < nrows; r += gridDim.x * 4) {
        int rs = gidx ? gidx[r] : r;
        const float4* p = (const float4*)(src + (size_t)rs * DD_);
        float4 x = p[lane * 2], y = p[lane * 2 + 1];
        float sc;
        if (NORM) {
            float s = x.x * x.x + x.y * x.y + x.z * x.z + x.w * x.w
                    + y.x * y.x + y.y * y.y + y.z * y.z + y.w * y.w;
            for (int off = 32; off; off >>= 1) s += __shfl_xor(s, off);
            sc = 1.0f / sqrtf(s + 1e-12f);
            if (scaleOut && lane == 0) scaleOut[r] = sc;
        } else {
            sc = scaleIn ? scaleIn[rs] : 1.0f;
        }
        float vals[8] = {x.x*sc, x.y*sc, x.z*sc, x.w*sc, y.x*sc, y.y*sc, y.z*sc, y.w*sc};
        uint4 hw, lw;
        split8(vals, hw, lw);
        size_t base = (((size_t)(r >> 4) * 16 + (lane >> 2)) * 64 + (lane & 3) * 16 + (r & 15)) * 8;
        *(uint4*)(dh + base) = hw;
        *(uint4*)(dl + base) = lw;
    }
}

// transpose-pack a [512,512] weight: Bp rows = output cols
__global__ __launch_bounds__(256) void k_wpack(
    const float* __restrict__ W,
    unsigned short* __restrict__ dh, unsigned short* __restrict__ dl) {
    int u = threadIdx.x >> 6, lane = threadIdx.x & 63;
    int mt = blockIdx.x, kb = blockIdx.y * 4 + u;
    int n = mt * 16 + (lane & 15);
    int k = kb * 32 + (lane >> 4) * 8;
    float vals[8];
    #pragma unroll
    for (int j = 0; j < 8; ++j) vals[j] = W[(size_t)(k + j) * DD_ + n];
    uint4 hw, lw;
    split8(vals, hw, lw);
    size_t base = (((size_t)mt * 16 + kb) * 64 + lane) * 8;
    *(uint4*)(dh + base) = hw;
    *(uint4*)(dl + base) = lw;
}

// ---------------- MFMA GEMM, C = A . B^T via split-bf16 ----------
// THREE=1: 3-mfma hi/lo (hh+hl+lh). THREE=0: 2-mfma (hh+hl) — dist GEMM only.
// MODE 0: dist — store C fp32 to Cout (stride KK_)
// MODE 2: dense — store C+bias (opt relu) to Cout (stride DD_), rows < Mrows
// MODE 4: fused Wd — grid (8,47): bx<4 = dense (Wd1,bias,store QE);
//         bx>=4 = rec loss (Wd2 at B+2*WPACKE, bias2) -> gacc[3]. bx==4 blocks
//         additionally fold the commit loss sum((q-h)^2) from the A tile -> gacc[2].
template<int MODE, int THREE>
__global__ __launch_bounds__(256) void gemm_mfma(
    const unsigned short* __restrict__ Ah, const unsigned short* __restrict__ Al,
    const unsigned short* __restrict__ Bh, const unsigned short* __restrict__ Bl,
    float* __restrict__ Cout, const float* __restrict__ bias,
    const float* __restrict__ Ref, int relu, int Mrows,
    float* __restrict__ gacc, const float* __restrict__ bias2) {
    int bx = blockIdx.x, by = blockIdx.y;
    int side = (MODE == 4) ? (bx >> 2) : 0;
    int bxe  = (MODE == 4) ? (bx & 3) : bx;
    __shared__ char lds[32768];  // Ah|Al|Bh|Bl tiles, 8 KB each; epilogue scratch aliased
    float* wred0 = (float*)lds;          // valid after final barrier
    float* wred1 = (float*)lds + 4;
    int tid = threadIdx.x;
    int wave = tid >> 6, lane = tid & 63;
    int gmtA = by * 8, gmtB = bxe * 8;
    const unsigned short* garr; int gmt0;
    if (wave == 0)      { garr = Ah; gmt0 = gmtA; }
    else if (wave == 1) { garr = Al; gmt0 = gmtA; }
    else if (wave == 2) { garr = Bh + (size_t)side * 2 * WPACKE; gmt0 = gmtB; }
    else                { garr = Bl + (size_t)side * 2 * WPACKE; gmt0 = gmtB; }
    char* ldst = lds + wave * 8192;
    f32x4 acc[4][4];
    #pragma unroll
    for (int i = 0; i < 4; ++i)
        #pragma unroll
        for (int j = 0; j < 4; ++j) acc[i][j] = (f32x4){0.f, 0.f, 0.f, 0.f};
    float commitAcc = 0.f;
    int wm = wave >> 1, wn = wave & 1;
    for (int kb = 0; kb < 16; ++kb) {
        if (THREE || wave != 1) {
            #pragma unroll
            for (int t = 0; t < 8; ++t) {
                const char* g = (const char*)garr + (((size_t)(gmt0 + t) * 16 + kb) * 1024) + lane * 16;
                gld_lds16(ldst + t * 1024 + lane * 16, g);
            }
        }
        __syncthreads();
        // commit-loss fold: reconstruct q from the A tile, compare vs h (=Ref)
        if (MODE == 4 && bx == 4) {
            int rg = tid >> 1, half = tid & 1;
            int m = by * 128 + rg;
            if (m < Mrows) {
                int tt = rg >> 4, r = rg & 15;
                const float* hp = Ref + (size_t)m * DD_ + kb * 32 + half * 16;
                float4 h0 = ((const float4*)hp)[0], h1 = ((const float4*)hp)[1];
                float4 h2 = ((const float4*)hp)[2], h3 = ((const float4*)hp)[3];
                float hv[16] = {h0.x,h0.y,h0.z,h0.w, h1.x,h1.y,h1.z,h1.w,
                                h2.x,h2.y,h2.z,h2.w, h3.x,h3.y,h3.z,h3.w};
                #pragma unroll
                for (int j2 = 0; j2 < 16; ++j2) {
                    int sub = half * 2 + (j2 >> 3), j = j2 & 7;
                    int off = tt * 1024 + (sub * 16 + r) * 16 + j * 2;
                    u32 hb = *(const unsigned short*)(lds + off);
                    u32 lb = *(const unsigned short*)(lds + 8192 + off);
                    float q = __uint_as_float(hb << 16) + __uint_as_float(lb << 16);
                    float d = q - hv[j2];
                    commitAcc = fmaf(d, d, commitAcc);
                }
            }
        }
        bf16x8 a_h[4], a_l[4], b_h[4], b_l[4];
        #pragma unroll
        for (int i = 0; i < 4; ++i) {
            int at = wm * 4 + i, bt = wn * 4 + i;
            a_h[i] = *(const bf16x8*)(lds + 0     + at * 1024 + lane * 16);
            if (THREE) a_l[i] = *(const bf16x8*)(lds + 8192 + at * 1024 + lane * 16);
            b_h[i] = *(const bf16x8*)(lds + 16384 + bt * 1024 + lane * 16);
            b_l[i] = *(const bf16x8*)(lds + 24576 + bt * 1024 + lane * 16);
        }
        #pragma unroll
        for (int i = 0; i < 4; ++i)
            #pragma unroll
            for (int j = 0; j < 4; ++j) {
                acc[i][j] = __builtin_amdgcn_mfma_f32_16x16x32_bf16(a_h[i], b_h[j], acc[i][j], 0, 0, 0);
                acc[i][j] = __builtin_amdgcn_mfma_f32_16x16x32_bf16(a_h[i], b_l[j], acc[i][j], 0, 0, 0);
                if (THREE)
                    acc[i][j] = __builtin_amdgcn_mfma_f32_16x16x32_bf16(a_l[i], b_h[j], acc[i][j], 0, 0, 0);
            }
        __syncthreads();   // also makes lds safe for epilogue-scratch reuse
    }
    // C/D layout: col = lane&15, row = (lane>>4)*4 + reg
    int m_base = by * 128 + wm * 64;
    int n_base = bxe * 128 + wn * 64;
    int rq = lane >> 4, cc = lane & 15;
    if (MODE == 0) {
        #pragma unroll
        for (int i = 0; i < 4; ++i) {
            int m = m_base + i * 16 + rq * 4;
            #pragma unroll
            for (int j = 0; j < 4; ++j) {
                int n = n_base + j * 16 + cc;
                #pragma unroll
                for (int r = 0; r < 4; ++r) {
                    if (m + r < NN_) Cout[(size_t)(m + r) * KK_ + n] = acc[i][j][r];
                }
            }
        }
    } else if (MODE == 2 || (MODE == 4 && side == 0)) {
        #pragma unroll
        for (int i = 0; i < 4; ++i) {
            int m = m_base + i * 16 + rq * 4;
            #pragma unroll
            for (int j = 0; j < 4; ++j) {
                int n = n_base + j * 16 + cc;
                float bv = bias[n];
                #pragma unroll
                for (int r = 0; r < 4; ++r) {
                    if (m + r < Mrows) {
                        float v = acc[i][j][r] + bv;
                        if (relu) v = fmaxf(v, 0.f);
                        Cout[(size_t)(m + r) * DD_ + n] = v;
                    }
                }
            }
        }
    } else {  // MODE 4 rec-loss side
        const float* bs = bias2;
        float s = 0.f;
        #pragma unroll
        for (int i = 0; i < 4; ++i) {
            int m = m_base + i * 16 + rq * 4;
            #pragma unroll
            for (int j = 0; j < 4; ++j) {
                int n = n_base + j * 16 + cc;
                float bv = bs[n];
                #pragma unroll
                for (int r = 0; r < 4; ++r) {
                    if (m + r < Mrows) {
                        float d = Ref[(size_t)(m + r) * DD_ + n] - (acc[i][j][r] + bv);
                        s = fmaf(d, d, s);
                    }
                }
            }
        }
        for (int off = 32; off; off >>= 1) s += __shfl_xor(s, off);
        if (lane == 0) wred0[wave] = s;
        if (MODE == 4 && bx == 4) {
            float c = commitAcc;
            for (int off = 32; off; off >>= 1) c += __shfl_xor(c, off);
            if (lane == 0) wred1[wave] = c;
        }
        __syncthreads();
        if (tid == 0) {
            atomicAdd(&gacc[3], wred0[0] + wred0[1] + wred0[2] + wred0[3]);
            if (MODE == 4 && bx == 4)
                atomicAdd(&gacc[2], wred1[0] + wred1[1] + wred1[2] + wred1[3]);
        }
    }
}

// ---------------- dedicated rpass GEMM: exact r5 MODE1 structure -------
// R10 post-mortem: neither LDS size (r9) nor block order (r10) recovered r5's
// 78.7us. Remaining diffs vs r5: (a) LDS-tree epilogue (r5 aliased red=lds),
// (b) 2D 47x47 grid with early-return (1081 null blocks interleave with real
// blocks in the round-robin block->CU assignment, smoothing the 4-vs-5
// blocks/CU tail — MFMA is ~2us here, so distribution is first-order).
// This round restores BOTH exactly; only co-compilation context remains.
__global__ __launch_bounds__(256) void gemm_rpass(
    const unsigned short* __restrict__ Qh, const unsigned short* __restrict__ Ql,
    float* __restrict__ gacc, u32* __restrict__ minKey, u32* __restrict__ maxKey) {
    if (blockIdx.x < blockIdx.y) return;  // bx >= by only
    int bx = blockIdx.x, by = blockIdx.y;
    __shared__ char lds[32768];  // Ah|Al|Bh|Bl tiles, 8 KB each
    int tid = threadIdx.x;
    int wave = tid >> 6, lane = tid & 63;
    int gmtA = by * 8, gmtB = bx * 8;
    const unsigned short* garr; int gmt0;
    if (wave == 0)      { garr = Qh; gmt0 = gmtA; }
    else if (wave == 1) { garr = Ql; gmt0 = gmtA; }
    else if (wave == 2) { garr = Qh; gmt0 = gmtB; }
    else                { garr = Ql; gmt0 = gmtB; }
    char* ldst = lds + wave * 8192;
    f32x4 acc[4][4];
    #pragma unroll
    for (int i = 0; i < 4; ++i)
        #pragma unroll
        for (int j = 0; j < 4; ++j) acc[i][j] = (f32x4){0.f, 0.f, 0.f, 0.f};
    int wm = wave >> 1, wn = wave & 1;
    for (int kb = 0; kb < 16; ++kb) {
        #pragma unroll
        for (int t = 0; t < 8; ++t) {
            const char* g = (const char*)garr + (((size_t)(gmt0 + t) * 16 + kb) * 1024) + lane * 16;
            gld_lds16(ldst + t * 1024 + lane * 16, g);
        }
        __syncthreads();
        bf16x8 a_h[4], a_l[4], b_h[4], b_l[4];
        #pragma unroll
        for (int i = 0; i < 4; ++i) {
            int at = wm * 4 + i, bt = wn * 4 + i;
            a_h[i] = *(const bf16x8*)(lds + 0     + at * 1024 + lane * 16);
            a_l[i] = *(const bf16x8*)(lds + 8192  + at * 1024 + lane * 16);
            b_h[i] = *(const bf16x8*)(lds + 16384 + bt * 1024 + lane * 16);
            b_l[i] = *(const bf16x8*)(lds + 24576 + bt * 1024 + lane * 16);
        }
        #pragma unroll
        for (int i = 0; i < 4; ++i)
            #pragma unroll
            for (int j = 0; j < 4; ++j) {
                acc[i][j] = __builtin_amdgcn_mfma_f32_16x16x32_bf16(a_h[i], b_h[j], acc[i][j], 0, 0, 0);
                acc[i][j] = __builtin_amdgcn_mfma_f32_16x16x32_bf16(a_h[i], b_l[j], acc[i][j], 0, 0, 0);
                acc[i][j] = __builtin_amdgcn_mfma_f32_16x16x32_bf16(a_l[i], b_h[j], acc[i][j], 0, 0, 0);
            }
        __syncthreads();
    }
    int m_base = by * 128 + wm * 64;
    int n_base = bx * 128 + wn * 64;
    int rq = lane >> 4, cc = lane & 15;
    float tsum = 0.f, tsq = 0.f, tmin = 3.4e38f, tmax = -3.4e38f;
    #pragma unroll
    for (int i = 0; i < 4; ++i) {
        #pragma unroll
        for (int j = 0; j < 4; ++j) {
            #pragma unroll
            for (int r = 0; r < 4; ++r) {
                int m = m_base + i * 16 + rq * 4 + r;
                int n = n_base + j * 16 + cc;
                if (m < NN_ && n < NN_ && n >= m) {
                    float v = acc[i][j][r];
                    float w = (n > m) ? 2.f : 1.f;
                    tsum += w * v;
                    tsq  += w * v * v;
                    tmin = fminf(tmin, v);
                    tmax = fmaxf(tmax, v);
                }
            }
        }
    }
    // r5's LDS-tree epilogue, red aliased onto lds (safe: all tile reads done)
    float* red = (float*)lds;
    red[tid] = tsum; __syncthreads();
    for (int s = 128; s; s >>= 1) { if (tid < s) red[tid] += red[tid + s]; __syncthreads(); }
    if (tid == 0) atomicAdd(&gacc[0], red[0]);
    __syncthreads();
    red[tid] = tsq; __syncthreads();
    for (int s = 128; s; s >>= 1) { if (tid < s) red[tid] += red[tid + s]; __syncthreads(); }
    if (tid == 0) atomicAdd(&gacc[1], red[0]);
    __syncthreads();
    red[tid] = tmin; __syncthreads();
    for (int s = 128; s; s >>= 1) { if (tid < s) red[tid] = fminf(red[tid], red[tid + s]); __syncthreads(); }
    if (tid == 0) atomicMin(minKey, okey(red[0]));
    __syncthreads();
    red[tid] = tmax; __syncthreads();
    for (int s = 128; s; s >>= 1) { if (tid < s) red[tid] = fmaxf(red[tid], red[tid + s]); __syncthreads(); }
    if (tid == 0) atomicMax(maxKey, okey(red[0]));
}

// exact-fp32 argmax rescue — persistent, wave-per-row.
__global__ __launch_bounds__(256) void k_rescore(
    const float* __restrict__ dist, const float* __restrict__ h,
    const float* __restrict__ rnorm, const float* __restrict__ cb,
    const float* __restrict__ scale, int* __restrict__ ind) {
    int w = threadIdx.x >> 6, lane = threadIdx.x & 63;
    for (int row = blockIdx.x * 4 + w; row < NN_; row += gridDim.x * 4) {
        const float4* dr4 = (const float4*)(dist + (size_t)row * KK_);
        float4 vbuf[16];
        float lmax = -3.4e38f;
        #pragma unroll
        for (int it = 0; it < 16; ++it) {
            float4 v = dr4[lane + it * 64];
            vbuf[it] = v;
            lmax = fmaxf(lmax, fmaxf(fmaxf(v.x, v.y), fmaxf(v.z, v.w)));
        }
        for (int off = 32; off; off >>= 1) lmax = fmaxf(lmax, __shfl_xor(lmax, off));
        float thr = lmax - 1e-3f;
        float hr = rnorm[row];
        const float* hp = h + (size_t)row * DD_;
        u64 best = 0;
        #pragma unroll 1
        for (int it = 0; it < 16; ++it) {
            float4 v = vbuf[it];
            u32 m4 = (v.x >= thr ? 1u : 0u) | (v.y >= thr ? 2u : 0u)
                   | (v.z >= thr ? 4u : 0u) | (v.w >= thr ? 8u : 0u);
            u64 bal = __ballot(m4 != 0);
            while (bal) {
                int l = __ffsll((unsigned long long)bal) - 1;
                bal &= bal - 1;
                u32 mm = __shfl(m4, l);
                while (mm) {
                    int j = __ffs(mm) - 1;
                    mm &= mm - 1;
                    int col = (l + it * 64) * 4 + j;
                    const float* cp = cb + (size_t)col * DD_;
                    float dot = 0.f;
                    #pragma unroll
                    for (int jj = 0; jj < 8; ++jj)
                        dot = fmaf(hp[lane + jj * 64], cp[lane + jj * 64], dot);
                    for (int off = 32; off; off >>= 1) dot += __shfl_xor(dot, off);
                    u64 key = packKey(dot * hr * scale[col], col);
                    if (key > best) best = key;   // dot wave-uniform after butterfly
                }
            }
        }
        if (lane == 0) ind[row] = (int)(~(u32)(best & 0xFFFFFFFFull));
    }
}

// ---------------- fp32 GEMM (kept only for the 6000x40 output) ----------------
__global__ __launch_bounds__(256) void gemm_nn(
    const float* __restrict__ A, const float* __restrict__ B,
    const float* __restrict__ bias, float* __restrict__ C,
    int M, int Ncols, int Kdim) {
    __shared__ float As[16][68];
    __shared__ float Bs[16][68];
    int tid = threadIdx.x;
    int tx = tid & 15, ty = tid >> 4;
    int m0 = blockIdx.y * 64, n0 = blockIdx.x * 64;
    float cv[4][4] = {};
    int ar = tid >> 2;
    int ak = (tid & 3) << 2;
    int am = m0 + ar;
    const float* Arow = (am < M) ? (A + (size_t)am * Kdim) : nullptr;
    int bk = tid >> 4;
    int bn = (tid & 15) << 2;
    for (int k0 = 0; k0 < Kdim; k0 += 16) {
        float4 av = make_float4(0.f, 0.f, 0.f, 0.f);
        if (Arow) av = *(const float4*)(Arow + k0 + ak);
        As[ak + 0][ar] = av.x; As[ak + 1][ar] = av.y;
        As[ak + 2][ar] = av.z; As[ak + 3][ar] = av.w;
        float4 bv = make_float4(0.f, 0.f, 0.f, 0.f);
        if (n0 + bn < Ncols)
            bv = *(const float4*)(B + (size_t)(k0 + bk) * Ncols + n0 + bn);
        Bs[bk][bn + 0] = bv.x; Bs[bk][bn + 1] = bv.y;
        Bs[bk][bn + 2] = bv.z; Bs[bk][bn + 3] = bv.w;
        __syncthreads();
        #pragma unroll
        for (int kk = 0; kk < 16; ++kk) {
            float4 a4 = *(const float4*)&As[kk][ty << 2];
            float4 b4 = *(const float4*)&Bs[kk][tx << 2];
            float ax[4] = {a4.x, a4.y, a4.z, a4.w};
            float bx[4] = {b4.x, b4.y, b4.z, b4.w};
            #pragma unroll
            for (int i = 0; i < 4; ++i)
                #pragma unroll
                for (int j = 0; j < 4; ++j)
                    cv[i][j] = fmaf(ax[i], bx[j], cv[i][j]);
        }
        __syncthreads();
    }
    #pragma unroll
    for (int i = 0; i < 4; ++i) {
        int m = m0 + (ty << 2) + i;
        if (m >= M) continue;
        #pragma unroll
        for (int j = 0; j < 4; ++j) {
            int n = n0 + (tx << 2) + j;
            if (n >= Ncols) continue;
            C[(size_t)m * Ncols + n] = cv[i][j] + bias[n];
        }
    }
}

// ---------------- edge multiplicity hash (for sum m^2 only) ----------------
__global__ void k_hash(const int* __restrict__ src, const int* __restrict__ dst,
                       int* __restrict__ hkey, int* __restrict__ hcnt) {
    int e = blockIdx.x * 256 + threadIdx.x;
    if (e >= EE_) return;
    int key = dst[e] * NN_ + src[e];
    u32 h = ((u32)key * 2654435761u) & HMASK;
    while (true) {
        int old = atomicCAS(&hkey[h], -1, key);
        if (old == -1 || old == key) { atomicAdd(&hcnt[h], 1); break; }
        h = (h + 1) & HMASK;
    }
}

__global__ __launch_bounds__(256) void k_m2scan(const int* __restrict__ hcnt, float* __restrict__ gacc) {
    float s = 0.f;
    for (int i = blockIdx.x * 256 + threadIdx.x; i < HSZ; i += gridDim.x * 256) {
        float c = (float)hcnt[i];
        s = fmaf(c, c, s);
    }
    for (int off = 32; off; off >>= 1) s += __shfl_xor(s, off);
    __shared__ float w1[4];
    int lane = threadIdx.x & 63, wv = threadIdx.x >> 6;
    if (lane == 0) w1[wv] = s;
    __syncthreads();
    if (threadIdx.x == 0) atomicAdd(&gacc[4], w1[0] + w1[1] + w1[2] + w1[3]);
}

// ---------------- final loss assembly ----------------
__global__ void k_final(const float* __restrict__ gacc, const u32* __restrict__ minKey,
                        const u32* __restrict__ maxKey, float* __restrict__ lossOut) {
    if (threadIdx.x != 0 || blockIdx.x != 0) return;
    double Rsum = gacc[0], Rsq = gacc[1], commitS = gacc[2], recS = gacc[3];
    double m2 = gacc[4], mr = gacc[5], ms = (double)EE_;
    double mn = (double)dkey(*minKey);
    double mx = (double)dkey(*maxKey);
    double den = mx - mn;
    double NN2 = (double)NN_ * (double)NN_;
    double sum_aq2 = (Rsq - 2.0 * mn * Rsum + NN2 * mn * mn) / (den * den);
    double sum_maq = (mr - mn * ms) / den;
    double total = sum_aq2 + m2 - 2.0 * sum_maq;
    double edge = sqrt(total / NN2);
    double commit = 0.25 * commitS / ((double)NN_ * (double)DD_);
    double rec = recS / ((double)NN_ * (double)DD_);
    *lossOut = (float)(rec + edge + commit);
}

extern "C" void kernel_launch(void* const* d_in, const int* in_sizes, int n_in,
                              void* d_out, int out_size, void* d_ws, size_t ws_size,
                              hipStream_t stream) {
    const float* feats = (const float*)d_in[0];
    const float* W1 = (const float*)d_in[1];
    const float* b1 = (const float*)d_in[2];
    const float* W2 = (const float*)d_in[3];
    const float* b2v = (const float*)d_in[4];
    const float* Wd1 = (const float*)d_in[5];
    const float* bd1 = (const float*)d_in[6];
    const float* Wd2 = (const float*)d_in[7];
    const float* bd2 = (const float*)d_in[8];
    const float* Wl = (const float*)d_in[9];
    const float* bl = (const float*)d_in[10];
    const float* cb = (const float*)d_in[11];
    const int* src = (const int*)d_in[12];
    const int* dst = (const int*)d_in[13];

    float* outF = (float*)d_out;
    float* lossOut = outF + (size_t)NN_ * OO_;     // element 240000
    float* distOut = lossOut + 1;                  // element 240001

    char* w = (char*)d_ws;
    size_t off = 0;
    auto alloc = [&](size_t bytes) -> void* {
        void* p = w + off;
        off = (off + bytes + 255) & ~(size_t)255;
        return p;
    };
    // zone0: zero-init
    float* gacc = (float*)alloc(64);
    u32* maxKey = (u32*)alloc(4);
    int* degin = (int*)alloc((size_t)NN_ * 4);
    int* degout = (int*)alloc((size_t)NN_ * 4);
    int* cursor = (int*)alloc((size_t)NN_ * 4);
    int* hcnt = (int*)alloc((size_t)HSZ * 4);
    size_t z0end = off;
    // zone1: 0xFF-init
    int* hkey = (int*)alloc((size_t)HSZ * 4);
    u32* minKey = (u32*)alloc(4);
    size_t z1end = off;
    // uninit scratch
    int* offs = (int*)alloc((size_t)(NN_ + 1) * 4);
    int* esrc = (int*)alloc((size_t)EE_ * 4);
    float* rin = (float*)alloc((size_t)NN_ * 4);
    float* rout = (float*)alloc((size_t)NN_ * 4);
    int* ind = (int*)alloc((size_t)NN_ * 4);
    float* scale = (float*)alloc((size_t)KK_ * 4);
    float* rnorm = (float*)alloc((size_t)NN_ * 4);
    float* h = (float*)alloc((size_t)NN_ * DD_ * 4);       // h, later h2
    float* QE = (float*)alloc((size_t)NN_ * DD_ * 4);
    const size_t NPACK = (size_t)MT_A * 16 * DD_;          // node-sized packed half
    unsigned short* P1 = (unsigned short*)alloc(NPACK * 2 * 2);  // aggp -> qcp -> agg2p
    unsigned short* P2 = (unsigned short*)alloc(NPACK * 2 * 2);  // hnp -> QEp
    unsigned short* enp = (unsigned short*)alloc((size_t)KK_ * DD_ * 2 * 2);
    const size_t WPACK = (size_t)32 * 16 * DD_;            // 512-row packed half
    unsigned short* W1p = (unsigned short*)alloc(WPACK * 2 * 2);
    unsigned short* Wd1p = (unsigned short*)alloc(WPACK * 2 * 2);  // MUST stay
    unsigned short* Wd2p = (unsigned short*)alloc(WPACK * 2 * 2);  // contiguous (MODE4)
    unsigned short* W2p = (unsigned short*)alloc(WPACK * 2 * 2);

    unsigned short* aggp_h = P1,  *aggp_l = P1 + NPACK;
    unsigned short* qcp_h  = P1,  *qcp_l  = P1 + NPACK;
    unsigned short* ag2p_h = P1,  *ag2p_l = P1 + NPACK;
    unsigned short* hnp_h  = P2,  *hnp_l  = P2 + NPACK;
    unsigned short* QEp_h  = P2,  *QEp_l  = P2 + NPACK;
    unsigned short* enp_h  = enp, *enp_l  = enp + (size_t)KK_ * DD_;

    hipMemsetAsync(w, 0, z0end, stream);
    hipMemsetAsync(w + z0end, 0xFF, z1end - z0end, stream);

    const int TB = 256;
    k_deg<<<(EE_ + TB - 1) / TB, TB, 0, stream>>>(src, dst, degout, degin);
    k_rsqrtdeg<<<(NN_ + TB - 1) / TB, TB, 0, stream>>>(degout, degin, rout, rin);
    k_scan<<<1, 1024, 0, stream>>>(degin, offs, NN_);
    k_fill<<<(EE_ + TB - 1) / TB, TB, 0, stream>>>(src, dst, offs, cursor, esrc);
    k_wpack<<<dim3(32, 4), TB, 0, stream>>>(W1, W1p, W1p + WPACK);
    k_wpack<<<dim3(32, 4), TB, 0, stream>>>(Wd1, Wd1p, Wd1p + WPACK);
    k_wpack<<<dim3(32, 4), TB, 0, stream>>>(Wd2, Wd2p, Wd2p + WPACK);
    k_wpack<<<dim3(32, 4), TB, 0, stream>>>(W2, W2p, W2p + WPACK);
    k_aggs<0><<<1024, TB, 0, stream>>>(feats, esrc, offs, rout, rin, aggp_h, aggp_l, nullptr);
    gemm_mfma<2,1><<<dim3(4, NB_N), TB, 0, stream>>>(aggp_h, aggp_l, W1p, W1p + WPACK,
                                                     h, b1, nullptr, 1, NN_, nullptr, nullptr);
    k_rowpack<1><<<1024, TB, 0, stream>>>(h, nullptr, nullptr, rnorm, NN_, hnp_h, hnp_l);
    k_rowpack<1><<<1024, TB, 0, stream>>>(cb, nullptr, nullptr, scale, KK_, enp_h, enp_l);
    gemm_mfma<0,0><<<dim3(KK_ / 128, NB_N), TB, 0, stream>>>(hnp_h, hnp_l, enp_h, enp_l,
                                                             distOut, nullptr, nullptr, 0, NN_,
                                                             nullptr, nullptr);
    k_rescore<<<1024, TB, 0, stream>>>(distOut, h, rnorm, cb, scale, ind);
    k_rowpack<0><<<1024, TB, 0, stream>>>(cb, ind, scale, nullptr, NN_, qcp_h, qcp_l);
    // fused Wd1+Wd2 GEMM: stores QE (bx<4), rec loss (bx>=4), commit fold (bx==4)
    gemm_mfma<4,1><<<dim3(8, NB_N), TB, 0, stream>>>(qcp_h, qcp_l, Wd1p, Wd1p + WPACK,
                                                     QE, bd1, h, 0, NN_, gacc, bd2);
    k_rowpack<0><<<1024, TB, 0, stream>>>(QE, nullptr, nullptr, nullptr, NN_, QEp_h, QEp_l);
    gemm_rpass<<<dim3(NB_N, NB_N), TB, 0, stream>>>(QEp_h, QEp_l, gacc, minKey, maxKey);
    k_hash<<<(EE_ + TB - 1) / TB, TB, 0, stream>>>(src, dst, hkey, hcnt);
    k_m2scan<<<512, TB, 0, stream>>>(hcnt, gacc);
    k_aggs<1><<<1024, TB, 0, stream>>>(QE, esrc, offs, rout, rin, ag2p_h, ag2p_l, gacc);
    gemm_mfma<2,1><<<dim3(4, NB_N), TB, 0, stream>>>(ag2p_h, ag2p_l, W2p, W2p + WPACK,
                                                     h, b2v, nullptr, 1, NN_, nullptr, nullptr);
    gemm_nn<<<dim3(1, 94), TB, 0, stream>>>(h, Wl, bl, outF, NN_, OO_, DD_);
    k_final<<<1, 64, 0, stream>>>(gacc, minKey, maxKey, lossOut);
}